// Round 8
// baseline (445.103 us; speedup 1.0000x reference)
//
#include <hip/hip_runtime.h>
#include <hip/hip_bf16.h>
#include <stdint.h>

#define BB   8
#define CIN  256
#define CI   128
#define NN   4096
#define EPSV 1e-5f
#define LOG2E 1.44269504088896340736f

typedef __attribute__((ext_vector_type(8))) short bf16x8;
typedef __attribute__((ext_vector_type(4))) short bf16x4;
typedef __attribute__((ext_vector_type(4))) float f32x4;
typedef __attribute__((ext_vector_type(2))) float f32x2;
typedef __attribute__((ext_vector_type(2))) unsigned int u32x2;

static __device__ inline short f2bf(float f) {
    uint32_t u = __builtin_bit_cast(uint32_t, f);
    u += 0x7FFFu + ((u >> 16) & 1u);   // round-to-nearest-even
    return (short)(u >> 16);
}

static __device__ inline float bf2f(short s) {
    uint32_t u = ((uint32_t)(uint16_t)s) << 16;
    return __builtin_bit_cast(float, u);
}

static __device__ inline uint32_t cvt_pk_bf16(float lo, float hi) {
    uint32_t r;
    asm("v_cvt_pk_bf16_f32 %0, %1, %2" : "=v"(r) : "v"(lo), "v"(hi));
    return r;
}

// ---------------------------------------------------------------------------
// Kernel 1 (FUSED): BN + all three 1x1 projections in one pass over x.
// ---------------------------------------------------------------------------
__global__ __launch_bounds__(256, 2) void proj_kernel(
    const float* __restrict__ x,
    const float* __restrict__ gamma, const float* __restrict__ beta,
    const float* __restrict__ mean,  const float* __restrict__ var,
    const float* __restrict__ wg,  const float* __restrict__ bg,
    const float* __restrict__ wth, const float* __restrict__ bth,
    const float* __restrict__ wph, const float* __restrict__ bph,
    short* __restrict__ qp, short* __restrict__ kp, short* __restrict__ vtp)
{
    __shared__ float s_scale[CIN];
    __shared__ float s_shift[CIN];
    __shared__ __align__(16) short A_lds[64][264];   // [n][c] full K, pad 264
    __shared__ __align__(16) short B_lds[128][72];   // [o][c-chunk], reused x12

    const int tid = threadIdx.x;
    const int b   = blockIdx.x & 7;           // batch == XCD
    const int n0  = (blockIdx.x >> 3) * 64;
    const int w = tid >> 6, lane = tid & 63, lr = lane & 15, lg = lane >> 4;

    {   // BN scale/shift (256 threads == 256 channels)
        float sc = gamma[tid] * rsqrtf(var[tid] + EPSV);
        s_scale[tid] = sc;
        s_shift[tid] = beta[tid] - mean[tid] * sc;
    }
    __syncthreads();

    // stage BN(x) -> A_lds[n][c] bf16, once (16 passes)
    #pragma unroll
    for (int p = 0; p < 16; ++p) {
        int c  = p * 16 + (tid >> 4);
        int n4 = (tid & 15) * 4;
        f32x4 v = *(const f32x4*)&x[((size_t)b * CIN + c) * NN + n0 + n4];
        float sc = s_scale[c], sh = s_shift[c];
        #pragma unroll
        for (int i = 0; i < 4; ++i)
            A_lds[n4 + i][c] = f2bf(v[i] * sc + sh);
    }
    __syncthreads();

    const float* WS[3] = {wth, wph, wg};
    const float* BS[3] = {bth, bph, bg};

    #pragma unroll
    for (int s = 0; s < 3; ++s) {
        f32x4 acc[8];
        #pragma unroll
        for (int i = 0; i < 8; ++i) acc[i] = (f32x4){0.f, 0.f, 0.f, 0.f};

        for (int c0 = 0; c0 < CIN; c0 += 64) {
            // stage B chunk [o][c0..c0+63]
            #pragma unroll
            for (int p = 0; p < 8; ++p) {
                int o  = p * 16 + (tid >> 4);
                int c4 = (tid & 15) * 4;
                f32x4 v = *(const f32x4*)&WS[s][(size_t)o * CIN + c0 + c4];
                bf16x4 bv;
                #pragma unroll
                for (int i = 0; i < 4; ++i) bv[i] = f2bf(v[i]);
                *(bf16x4*)&B_lds[o][c4] = bv;
            }
            __syncthreads();

            bf16x8 a0 = *(const bf16x8*)&A_lds[w * 16 + lr][c0 + lg * 8];
            bf16x8 a1 = *(const bf16x8*)&A_lds[w * 16 + lr][c0 + 32 + lg * 8];
            #pragma unroll
            for (int ot = 0; ot < 8; ++ot) {
                bf16x8 b0 = *(const bf16x8*)&B_lds[ot * 16 + lr][lg * 8];
                bf16x8 b1 = *(const bf16x8*)&B_lds[ot * 16 + lr][32 + lg * 8];
                acc[ot] = __builtin_amdgcn_mfma_f32_16x16x32_bf16(a0, b0, acc[ot], 0, 0, 0);
                acc[ot] = __builtin_amdgcn_mfma_f32_16x16x32_bf16(a1, b1, acc[ot], 0, 0, 0);
            }
            __syncthreads();
        }

        if (s < 2) {   // Q / K: (b, n, c) row-major; Q scaled by log2e
            short* dst = (s == 0) ? qp : kp;
            const float om = (s == 0) ? LOG2E : 1.0f;
            #pragma unroll
            for (int ot = 0; ot < 8; ++ot) {
                float bias = BS[s][ot * 16 + lr];
                #pragma unroll
                for (int rr = 0; rr < 4; ++rr) {
                    int n = n0 + w * 16 + lg * 4 + rr;
                    dst[((size_t)b * NN + n) * CI + ot * 16 + lr] = f2bf((acc[ot][rr] + bias) * om);
                }
            }
        } else {       // V^T: (b, c, n)
            #pragma unroll
            for (int ot = 0; ot < 8; ++ot) {
                float bias = BS[s][ot * 16 + lr];
                bf16x4 pk;
                #pragma unroll
                for (int rr = 0; rr < 4; ++rr) pk[rr] = f2bf(acc[ot][rr] + bias);
                *(bf16x4*)&vtp[((size_t)b * CI + ot * 16 + lr) * NN + n0 + w * 16 + lg * 4] = pk;
            }
        }
    }
}

// ---------------------------------------------------------------------------
// Kernel 2: flash attention, SPLIT-KV x4, 2 Q-strips/wave. K and V SINGLE-
// buffered (LDS 40KB: K 16 + V 16 + P 8) -> 3-4 blocks/CU. Two barriers/iter:
//   QK^T -> bar1 -> stageK(t+1) -> softmax -> PV -> bar2 -> stageV(t+1)
// Each stage's vmcnt drains at the NEXT barrier (window = full compute phase).
// amdgpu_waves_per_eu(3,4): reg budget >=128, no R7-style 64-reg collapse.
// ---------------------------------------------------------------------------
__global__ __launch_bounds__(256) __attribute__((amdgpu_waves_per_eu(3, 4)))
void attn_kernel(
    const short* __restrict__ qp, const short* __restrict__ kp,
    const short* __restrict__ vtp, short* __restrict__ yh,
    float* __restrict__ ml)
{
    __shared__ __align__(16) char K_sh[64 * 256];      // [m][c] swizzled, 16KB
    __shared__ __align__(16) char V_sh[128 * 128];     // [c][m] swizzled, 16KB
    __shared__ __align__(16) char P_sh[4][16 * 128];   // per-wave P buf, 2KB

    const int tid = threadIdx.x;
    const int b   = blockIdx.x & 7;             // batch == XCD (round-robin)
    const int qtr = (blockIdx.x >> 3) & 3;      // kv quarter
    const int n0  = (blockIdx.x >> 5) * 128;
    const int w = tid >> 6, lane = tid & 63, lr = lane & 15, lg = lane >> 4;
    const int NT = NN / 256;                    // 16 kv tiles per quarter
    const int t0 = qtr * NT;

    const char* kbase = (const char*)(kp + (size_t)b * NN * CI);
    const char* vbase = (const char*)(vtp + (size_t)b * CI * NN);
    uint32_t koff[4], vof[4];
    #pragma unroll
    for (int r = 0; r < 4; ++r) {
        int idx = ((r * 4 + w) << 6) + lane;          // 16B-chunk index 0..1023
        int mm  = idx >> 4, cb = (idx & 15) << 4;     // K: row m, dest col-byte
        koff[r] = (uint32_t)((t0 * 64 + mm) * 256) + (uint32_t)(cb ^ ((mm & 7) << 4));
        int cc = idx >> 3, cbv = (idx & 7) << 4;      // V: row c, dest col-byte
        vof[r] = (uint32_t)(cc * (NN * 2) + t0 * 128) + (uint32_t)(cbv ^ ((cc & 7) << 4));
    }
    auto stageK = [&]() {
        #pragma unroll
        for (int r = 0; r < 4; ++r) {
            __builtin_amdgcn_global_load_lds(
                (const __attribute__((address_space(1))) void*)(kbase + koff[r]),
                (__attribute__((address_space(3))) void*)&K_sh[(r * 4 + w) << 10],
                16, 0, 0);
            koff[r] += 64 * 256;      // next K tile: 16 KB
        }
    };
    auto stageV = [&]() {
        #pragma unroll
        for (int r = 0; r < 4; ++r) {
            __builtin_amdgcn_global_load_lds(
                (const __attribute__((address_space(1))) void*)(vbase + vof[r]),
                (__attribute__((address_space(3))) void*)&V_sh[(r * 4 + w) << 10],
                16, 0, 0);
            vof[r] += 128;            // next V tile: 64 m * 2B
        }
    };

    // Q strips in registers (B-frag for mfma(K,Q): col=q=lr, k contiguous)
    bf16x8 qf[2][4];
    #pragma unroll
    for (int s = 0; s < 2; ++s) {
        const short* qrow = qp + ((size_t)b * NN + n0 + w * 32 + s * 16 + lr) * CI;
        #pragma unroll
        for (int kf = 0; kf < 4; ++kf)
            qf[s][kf] = *(const bf16x8*)&qrow[kf * 32 + lg * 8];
    }

    f32x4 yacc[2][8];
    #pragma unroll
    for (int s = 0; s < 2; ++s)
        #pragma unroll
        for (int i = 0; i < 8; ++i) yacc[s][i] = (f32x4){0.f, 0.f, 0.f, 0.f};
    float m_run[2] = {-__builtin_huge_valf(), -__builtin_huge_valf()};
    float l_run[2] = {0.f, 0.f};   // per-lane partial sums; reduced after loop

    stageK();
    stageV();
    __syncthreads();   // vmcnt(0) drained by compiler before barrier

    for (int t = 0; t < NT; ++t) {
        // ---- A: S^T = K Q from K_sh ----
        f32x4 sa[2][4];
        __builtin_amdgcn_s_setprio(1);
        #pragma unroll
        for (int mt = 0; mt < 4; ++mt) {
            const int mrow = mt * 16 + lr;
            const int sw   = (mrow & 7) << 4;
            sa[0][mt] = (f32x4){0.f, 0.f, 0.f, 0.f};
            sa[1][mt] = (f32x4){0.f, 0.f, 0.f, 0.f};
            #pragma unroll
            for (int kf = 0; kf < 4; ++kf) {
                bf16x8 kfrag = *(const bf16x8*)(K_sh + (mrow << 8) + ((kf * 64 + lg * 16) ^ sw));
                sa[0][mt] = __builtin_amdgcn_mfma_f32_16x16x32_bf16(kfrag, qf[0][kf], sa[0][mt], 0, 0, 0);
                sa[1][mt] = __builtin_amdgcn_mfma_f32_16x16x32_bf16(kfrag, qf[1][kf], sa[1][mt], 0, 0, 0);
            }
        }
        __builtin_amdgcn_s_setprio(0);

        __syncthreads();              // bar1: all waves done reading K_sh
        if (t + 1 < NT) stageK();     // async K(t+1); drains at bar2

        // ---- lazy online softmax: no cross-lane ops on the common path ----
        float tml[2];
        #pragma unroll
        for (int s = 0; s < 2; ++s) {
            float tm = fmaxf(fmaxf(fmaxf(sa[s][0][0], sa[s][0][1]), fmaxf(sa[s][0][2], sa[s][0][3])),
                             fmaxf(fmaxf(sa[s][1][0], sa[s][1][1]), fmaxf(sa[s][1][2], sa[s][1][3])));
            tm = fmaxf(tm, fmaxf(fmaxf(fmaxf(sa[s][2][0], sa[s][2][1]), fmaxf(sa[s][2][2], sa[s][2][3])),
                                 fmaxf(fmaxf(sa[s][3][0], sa[s][3][1]), fmaxf(sa[s][3][2], sa[s][3][3]))));
            tml[s] = tm;
        }
        if (__any((tml[0] - m_run[0] > 8.f) || (tml[1] - m_run[1] > 8.f))) {
            #pragma unroll
            for (int s = 0; s < 2; ++s) {
                float tm = tml[s];
                tm = fmaxf(tm, __shfl_xor(tm, 16));
                tm = fmaxf(tm, __shfl_xor(tm, 32));
                float mnew = fmaxf(m_run[s], tm);
                float sc   = __builtin_amdgcn_exp2f(m_run[s] - mnew);
                m_run[s] = mnew;
                l_run[s] *= sc;
                #pragma unroll
                for (int rr = 0; rr < 4; ++rr) {
                    float scb = __shfl(sc, (lane & 48) | (lg * 4 + rr));
                    #pragma unroll
                    for (int ct = 0; ct < 8; ++ct) yacc[s][ct][rr] *= scb;
                }
            }
        }

        // V-frags into regs early (shared by both strips)
        bf16x8 vf[2][8];
        #pragma unroll
        for (int kf = 0; kf < 2; ++kf)
            #pragma unroll
            for (int ct = 0; ct < 8; ++ct) {
                const int vr = ct * 16 + lr;
                vf[kf][ct] = *(const bf16x8*)(V_sh + (vr << 7) +
                                              ((kf * 64 + lg * 16) ^ ((vr & 7) << 4)));
            }

        // strip 0: exp2 + cvt_pk pack into per-wave P buf, then read pa0
        char* Pb = P_sh[w];
        bf16x8 pa0[2], pa1[2];
        {
            float rs = 0.f;
            #pragma unroll
            for (int mt = 0; mt < 4; ++mt) {
                float e0 = __builtin_amdgcn_exp2f(sa[0][mt][0] - m_run[0]);
                float e1 = __builtin_amdgcn_exp2f(sa[0][mt][1] - m_run[0]);
                float e2 = __builtin_amdgcn_exp2f(sa[0][mt][2] - m_run[0]);
                float e3 = __builtin_amdgcn_exp2f(sa[0][mt][3] - m_run[0]);
                rs += (e0 + e1) + (e2 + e3);
                u32x2 pk = {cvt_pk_bf16(e0, e1), cvt_pk_bf16(e2, e3)};
                *(u32x2*)(Pb + lr * 128 + ((mt * 32 + lg * 8) ^ ((lr & 7) << 4))) = pk;
            }
            l_run[0] += rs;           // per-lane partial; reduced after loop
        }
        asm volatile("" ::: "memory");
        #pragma unroll
        for (int kf = 0; kf < 2; ++kf)
            pa0[kf] = *(const bf16x8*)(Pb + lr * 128 + ((kf * 64 + lg * 16) ^ ((lr & 7) << 4)));
        asm volatile("" ::: "memory");

        // strip 1: overwrite same P buf (same-wave DS is in-order; fenced)
        {
            float rs = 0.f;
            #pragma unroll
            for (int mt = 0; mt < 4; ++mt) {
                float e0 = __builtin_amdgcn_exp2f(sa[1][mt][0] - m_run[1]);
                float e1 = __builtin_amdgcn_exp2f(sa[1][mt][1] - m_run[1]);
                float e2 = __builtin_amdgcn_exp2f(sa[1][mt][2] - m_run[1]);
                float e3 = __builtin_amdgcn_exp2f(sa[1][mt][3] - m_run[1]);
                rs += (e0 + e1) + (e2 + e3);
                u32x2 pk = {cvt_pk_bf16(e0, e1), cvt_pk_bf16(e2, e3)};
                *(u32x2*)(Pb + lr * 128 + ((mt * 32 + lg * 8) ^ ((lr & 7) << 4))) = pk;
            }
            l_run[1] += rs;
        }
        asm volatile("" ::: "memory");
        #pragma unroll
        for (int kf = 0; kf < 2; ++kf)
            pa1[kf] = *(const bf16x8*)(Pb + lr * 128 + ((kf * 64 + lg * 16) ^ ((lr & 7) << 4)));

        // ---- E: Y += P V (all operands in registers) ----
        __builtin_amdgcn_s_setprio(1);
        #pragma unroll
        for (int kf = 0; kf < 2; ++kf)
            #pragma unroll
            for (int ct = 0; ct < 8; ++ct) {
                yacc[0][ct] = __builtin_amdgcn_mfma_f32_16x16x32_bf16(pa0[kf], vf[kf][ct], yacc[0][ct], 0, 0, 0);
                yacc[1][ct] = __builtin_amdgcn_mfma_f32_16x16x32_bf16(pa1[kf], vf[kf][ct], yacc[1][ct], 0, 0, 0);
            }
        __builtin_amdgcn_s_setprio(0);

        __syncthreads();              // bar2: V reads done; K(t+1) drained
        if (t + 1 < NT) stageV();     // async V(t+1); drains at next bar1
    }

    // reduce l across the 4 lane-groups (deferred from the loop)
    #pragma unroll
    for (int s = 0; s < 2; ++s) {
        float lt = l_run[s];
        lt += __shfl_xor(lt, 16);
        lt += __shfl_xor(lt, 32);
        l_run[s] = lt;
    }

    // store UNNORMALIZED partial Yhat (bf16) + (m,l) per q-row
    short* yb = yh + ((size_t)qtr * BB + b) * NN * (size_t)CI;
    #pragma unroll
    for (int s = 0; s < 2; ++s) {
        #pragma unroll
        for (int rr = 0; rr < 4; ++rr) {
            int n = n0 + w * 32 + s * 16 + lg * 4 + rr;
            #pragma unroll
            for (int ct = 0; ct < 8; ++ct)
                yb[(size_t)n * CI + ct * 16 + lr] = f2bf(yacc[s][ct][rr]);
        }
    }
    if (lg == 0) {
        #pragma unroll
        for (int s = 0; s < 2; ++s) {
            int n = n0 + w * 32 + s * 16 + lr;
            f32x2 v = {m_run[s], l_run[s]};
            *(f32x2*)&ml[(((size_t)qtr * BB + b) * NN + n) * 2] = v;
        }
    }
}

// ---------------------------------------------------------------------------
// Kernel 2b: merge the four KV-quarter bf16 partials -> normalized Y^T bf16
// ---------------------------------------------------------------------------
__global__ __launch_bounds__(256) void merge_kernel(
    const short* __restrict__ yh, const float* __restrict__ ml,
    short* __restrict__ yp)
{
    const int tid = threadIdx.x;
    const int row = blockIdx.x * 8 + (tid >> 5);    // (b*NN + n) in [0, BB*NN)
    const int c4  = (tid & 31) * 4;
    const size_t H = (size_t)BB * NN * CI;          // quarter stride in yh
    const size_t R = (size_t)BB * NN * 2;           // quarter stride in ml

    float m[4], l[4];
    #pragma unroll
    for (int h = 0; h < 4; ++h) {
        f32x2 v = *(const f32x2*)&ml[h * R + (size_t)row * 2];
        m[h] = v[0]; l[h] = v[1];
    }
    float mm = fmaxf(fmaxf(m[0], m[1]), fmaxf(m[2], m[3]));
    float wh[4], den = 0.f;
    #pragma unroll
    for (int h = 0; h < 4; ++h) {
        wh[h] = __builtin_amdgcn_exp2f(m[h] - mm);
        den += l[h] * wh[h];
    }
    float inv = 1.0f / den;

    float o[4] = {0.f, 0.f, 0.f, 0.f};
    #pragma unroll
    for (int h = 0; h < 4; ++h) {
        bf16x4 a = *(const bf16x4*)&yh[h * H + (size_t)row * CI + c4];
        float wn = wh[h] * inv;
        #pragma unroll
        for (int i = 0; i < 4; ++i) o[i] += bf2f(a[i]) * wn;
    }
    bf16x4 ov;
    #pragma unroll
    for (int i = 0; i < 4; ++i) ov[i] = f2bf(o[i]);
    *(bf16x4*)&yp[(size_t)row * CI + c4] = ov;
}

// ---------------------------------------------------------------------------
// Kernel 3: out = w_w @ Y + b_w + x.  M=o (coalesced n-stores), 128x128 tiles.
// ---------------------------------------------------------------------------
__global__ __launch_bounds__(256) void out_kernel(
    const short* __restrict__ yp, const float* __restrict__ ww,
    const float* __restrict__ bw, const float* __restrict__ x,
    float* __restrict__ out)
{
    __shared__ __align__(16) short A_lds[128][136];   // w_w [o][c]
    __shared__ __align__(16) short Bl[128][136];      // Y^T [n][c]

    const int tid = threadIdx.x;
    const int ob = blockIdx.x & 1;
    const int g  = blockIdx.x >> 1;
    const int b  = g >> 5;
    const int nn = (g & 31) * 128;
    const int o0 = ob * 128;
    const int w = tid >> 6, lane = tid & 63, lr = lane & 15, lg = lane >> 4;

    #pragma unroll
    for (int pass = 0; pass < 8; ++pass) {
        int o  = pass * 16 + (tid >> 4);
        int c8 = (tid & 15) * 8;
        f32x4 v0 = *(const f32x4*)&ww[(size_t)(o0 + o) * CI + c8];
        f32x4 v1 = *(const f32x4*)&ww[(size_t)(o0 + o) * CI + c8 + 4];
        bf16x8 bv;
        #pragma unroll
        for (int i = 0; i < 4; ++i) { bv[i] = f2bf(v0[i]); bv[4 + i] = f2bf(v1[i]); }
        *(bf16x8*)&A_lds[o][c8] = bv;
    }
    #pragma unroll
    for (int pass = 0; pass < 8; ++pass) {
        int n  = pass * 16 + (tid >> 4);
        int c8 = (tid & 15) * 8;
        *(bf16x8*)&Bl[n][c8] = *(const bf16x8*)&yp[((size_t)b * NN + nn + n) * CI + c8];
    }
    __syncthreads();

    f32x4 acc[2][8];
    #pragma unroll
    for (int i = 0; i < 2; ++i)
        #pragma unroll
        for (int j = 0; j < 8; ++j) acc[i][j] = (f32x4){0.f, 0.f, 0.f, 0.f};

    #pragma unroll
    for (int kf = 0; kf < 4; ++kf) {
        bf16x8 a0 = *(const bf16x8*)&A_lds[w * 32 + lr][kf * 32 + lg * 8];
        bf16x8 a1 = *(const bf16x8*)&A_lds[w * 32 + 16 + lr][kf * 32 + lg * 8];
        #pragma unroll
        for (int nt = 0; nt < 8; ++nt) {
            bf16x8 bv = *(const bf16x8*)&Bl[nt * 16 + lr][kf * 32 + lg * 8];
            acc[0][nt] = __builtin_amdgcn_mfma_f32_16x16x32_bf16(a0, bv, acc[0][nt], 0, 0, 0);
            acc[1][nt] = __builtin_amdgcn_mfma_f32_16x16x32_bf16(a1, bv, acc[1][nt], 0, 0, 0);
        }
    }

    #pragma unroll
    for (int wo = 0; wo < 2; ++wo) {
        #pragma unroll
        for (int rr = 0; rr < 4; ++rr) {
            int o = o0 + w * 32 + wo * 16 + lg * 4 + rr;
            float bias = bw[o];
            #pragma unroll
            for (int nt = 0; nt < 8; ++nt) {
                size_t idx = ((size_t)b * CIN + o) * NN + nn + nt * 16 + lr;
                out[idx] = acc[wo][nt][rr] + bias + x[idx];
            }
        }
    }
}

// ---------------------------------------------------------------------------
extern "C" void kernel_launch(void* const* d_in, const int* in_sizes, int n_in,
                              void* d_out, int out_size, void* d_ws, size_t ws_size,
                              hipStream_t stream)
{
    const float* x     = (const float*)d_in[0];
    const float* gamma = (const float*)d_in[1];
    const float* beta  = (const float*)d_in[2];
    const float* mean  = (const float*)d_in[3];
    const float* var   = (const float*)d_in[4];
    const float* wg    = (const float*)d_in[5];
    const float* bg    = (const float*)d_in[6];
    const float* wth   = (const float*)d_in[7];
    const float* bth   = (const float*)d_in[8];
    const float* wph   = (const float*)d_in[9];
    const float* bph   = (const float*)d_in[10];
    const float* ww    = (const float*)d_in[11];
    const float* bw    = (const float*)d_in[12];

    // ws layout: qp 8MB | kp 8MB | vtp 8MB | ml 1MB  (yp aliases qp after attn)
    // d_out (33.5MB) doubles as bf16 Yhat partial scratch (4 x 8MB) between
    // attn and merge; out_kernel then overwrites d_out fully.
    const size_t seg = (size_t)BB * NN * CI;
    short* qp  = (short*)d_ws;
    short* kp  = qp + seg;
    short* vtp = kp + seg;
    float* ml  = (float*)(vtp + seg);
    short* yp  = qp;                       // reuse: q dead after attn
    short* yh  = (short*)d_out;            // [4][B][N][CI] bf16 partials
    (void)in_sizes; (void)n_in; (void)out_size; (void)ws_size;

    proj_kernel<<<BB * (NN / 64), 256, 0, stream>>>(
        x, gamma, beta, mean, var, wg, bg, wth, bth, wph, bph, qp, kp, vtp);
    attn_kernel<<<4 * BB * (NN / 128), 256, 0, stream>>>(qp, kp, vtp, yh, ml);
    merge_kernel<<<BB * NN / 8, 256, 0, stream>>>(yh, ml, yp);
    out_kernel<<<2 * BB * (NN / 128), 256, 0, stream>>>(yp, ww, bw, x, (float*)d_out);
}

// Round 9
// 120.924 us; speedup vs baseline: 3.6809x; 3.6809x over previous
//
#include <hip/hip_runtime.h>
#include <hip/hip_bf16.h>
#include <stdint.h>

#define BB   8
#define CIN  256
#define CI   128
#define NN   4096
#define EPSV 1e-5f
#define LOG2E 1.44269504088896340736f

typedef __attribute__((ext_vector_type(8))) short bf16x8;
typedef __attribute__((ext_vector_type(4))) short bf16x4;
typedef __attribute__((ext_vector_type(4))) float f32x4;
typedef __attribute__((ext_vector_type(2))) float f32x2;
typedef __attribute__((ext_vector_type(2))) unsigned int u32x2;

static __device__ inline short f2bf(float f) {
    uint32_t u = __builtin_bit_cast(uint32_t, f);
    u += 0x7FFFu + ((u >> 16) & 1u);   // round-to-nearest-even
    return (short)(u >> 16);
}

static __device__ inline float bf2f(short s) {
    uint32_t u = ((uint32_t)(uint16_t)s) << 16;
    return __builtin_bit_cast(float, u);
}

static __device__ inline uint32_t cvt_pk_bf16(float lo, float hi) {
    uint32_t r;
    asm("v_cvt_pk_bf16_f32 %0, %1, %2" : "=v"(r) : "v"(lo), "v"(hi));
    return r;
}

// ---------------------------------------------------------------------------
// Kernel 1 (FUSED): BN + all three 1x1 projections in one pass over x.
// ---------------------------------------------------------------------------
__global__ __launch_bounds__(256, 2) void proj_kernel(
    const float* __restrict__ x,
    const float* __restrict__ gamma, const float* __restrict__ beta,
    const float* __restrict__ mean,  const float* __restrict__ var,
    const float* __restrict__ wg,  const float* __restrict__ bg,
    const float* __restrict__ wth, const float* __restrict__ bth,
    const float* __restrict__ wph, const float* __restrict__ bph,
    short* __restrict__ qp, short* __restrict__ kp, short* __restrict__ vtp)
{
    __shared__ float s_scale[CIN];
    __shared__ float s_shift[CIN];
    __shared__ __align__(16) short A_lds[64][264];   // [n][c] full K, pad 264
    __shared__ __align__(16) short B_lds[128][72];   // [o][c-chunk], reused x12

    const int tid = threadIdx.x;
    const int b   = blockIdx.x & 7;           // batch == XCD
    const int n0  = (blockIdx.x >> 3) * 64;
    const int w = tid >> 6, lane = tid & 63, lr = lane & 15, lg = lane >> 4;

    {   // BN scale/shift (256 threads == 256 channels)
        float sc = gamma[tid] * rsqrtf(var[tid] + EPSV);
        s_scale[tid] = sc;
        s_shift[tid] = beta[tid] - mean[tid] * sc;
    }
    __syncthreads();

    // stage BN(x) -> A_lds[n][c] bf16, once (16 passes)
    #pragma unroll
    for (int p = 0; p < 16; ++p) {
        int c  = p * 16 + (tid >> 4);
        int n4 = (tid & 15) * 4;
        f32x4 v = *(const f32x4*)&x[((size_t)b * CIN + c) * NN + n0 + n4];
        float sc = s_scale[c], sh = s_shift[c];
        #pragma unroll
        for (int i = 0; i < 4; ++i)
            A_lds[n4 + i][c] = f2bf(v[i] * sc + sh);
    }
    __syncthreads();

    const float* WS[3] = {wth, wph, wg};
    const float* BS[3] = {bth, bph, bg};

    #pragma unroll
    for (int s = 0; s < 3; ++s) {
        f32x4 acc[8];
        #pragma unroll
        for (int i = 0; i < 8; ++i) acc[i] = (f32x4){0.f, 0.f, 0.f, 0.f};

        for (int c0 = 0; c0 < CIN; c0 += 64) {
            // stage B chunk [o][c0..c0+63]
            #pragma unroll
            for (int p = 0; p < 8; ++p) {
                int o  = p * 16 + (tid >> 4);
                int c4 = (tid & 15) * 4;
                f32x4 v = *(const f32x4*)&WS[s][(size_t)o * CIN + c0 + c4];
                bf16x4 bv;
                #pragma unroll
                for (int i = 0; i < 4; ++i) bv[i] = f2bf(v[i]);
                *(bf16x4*)&B_lds[o][c4] = bv;
            }
            __syncthreads();

            bf16x8 a0 = *(const bf16x8*)&A_lds[w * 16 + lr][c0 + lg * 8];
            bf16x8 a1 = *(const bf16x8*)&A_lds[w * 16 + lr][c0 + 32 + lg * 8];
            #pragma unroll
            for (int ot = 0; ot < 8; ++ot) {
                bf16x8 b0 = *(const bf16x8*)&B_lds[ot * 16 + lr][lg * 8];
                bf16x8 b1 = *(const bf16x8*)&B_lds[ot * 16 + lr][32 + lg * 8];
                acc[ot] = __builtin_amdgcn_mfma_f32_16x16x32_bf16(a0, b0, acc[ot], 0, 0, 0);
                acc[ot] = __builtin_amdgcn_mfma_f32_16x16x32_bf16(a1, b1, acc[ot], 0, 0, 0);
            }
            __syncthreads();
        }

        if (s < 2) {   // Q / K: (b, n, c) row-major; Q scaled by log2e
            short* dst = (s == 0) ? qp : kp;
            const float om = (s == 0) ? LOG2E : 1.0f;
            #pragma unroll
            for (int ot = 0; ot < 8; ++ot) {
                float bias = BS[s][ot * 16 + lr];
                #pragma unroll
                for (int rr = 0; rr < 4; ++rr) {
                    int n = n0 + w * 16 + lg * 4 + rr;
                    dst[((size_t)b * NN + n) * CI + ot * 16 + lr] = f2bf((acc[ot][rr] + bias) * om);
                }
            }
        } else {       // V^T: (b, c, n)
            #pragma unroll
            for (int ot = 0; ot < 8; ++ot) {
                float bias = BS[s][ot * 16 + lr];
                bf16x4 pk;
                #pragma unroll
                for (int rr = 0; rr < 4; ++rr) pk[rr] = f2bf(acc[ot][rr] + bias);
                *(bf16x4*)&vtp[((size_t)b * CI + ot * 16 + lr) * NN + n0 + w * 16 + lg * 4] = pk;
            }
        }
    }
}

// ---------------------------------------------------------------------------
// Kernel 2: flash attention — R5 proven structure (97.4us) + branchless-lazy
// softmax. SPLIT-KV x2, grid 512 = 8 batch x 2 half x 32 q-tiles -> 2 blk/CU.
// 4 waves x 2 Q-strips; K/V double-buffered via global_load_lds (pre-swizzled
// source, linear LDS dest); 1 barrier/iter. 192 regs (128 VGPR + 64 AGPR) =
// 2 waves/SIMD; do NOT raise occupancy with this body (R6/R7/R8 lessons).
// ---------------------------------------------------------------------------
__global__ __launch_bounds__(256, 2) void attn_kernel(
    const short* __restrict__ qp, const short* __restrict__ kp,
    const short* __restrict__ vtp, short* __restrict__ yh,
    float* __restrict__ ml)
{
    __shared__ __align__(16) char K_sh[2][64 * 256];    // [m][c] swizzled, 16KB x2
    __shared__ __align__(16) char V_sh[2][128 * 128];   // [c][m] swizzled, 16KB x2
    __shared__ __align__(16) char P_sh[4][16 * 128];    // per-wave single P buf

    const int tid  = threadIdx.x;
    const int b    = blockIdx.x & 7;            // batch == XCD (round-robin)
    const int half = (blockIdx.x >> 3) & 1;     // kv half
    const int n0   = (blockIdx.x >> 4) * 128;
    const int w = tid >> 6, lane = tid & 63, lr = lane & 15, lg = lane >> 4;
    const int NT = NN / 128;                    // 32 kv tiles per half
    const int t0 = half * NT;

    // loop-carried per-lane global source pointers (pre-swizzled), LDS dest linear
    const char* kgp[4];
    const char* vgp[4];
    #pragma unroll
    for (int r = 0; r < 4; ++r) {
        int idx = ((r * 4 + w) << 6) + lane;          // 16B-chunk index 0..1023
        int mm  = idx >> 4, cb = (idx & 15) << 4;     // K: row m, dest col-byte
        kgp[r] = (const char*)(kp + (size_t)b * NN * CI + (size_t)t0 * 64 * CI
                               + (size_t)mm * CI) + (cb ^ ((mm & 7) << 4));
        int cc = idx >> 3, cbv = (idx & 7) << 4;      // V: row c, dest col-byte
        vgp[r] = (const char*)(vtp + (size_t)b * CI * NN + (size_t)t0 * 64
                               + (size_t)cc * NN) + (cbv ^ ((cc & 7) << 4));
    }
    auto stage = [&](int bufi) {
        #pragma unroll
        for (int r = 0; r < 4; ++r) {
            __builtin_amdgcn_global_load_lds(
                (const __attribute__((address_space(1))) void*)kgp[r],
                (__attribute__((address_space(3))) void*)&K_sh[bufi][(r * 4 + w) << 10],
                16, 0, 0);
            __builtin_amdgcn_global_load_lds(
                (const __attribute__((address_space(1))) void*)vgp[r],
                (__attribute__((address_space(3))) void*)&V_sh[bufi][(r * 4 + w) << 10],
                16, 0, 0);
            kgp[r] += 64 * CI * 2;    // next K tile: 16 KB
            vgp[r] += 64 * 2;         // next V tile: 128 B
        }
    };

    // Q strips in registers (B-frag for mfma(K,Q): col=q=lr, k contiguous)
    bf16x8 qf[2][4];
    #pragma unroll
    for (int s = 0; s < 2; ++s) {
        const short* qrow = qp + ((size_t)b * NN + n0 + w * 32 + s * 16 + lr) * CI;
        #pragma unroll
        for (int kf = 0; kf < 4; ++kf)
            qf[s][kf] = *(const bf16x8*)&qrow[kf * 32 + lg * 8];
    }

    f32x4 yacc[2][8];
    #pragma unroll
    for (int s = 0; s < 2; ++s)
        #pragma unroll
        for (int i = 0; i < 8; ++i) yacc[s][i] = (f32x4){0.f, 0.f, 0.f, 0.f};
    float m_run[2] = {-__builtin_huge_valf(), -__builtin_huge_valf()};
    float l_run[2] = {0.f, 0.f};   // per-lane partials; reduced after the loop

    stage(0);
    __syncthreads();

    for (int t = 0; t < NT; ++t) {
        const int cur = t & 1;
        if (t + 1 < NT) stage(cur ^ 1);   // issue before compute

        // S^T = K Q : lane (lr,lg) holds S[q=lr][m=mt*16+lg*4+rr] per strip
        const char* Kc = K_sh[cur];
        f32x4 sa[2][4];
        __builtin_amdgcn_s_setprio(1);
        #pragma unroll
        for (int mt = 0; mt < 4; ++mt) {
            const int mrow = mt * 16 + lr;
            const int sw   = (mrow & 7) << 4;
            sa[0][mt] = (f32x4){0.f, 0.f, 0.f, 0.f};
            sa[1][mt] = (f32x4){0.f, 0.f, 0.f, 0.f};
            #pragma unroll
            for (int kf = 0; kf < 4; ++kf) {
                bf16x8 kfrag = *(const bf16x8*)(Kc + (mrow << 8) + ((kf * 64 + lg * 16) ^ sw));
                sa[0][mt] = __builtin_amdgcn_mfma_f32_16x16x32_bf16(kfrag, qf[0][kf], sa[0][mt], 0, 0, 0);
                sa[1][mt] = __builtin_amdgcn_mfma_f32_16x16x32_bf16(kfrag, qf[1][kf], sa[1][mt], 0, 0, 0);
            }
        }
        __builtin_amdgcn_s_setprio(0);

        // lazy online softmax: per-lane partial max only on the common path
        float tml[2];
        #pragma unroll
        for (int s = 0; s < 2; ++s) {
            float tm = fmaxf(fmaxf(fmaxf(sa[s][0][0], sa[s][0][1]), fmaxf(sa[s][0][2], sa[s][0][3])),
                             fmaxf(fmaxf(sa[s][1][0], sa[s][1][1]), fmaxf(sa[s][1][2], sa[s][1][3])));
            tm = fmaxf(tm, fmaxf(fmaxf(fmaxf(sa[s][2][0], sa[s][2][1]), fmaxf(sa[s][2][2], sa[s][2][3])),
                                 fmaxf(fmaxf(sa[s][3][0], sa[s][3][1]), fmaxf(sa[s][3][2], sa[s][3][3]))));
            tml[s] = tm;
        }
        if (__any((tml[0] - m_run[0] > 8.f) || (tml[1] - m_run[1] > 8.f))) {
            #pragma unroll
            for (int s = 0; s < 2; ++s) {
                float tm = tml[s];
                tm = fmaxf(tm, __shfl_xor(tm, 16));
                tm = fmaxf(tm, __shfl_xor(tm, 32));
                float mnew = fmaxf(m_run[s], tm);
                float sc   = __builtin_amdgcn_exp2f(m_run[s] - mnew);
                m_run[s] = mnew;
                l_run[s] *= sc;
                #pragma unroll
                for (int rr = 0; rr < 4; ++rr) {
                    float scb = __shfl(sc, (lane & 48) | (lg * 4 + rr));
                    #pragma unroll
                    for (int ct = 0; ct < 8; ++ct) yacc[s][ct][rr] *= scb;
                }
            }
        }

        // V-frags into regs early (shared by both strips)
        const char* Vc = V_sh[cur];
        bf16x8 vf[2][8];
        #pragma unroll
        for (int kf = 0; kf < 2; ++kf)
            #pragma unroll
            for (int ct = 0; ct < 8; ++ct) {
                const int vr = ct * 16 + lr;
                vf[kf][ct] = *(const bf16x8*)(Vc + (vr << 7) +
                                              ((kf * 64 + lg * 16) ^ ((vr & 7) << 4)));
            }

        // strip 0: exp2 + cvt_pk pack into per-wave P buf, then read pa0
        char* Pb = P_sh[w];
        bf16x8 pa0[2], pa1[2];
        {
            float rs = 0.f;
            #pragma unroll
            for (int mt = 0; mt < 4; ++mt) {
                float e0 = __builtin_amdgcn_exp2f(sa[0][mt][0] - m_run[0]);
                float e1 = __builtin_amdgcn_exp2f(sa[0][mt][1] - m_run[0]);
                float e2 = __builtin_amdgcn_exp2f(sa[0][mt][2] - m_run[0]);
                float e3 = __builtin_amdgcn_exp2f(sa[0][mt][3] - m_run[0]);
                rs += (e0 + e1) + (e2 + e3);
                u32x2 pk = {cvt_pk_bf16(e0, e1), cvt_pk_bf16(e2, e3)};
                *(u32x2*)(Pb + lr * 128 + ((mt * 32 + lg * 8) ^ ((lr & 7) << 4))) = pk;
            }
            l_run[0] += rs;           // per-lane partial; reduced after loop
        }
        asm volatile("" ::: "memory");
        #pragma unroll
        for (int kf = 0; kf < 2; ++kf)
            pa0[kf] = *(const bf16x8*)(Pb + lr * 128 + ((kf * 64 + lg * 16) ^ ((lr & 7) << 4)));
        asm volatile("" ::: "memory");

        // strip 1: overwrite same P buf (same-wave DS is in-order; fenced)
        {
            float rs = 0.f;
            #pragma unroll
            for (int mt = 0; mt < 4; ++mt) {
                float e0 = __builtin_amdgcn_exp2f(sa[1][mt][0] - m_run[1]);
                float e1 = __builtin_amdgcn_exp2f(sa[1][mt][1] - m_run[1]);
                float e2 = __builtin_amdgcn_exp2f(sa[1][mt][2] - m_run[1]);
                float e3 = __builtin_amdgcn_exp2f(sa[1][mt][3] - m_run[1]);
                rs += (e0 + e1) + (e2 + e3);
                u32x2 pk = {cvt_pk_bf16(e0, e1), cvt_pk_bf16(e2, e3)};
                *(u32x2*)(Pb + lr * 128 + ((mt * 32 + lg * 8) ^ ((lr & 7) << 4))) = pk;
            }
            l_run[1] += rs;
        }
        asm volatile("" ::: "memory");
        #pragma unroll
        for (int kf = 0; kf < 2; ++kf)
            pa1[kf] = *(const bf16x8*)(Pb + lr * 128 + ((kf * 64 + lg * 16) ^ ((lr & 7) << 4)));

        // Y += P V  (all operands in registers)
        __builtin_amdgcn_s_setprio(1);
        #pragma unroll
        for (int kf = 0; kf < 2; ++kf)
            #pragma unroll
            for (int ct = 0; ct < 8; ++ct) {
                yacc[0][ct] = __builtin_amdgcn_mfma_f32_16x16x32_bf16(pa0[kf], vf[kf][ct], yacc[0][ct], 0, 0, 0);
                yacc[1][ct] = __builtin_amdgcn_mfma_f32_16x16x32_bf16(pa1[kf], vf[kf][ct], yacc[1][ct], 0, 0, 0);
            }
        __builtin_amdgcn_s_setprio(0);

        __syncthreads();   // drains vmcnt: next tile staged; buf[cur] reads done
    }

    // reduce l across the 4 lane-groups (deferred from the loop)
    #pragma unroll
    for (int s = 0; s < 2; ++s) {
        float lt = l_run[s];
        lt += __shfl_xor(lt, 16);
        lt += __shfl_xor(lt, 32);
        l_run[s] = lt;
    }

    // store UNNORMALIZED partial Yhat (bf16) + (m,l) per q-row
    short* yb = yh + ((size_t)half * BB + b) * NN * (size_t)CI;
    #pragma unroll
    for (int s = 0; s < 2; ++s) {
        #pragma unroll
        for (int rr = 0; rr < 4; ++rr) {
            int n = n0 + w * 32 + s * 16 + lg * 4 + rr;
            #pragma unroll
            for (int ct = 0; ct < 8; ++ct)
                yb[(size_t)n * CI + ct * 16 + lr] = f2bf(yacc[s][ct][rr]);
        }
    }
    if (lg == 0) {
        #pragma unroll
        for (int s = 0; s < 2; ++s) {
            int n = n0 + w * 32 + s * 16 + lr;
            f32x2 v = {m_run[s], l_run[s]};
            *(f32x2*)&ml[(((size_t)half * BB + b) * NN + n) * 2] = v;
        }
    }
}

// ---------------------------------------------------------------------------
// Kernel 2b: merge the two KV-half bf16 partials -> normalized Y^T bf16
// ---------------------------------------------------------------------------
__global__ __launch_bounds__(256) void merge_kernel(
    const short* __restrict__ yh, const float* __restrict__ ml,
    short* __restrict__ yp)
{
    const int tid = threadIdx.x;
    const int row = blockIdx.x * 8 + (tid >> 5);    // (b*NN + n) in [0, BB*NN)
    const int c4  = (tid & 31) * 4;
    const size_t H = (size_t)BB * NN * CI;          // half stride in yh
    const size_t R = (size_t)BB * NN * 2;           // half stride in ml

    float m0 = ml[(size_t)row * 2],     l0 = ml[(size_t)row * 2 + 1];
    float m1 = ml[R + (size_t)row * 2], l1 = ml[R + (size_t)row * 2 + 1];
    float mm = fmaxf(m0, m1);
    float w0 = __builtin_amdgcn_exp2f(m0 - mm);
    float w1 = __builtin_amdgcn_exp2f(m1 - mm);
    float inv = 1.0f / (l0 * w0 + l1 * w1);
    w0 *= inv; w1 *= inv;

    bf16x4 a  = *(const bf16x4*)&yh[(size_t)row * CI + c4];
    bf16x4 bb = *(const bf16x4*)&yh[H + (size_t)row * CI + c4];
    bf16x4 o;
    #pragma unroll
    for (int i = 0; i < 4; ++i) o[i] = f2bf(bf2f(a[i]) * w0 + bf2f(bb[i]) * w1);
    *(bf16x4*)&yp[(size_t)row * CI + c4] = o;
}

// ---------------------------------------------------------------------------
// Kernel 3: out = w_w @ Y + b_w + x.  M=o (coalesced n-stores), 128x128 tiles.
// XCD-pinned: b = blockIdx & 7.
// ---------------------------------------------------------------------------
__global__ __launch_bounds__(256) void out_kernel(
    const short* __restrict__ yp, const float* __restrict__ ww,
    const float* __restrict__ bw, const float* __restrict__ x,
    float* __restrict__ out)
{
    __shared__ __align__(16) short A_lds[128][136];   // w_w [o][c]
    __shared__ __align__(16) short Bl[128][136];      // Y^T [n][c]

    const int tid  = threadIdx.x;
    const int b    = blockIdx.x & 7;          // batch == XCD
    const int rest = blockIdx.x >> 3;         // 0..63
    const int ob   = rest & 1;
    const int nn   = (rest >> 1) * 128;
    const int o0   = ob * 128;
    const int w = tid >> 6, lane = tid & 63, lr = lane & 15, lg = lane >> 4;

    #pragma unroll
    for (int pass = 0; pass < 8; ++pass) {
        int o  = pass * 16 + (tid >> 4);
        int c8 = (tid & 15) * 8;
        f32x4 v0 = *(const f32x4*)&ww[(size_t)(o0 + o) * CI + c8];
        f32x4 v1 = *(const f32x4*)&ww[(size_t)(o0 + o) * CI + c8 + 4];
        bf16x8 bv;
        #pragma unroll
        for (int i = 0; i < 4; ++i) { bv[i] = f2bf(v0[i]); bv[4 + i] = f2bf(v1[i]); }
        *(bf16x8*)&A_lds[o][c8] = bv;
    }
    #pragma unroll
    for (int pass = 0; pass < 8; ++pass) {
        int n  = pass * 16 + (tid >> 4);
        int c8 = (tid & 15) * 8;
        *(bf16x8*)&Bl[n][c8] = *(const bf16x8*)&yp[((size_t)b * NN + nn + n) * CI + c8];
    }
    __syncthreads();

    f32x4 acc[2][8];
    #pragma unroll
    for (int i = 0; i < 2; ++i)
        #pragma unroll
        for (int j = 0; j < 8; ++j) acc[i][j] = (f32x4){0.f, 0.f, 0.f, 0.f};

    #pragma unroll
    for (int kf = 0; kf < 4; ++kf) {
        bf16x8 a0 = *(const bf16x8*)&A_lds[w * 32 + lr][kf * 32 + lg * 8];
        bf16x8 a1 = *(const bf16x8*)&A_lds[w * 32 + 16 + lr][kf * 32 + lg * 8];
        #pragma unroll
        for (int nt = 0; nt < 8; ++nt) {
            bf16x8 bv = *(const bf16x8*)&Bl[nt * 16 + lr][kf * 32 + lg * 8];
            acc[0][nt] = __builtin_amdgcn_mfma_f32_16x16x32_bf16(a0, bv, acc[0][nt], 0, 0, 0);
            acc[1][nt] = __builtin_amdgcn_mfma_f32_16x16x32_bf16(a1, bv, acc[1][nt], 0, 0, 0);
        }
    }

    #pragma unroll
    for (int wo = 0; wo < 2; ++wo) {
        #pragma unroll
        for (int rr = 0; rr < 4; ++rr) {
            int o = o0 + w * 32 + wo * 16 + lg * 4 + rr;
            float bias = bw[o];
            #pragma unroll
            for (int nt = 0; nt < 8; ++nt) {
                size_t idx = ((size_t)b * CIN + o) * NN + nn + nt * 16 + lr;
                out[idx] = acc[wo][nt][rr] + bias + x[idx];
            }
        }
    }
}

// ---------------------------------------------------------------------------
extern "C" void kernel_launch(void* const* d_in, const int* in_sizes, int n_in,
                              void* d_out, int out_size, void* d_ws, size_t ws_size,
                              hipStream_t stream)
{
    const float* x     = (const float*)d_in[0];
    const float* gamma = (const float*)d_in[1];
    const float* beta  = (const float*)d_in[2];
    const float* mean  = (const float*)d_in[3];
    const float* var   = (const float*)d_in[4];
    const float* wg    = (const float*)d_in[5];
    const float* bg    = (const float*)d_in[6];
    const float* wth   = (const float*)d_in[7];
    const float* bth   = (const float*)d_in[8];
    const float* wph   = (const float*)d_in[9];
    const float* bph   = (const float*)d_in[10];
    const float* ww    = (const float*)d_in[11];
    const float* bw    = (const float*)d_in[12];

    // ws layout: qp 8MB | kp 8MB | vtp 8MB | ml 0.5MB  (yp aliases qp after attn)
    // d_out (32MB) doubles as bf16 Yhat partial scratch (2 x 8MB) between
    // attn and merge; out_kernel then overwrites d_out fully.
    const size_t seg = (size_t)BB * NN * CI;
    short* qp  = (short*)d_ws;
    short* kp  = qp + seg;
    short* vtp = kp + seg;
    float* ml  = (float*)(vtp + seg);
    short* yp  = qp;                       // reuse: q dead after attn
    short* yh  = (short*)d_out;            // [2][B][N][CI] bf16 partials
    (void)in_sizes; (void)n_in; (void)out_size; (void)ws_size;

    proj_kernel<<<BB * (NN / 64), 256, 0, stream>>>(
        x, gamma, beta, mean, var, wg, bg, wth, bth, wph, bph, qp, kp, vtp);
    attn_kernel<<<2 * BB * (NN / 128), 256, 0, stream>>>(qp, kp, vtp, yh, ml);
    merge_kernel<<<BB * NN / 8, 256, 0, stream>>>(yh, ml, yp);
    out_kernel<<<2 * BB * (NN / 128), 256, 0, stream>>>(yp, ww, bw, x, (float*)d_out);
}

// Round 10
// 120.790 us; speedup vs baseline: 3.6849x; 1.0011x over previous
//
#include <hip/hip_runtime.h>
#include <hip/hip_bf16.h>
#include <stdint.h>

#define BB   8
#define CIN  256
#define CI   128
#define NN   4096
#define EPSV 1e-5f
#define LOG2E 1.44269504088896340736f

typedef __attribute__((ext_vector_type(8))) short bf16x8;
typedef __attribute__((ext_vector_type(4))) short bf16x4;
typedef __attribute__((ext_vector_type(4))) float f32x4;
typedef __attribute__((ext_vector_type(2))) float f32x2;
typedef __attribute__((ext_vector_type(2))) unsigned int u32x2;

static __device__ inline short f2bf(float f) {
    uint32_t u = __builtin_bit_cast(uint32_t, f);
    u += 0x7FFFu + ((u >> 16) & 1u);   // round-to-nearest-even
    return (short)(u >> 16);
}

static __device__ inline float bf2f(short s) {
    uint32_t u = ((uint32_t)(uint16_t)s) << 16;
    return __builtin_bit_cast(float, u);
}

static __device__ inline uint32_t cvt_pk_bf16(float lo, float hi) {
    uint32_t r;
    asm("v_cvt_pk_bf16_f32 %0, %1, %2" : "=v"(r) : "v"(lo), "v"(hi));
    return r;
}

// ---------------------------------------------------------------------------
// Kernel 1 (FUSED): BN + all three 1x1 projections in one pass over x.
// ---------------------------------------------------------------------------
__global__ __launch_bounds__(256, 2) void proj_kernel(
    const float* __restrict__ x,
    const float* __restrict__ gamma, const float* __restrict__ beta,
    const float* __restrict__ mean,  const float* __restrict__ var,
    const float* __restrict__ wg,  const float* __restrict__ bg,
    const float* __restrict__ wth, const float* __restrict__ bth,
    const float* __restrict__ wph, const float* __restrict__ bph,
    short* __restrict__ qp, short* __restrict__ kp, short* __restrict__ vtp)
{
    __shared__ float s_scale[CIN];
    __shared__ float s_shift[CIN];
    __shared__ __align__(16) short A_lds[64][264];   // [n][c] full K, pad 264
    __shared__ __align__(16) short B_lds[128][72];   // [o][c-chunk], reused x12

    const int tid = threadIdx.x;
    const int b   = blockIdx.x & 7;           // batch == XCD
    const int n0  = (blockIdx.x >> 3) * 64;
    const int w = tid >> 6, lane = tid & 63, lr = lane & 15, lg = lane >> 4;

    {   // BN scale/shift (256 threads == 256 channels)
        float sc = gamma[tid] * rsqrtf(var[tid] + EPSV);
        s_scale[tid] = sc;
        s_shift[tid] = beta[tid] - mean[tid] * sc;
    }
    __syncthreads();

    // stage BN(x) -> A_lds[n][c] bf16, once (16 passes)
    #pragma unroll
    for (int p = 0; p < 16; ++p) {
        int c  = p * 16 + (tid >> 4);
        int n4 = (tid & 15) * 4;
        f32x4 v = *(const f32x4*)&x[((size_t)b * CIN + c) * NN + n0 + n4];
        float sc = s_scale[c], sh = s_shift[c];
        #pragma unroll
        for (int i = 0; i < 4; ++i)
            A_lds[n4 + i][c] = f2bf(v[i] * sc + sh);
    }
    __syncthreads();

    const float* WS[3] = {wth, wph, wg};
    const float* BS[3] = {bth, bph, bg};

    #pragma unroll
    for (int s = 0; s < 3; ++s) {
        f32x4 acc[8];
        #pragma unroll
        for (int i = 0; i < 8; ++i) acc[i] = (f32x4){0.f, 0.f, 0.f, 0.f};

        for (int c0 = 0; c0 < CIN; c0 += 64) {
            // stage B chunk [o][c0..c0+63]
            #pragma unroll
            for (int p = 0; p < 8; ++p) {
                int o  = p * 16 + (tid >> 4);
                int c4 = (tid & 15) * 4;
                f32x4 v = *(const f32x4*)&WS[s][(size_t)o * CIN + c0 + c4];
                bf16x4 bv;
                #pragma unroll
                for (int i = 0; i < 4; ++i) bv[i] = f2bf(v[i]);
                *(bf16x4*)&B_lds[o][c4] = bv;
            }
            __syncthreads();

            bf16x8 a0 = *(const bf16x8*)&A_lds[w * 16 + lr][c0 + lg * 8];
            bf16x8 a1 = *(const bf16x8*)&A_lds[w * 16 + lr][c0 + 32 + lg * 8];
            #pragma unroll
            for (int ot = 0; ot < 8; ++ot) {
                bf16x8 b0 = *(const bf16x8*)&B_lds[ot * 16 + lr][lg * 8];
                bf16x8 b1 = *(const bf16x8*)&B_lds[ot * 16 + lr][32 + lg * 8];
                acc[ot] = __builtin_amdgcn_mfma_f32_16x16x32_bf16(a0, b0, acc[ot], 0, 0, 0);
                acc[ot] = __builtin_amdgcn_mfma_f32_16x16x32_bf16(a1, b1, acc[ot], 0, 0, 0);
            }
            __syncthreads();
        }

        if (s < 2) {   // Q / K: (b, n, c) row-major; Q scaled by log2e
            short* dst = (s == 0) ? qp : kp;
            const float om = (s == 0) ? LOG2E : 1.0f;
            #pragma unroll
            for (int ot = 0; ot < 8; ++ot) {
                float bias = BS[s][ot * 16 + lr];
                #pragma unroll
                for (int rr = 0; rr < 4; ++rr) {
                    int n = n0 + w * 16 + lg * 4 + rr;
                    dst[((size_t)b * NN + n) * CI + ot * 16 + lr] = f2bf((acc[ot][rr] + bias) * om);
                }
            }
        } else {       // V^T: (b, c, n)
            #pragma unroll
            for (int ot = 0; ot < 8; ++ot) {
                float bias = BS[s][ot * 16 + lr];
                bf16x4 pk;
                #pragma unroll
                for (int rr = 0; rr < 4; ++rr) pk[rr] = f2bf(acc[ot][rr] + bias);
                *(bf16x4*)&vtp[((size_t)b * CI + ot * 16 + lr) * NN + n0 + w * 16 + lg * 4] = pk;
            }
        }
    }
}

// ---------------------------------------------------------------------------
// Kernel 2: flash attention — R9 structure + strip-pipelined epilogue:
//   QK^T(both) -> sm0 -> PV0 (MFMA) -> sm1 (VALU overlaps PV0) -> PV1
// SPLIT-KV x2, 2 blk/CU, 192 regs (128 VGPR + 64 AGPR) = 2 waves/SIMD.
// Do NOT raise occupancy with this body (R6/R7/R8 lessons).
// ---------------------------------------------------------------------------
__global__ __launch_bounds__(256, 2) void attn_kernel(
    const short* __restrict__ qp, const short* __restrict__ kp,
    const short* __restrict__ vtp, short* __restrict__ yh,
    float* __restrict__ ml)
{
    __shared__ __align__(16) char K_sh[2][64 * 256];    // [m][c] swizzled, 16KB x2
    __shared__ __align__(16) char V_sh[2][128 * 128];   // [c][m] swizzled, 16KB x2
    __shared__ __align__(16) char P_sh[4][16 * 128];    // per-wave single P buf

    const int tid  = threadIdx.x;
    const int b    = blockIdx.x & 7;            // batch == XCD (round-robin)
    const int half = (blockIdx.x >> 3) & 1;     // kv half
    const int n0   = (blockIdx.x >> 4) * 128;
    const int w = tid >> 6, lane = tid & 63, lr = lane & 15, lg = lane >> 4;
    const int NT = NN / 128;                    // 32 kv tiles per half
    const int t0 = half * NT;

    // loop-carried per-lane global source pointers (pre-swizzled), LDS dest linear
    const char* kgp[4];
    const char* vgp[4];
    #pragma unroll
    for (int r = 0; r < 4; ++r) {
        int idx = ((r * 4 + w) << 6) + lane;          // 16B-chunk index 0..1023
        int mm  = idx >> 4, cb = (idx & 15) << 4;     // K: row m, dest col-byte
        kgp[r] = (const char*)(kp + (size_t)b * NN * CI + (size_t)t0 * 64 * CI
                               + (size_t)mm * CI) + (cb ^ ((mm & 7) << 4));
        int cc = idx >> 3, cbv = (idx & 7) << 4;      // V: row c, dest col-byte
        vgp[r] = (const char*)(vtp + (size_t)b * CI * NN + (size_t)t0 * 64
                               + (size_t)cc * NN) + (cbv ^ ((cc & 7) << 4));
    }
    auto stage = [&](int bufi) {
        #pragma unroll
        for (int r = 0; r < 4; ++r) {
            __builtin_amdgcn_global_load_lds(
                (const __attribute__((address_space(1))) void*)kgp[r],
                (__attribute__((address_space(3))) void*)&K_sh[bufi][(r * 4 + w) << 10],
                16, 0, 0);
            __builtin_amdgcn_global_load_lds(
                (const __attribute__((address_space(1))) void*)vgp[r],
                (__attribute__((address_space(3))) void*)&V_sh[bufi][(r * 4 + w) << 10],
                16, 0, 0);
            kgp[r] += 64 * CI * 2;    // next K tile: 16 KB
            vgp[r] += 64 * 2;         // next V tile: 128 B
        }
    };

    // Q strips in registers (B-frag for mfma(K,Q): col=q=lr, k contiguous)
    bf16x8 qf[2][4];
    #pragma unroll
    for (int s = 0; s < 2; ++s) {
        const short* qrow = qp + ((size_t)b * NN + n0 + w * 32 + s * 16 + lr) * CI;
        #pragma unroll
        for (int kf = 0; kf < 4; ++kf)
            qf[s][kf] = *(const bf16x8*)&qrow[kf * 32 + lg * 8];
    }

    f32x4 yacc[2][8];
    #pragma unroll
    for (int s = 0; s < 2; ++s)
        #pragma unroll
        for (int i = 0; i < 8; ++i) yacc[s][i] = (f32x4){0.f, 0.f, 0.f, 0.f};
    float m_run[2] = {-__builtin_huge_valf(), -__builtin_huge_valf()};
    float l_run[2] = {0.f, 0.f};   // per-lane partials; reduced after the loop

    stage(0);
    __syncthreads();

    for (int t = 0; t < NT; ++t) {
        const int cur = t & 1;
        if (t + 1 < NT) stage(cur ^ 1);   // issue before compute

        // S^T = K Q : lane (lr,lg) holds S[q=lr][m=mt*16+lg*4+rr] per strip
        const char* Kc = K_sh[cur];
        f32x4 sa[2][4];
        __builtin_amdgcn_s_setprio(1);
        #pragma unroll
        for (int mt = 0; mt < 4; ++mt) {
            const int mrow = mt * 16 + lr;
            const int sw   = (mrow & 7) << 4;
            sa[0][mt] = (f32x4){0.f, 0.f, 0.f, 0.f};
            sa[1][mt] = (f32x4){0.f, 0.f, 0.f, 0.f};
            #pragma unroll
            for (int kf = 0; kf < 4; ++kf) {
                bf16x8 kfrag = *(const bf16x8*)(Kc + (mrow << 8) + ((kf * 64 + lg * 16) ^ sw));
                sa[0][mt] = __builtin_amdgcn_mfma_f32_16x16x32_bf16(kfrag, qf[0][kf], sa[0][mt], 0, 0, 0);
                sa[1][mt] = __builtin_amdgcn_mfma_f32_16x16x32_bf16(kfrag, qf[1][kf], sa[1][mt], 0, 0, 0);
            }
        }
        __builtin_amdgcn_s_setprio(0);

        // lazy online softmax: per-lane partial max only on the common path
        float tml[2];
        #pragma unroll
        for (int s = 0; s < 2; ++s) {
            float tm = fmaxf(fmaxf(fmaxf(sa[s][0][0], sa[s][0][1]), fmaxf(sa[s][0][2], sa[s][0][3])),
                             fmaxf(fmaxf(sa[s][1][0], sa[s][1][1]), fmaxf(sa[s][1][2], sa[s][1][3])));
            tm = fmaxf(tm, fmaxf(fmaxf(fmaxf(sa[s][2][0], sa[s][2][1]), fmaxf(sa[s][2][2], sa[s][2][3])),
                                 fmaxf(fmaxf(sa[s][3][0], sa[s][3][1]), fmaxf(sa[s][3][2], sa[s][3][3]))));
            tml[s] = tm;
        }
        if (__any((tml[0] - m_run[0] > 8.f) || (tml[1] - m_run[1] > 8.f))) {
            #pragma unroll
            for (int s = 0; s < 2; ++s) {
                float tm = tml[s];
                tm = fmaxf(tm, __shfl_xor(tm, 16));
                tm = fmaxf(tm, __shfl_xor(tm, 32));
                float mnew = fmaxf(m_run[s], tm);
                float sc   = __builtin_amdgcn_exp2f(m_run[s] - mnew);
                m_run[s] = mnew;
                l_run[s] *= sc;
                #pragma unroll
                for (int rr = 0; rr < 4; ++rr) {
                    float scb = __shfl(sc, (lane & 48) | (lg * 4 + rr));
                    #pragma unroll
                    for (int ct = 0; ct < 8; ++ct) yacc[s][ct][rr] *= scb;
                }
            }
        }

        // V-frags into regs (shared by both strips)
        const char* Vc = V_sh[cur];
        bf16x8 vf[2][8];
        #pragma unroll
        for (int kf = 0; kf < 2; ++kf)
            #pragma unroll
            for (int ct = 0; ct < 8; ++ct) {
                const int vr = ct * 16 + lr;
                vf[kf][ct] = *(const bf16x8*)(Vc + (vr << 7) +
                                              ((kf * 64 + lg * 16) ^ ((vr & 7) << 4)));
            }

        char* Pb = P_sh[w];
        const int psw = (lr & 7) << 4;

        // ---- strip 0 softmax -> pa0 ----
        bf16x8 pa0[2];
        {
            float rs = 0.f;
            #pragma unroll
            for (int mt = 0; mt < 4; ++mt) {
                float e0 = __builtin_amdgcn_exp2f(sa[0][mt][0] - m_run[0]);
                float e1 = __builtin_amdgcn_exp2f(sa[0][mt][1] - m_run[0]);
                float e2 = __builtin_amdgcn_exp2f(sa[0][mt][2] - m_run[0]);
                float e3 = __builtin_amdgcn_exp2f(sa[0][mt][3] - m_run[0]);
                rs += (e0 + e1) + (e2 + e3);
                u32x2 pk = {cvt_pk_bf16(e0, e1), cvt_pk_bf16(e2, e3)};
                *(u32x2*)(Pb + lr * 128 + ((mt * 32 + lg * 8) ^ psw)) = pk;
            }
            l_run[0] += rs;
        }
        asm volatile("" ::: "memory");
        #pragma unroll
        for (int kf = 0; kf < 2; ++kf)
            pa0[kf] = *(const bf16x8*)(Pb + lr * 128 + ((kf * 64 + lg * 16) ^ psw));
        asm volatile("" ::: "memory");

        // ---- PV strip 0 (MFMA pipe; strip-1 softmax VALU overlaps below) ----
        __builtin_amdgcn_s_setprio(1);
        #pragma unroll
        for (int kf = 0; kf < 2; ++kf)
            #pragma unroll
            for (int ct = 0; ct < 8; ++ct)
                yacc[0][ct] = __builtin_amdgcn_mfma_f32_16x16x32_bf16(pa0[kf], vf[kf][ct], yacc[0][ct], 0, 0, 0);
        __builtin_amdgcn_s_setprio(0);

        // ---- strip 1 softmax (overwrites same P buf; same-wave DS in-order) --
        bf16x8 pa1[2];
        {
            float rs = 0.f;
            #pragma unroll
            for (int mt = 0; mt < 4; ++mt) {
                float e0 = __builtin_amdgcn_exp2f(sa[1][mt][0] - m_run[1]);
                float e1 = __builtin_amdgcn_exp2f(sa[1][mt][1] - m_run[1]);
                float e2 = __builtin_amdgcn_exp2f(sa[1][mt][2] - m_run[1]);
                float e3 = __builtin_amdgcn_exp2f(sa[1][mt][3] - m_run[1]);
                rs += (e0 + e1) + (e2 + e3);
                u32x2 pk = {cvt_pk_bf16(e0, e1), cvt_pk_bf16(e2, e3)};
                *(u32x2*)(Pb + lr * 128 + ((mt * 32 + lg * 8) ^ psw)) = pk;
            }
            l_run[1] += rs;
        }
        asm volatile("" ::: "memory");
        #pragma unroll
        for (int kf = 0; kf < 2; ++kf)
            pa1[kf] = *(const bf16x8*)(Pb + lr * 128 + ((kf * 64 + lg * 16) ^ psw));

        // ---- PV strip 1 ----
        __builtin_amdgcn_s_setprio(1);
        #pragma unroll
        for (int kf = 0; kf < 2; ++kf)
            #pragma unroll
            for (int ct = 0; ct < 8; ++ct)
                yacc[1][ct] = __builtin_amdgcn_mfma_f32_16x16x32_bf16(pa1[kf], vf[kf][ct], yacc[1][ct], 0, 0, 0);
        __builtin_amdgcn_s_setprio(0);

        __syncthreads();   // drains vmcnt: next tile staged; buf[cur] reads done
    }

    // reduce l across the 4 lane-groups (deferred from the loop)
    #pragma unroll
    for (int s = 0; s < 2; ++s) {
        float lt = l_run[s];
        lt += __shfl_xor(lt, 16);
        lt += __shfl_xor(lt, 32);
        l_run[s] = lt;
    }

    // store UNNORMALIZED partial Yhat (bf16) + (m,l) per q-row
    short* yb = yh + ((size_t)half * BB + b) * NN * (size_t)CI;
    #pragma unroll
    for (int s = 0; s < 2; ++s) {
        #pragma unroll
        for (int rr = 0; rr < 4; ++rr) {
            int n = n0 + w * 32 + s * 16 + lg * 4 + rr;
            #pragma unroll
            for (int ct = 0; ct < 8; ++ct)
                yb[(size_t)n * CI + ct * 16 + lr] = f2bf(yacc[s][ct][rr]);
        }
    }
    if (lg == 0) {
        #pragma unroll
        for (int s = 0; s < 2; ++s) {
            int n = n0 + w * 32 + s * 16 + lr;
            f32x2 v = {m_run[s], l_run[s]};
            *(f32x2*)&ml[(((size_t)half * BB + b) * NN + n) * 2] = v;
        }
    }
}

// ---------------------------------------------------------------------------
// Kernel 2b (fallback path): merge the two KV-half partials -> Y^T bf16
// ---------------------------------------------------------------------------
__global__ __launch_bounds__(256) void merge_kernel(
    const short* __restrict__ yh, const float* __restrict__ ml,
    short* __restrict__ yp)
{
    const int tid = threadIdx.x;
    const int row = blockIdx.x * 8 + (tid >> 5);    // (b*NN + n) in [0, BB*NN)
    const int c4  = (tid & 31) * 4;
    const size_t H = (size_t)BB * NN * CI;          // half stride in yh
    const size_t R = (size_t)BB * NN * 2;           // half stride in ml

    float m0 = ml[(size_t)row * 2],     l0 = ml[(size_t)row * 2 + 1];
    float m1 = ml[R + (size_t)row * 2], l1 = ml[R + (size_t)row * 2 + 1];
    float mm = fmaxf(m0, m1);
    float w0 = __builtin_amdgcn_exp2f(m0 - mm);
    float w1 = __builtin_amdgcn_exp2f(m1 - mm);
    float inv = 1.0f / (l0 * w0 + l1 * w1);
    w0 *= inv; w1 *= inv;

    bf16x4 a  = *(const bf16x4*)&yh[(size_t)row * CI + c4];
    bf16x4 bb = *(const bf16x4*)&yh[H + (size_t)row * CI + c4];
    bf16x4 o;
    #pragma unroll
    for (int i = 0; i < 4; ++i) o[i] = f2bf(bf2f(a[i]) * w0 + bf2f(bb[i]) * w1);
    *(bf16x4*)&yp[(size_t)row * CI + c4] = o;
}

// ---------------------------------------------------------------------------
// Kernel 3: out = w_w @ Y + b_w + x, 128x128 tiles, XCD-pinned.
// MERGED==1: stage Y by combining the two partials with ml weights (no merge
// kernel; yh must NOT alias d_out). MERGED==0: read pre-merged yp.
// ---------------------------------------------------------------------------
template <int MERGED>
__global__ __launch_bounds__(256) void out_kernel(
    const short* __restrict__ ysrc, const float* __restrict__ ml,
    const float* __restrict__ ww, const float* __restrict__ bw,
    const float* __restrict__ x, float* __restrict__ out)
{
    __shared__ __align__(16) short A_lds[128][136];   // w_w [o][c]
    __shared__ __align__(16) short Bl[128][136];      // Y^T [n][c]

    const int tid  = threadIdx.x;
    const int b    = blockIdx.x & 7;          // batch == XCD
    const int rest = blockIdx.x >> 3;         // 0..63
    const int ob   = rest & 1;
    const int nn   = (rest >> 1) * 128;
    const int o0   = ob * 128;
    const int w = tid >> 6, lane = tid & 63, lr = lane & 15, lg = lane >> 4;

    #pragma unroll
    for (int pass = 0; pass < 8; ++pass) {
        int o  = pass * 16 + (tid >> 4);
        int c8 = (tid & 15) * 8;
        f32x4 v0 = *(const f32x4*)&ww[(size_t)(o0 + o) * CI + c8];
        f32x4 v1 = *(const f32x4*)&ww[(size_t)(o0 + o) * CI + c8 + 4];
        bf16x8 bv;
        #pragma unroll
        for (int i = 0; i < 4; ++i) { bv[i] = f2bf(v0[i]); bv[4 + i] = f2bf(v1[i]); }
        *(bf16x8*)&A_lds[o][c8] = bv;
    }
    #pragma unroll
    for (int pass = 0; pass < 8; ++pass) {
        int n  = pass * 16 + (tid >> 4);
        int c8 = (tid & 15) * 8;
        size_t row = (size_t)b * NN + nn + n;
        if (MERGED) {
            *(bf16x8*)&Bl[n][c8] = *(const bf16x8*)&ysrc[row * CI + c8];
        } else {
            const size_t H = (size_t)BB * NN * CI;
            const size_t R = (size_t)BB * NN * 2;
            f32x2 v0 = *(const f32x2*)&ml[row * 2];
            f32x2 v1 = *(const f32x2*)&ml[R + row * 2];
            float mm = fmaxf(v0[0], v1[0]);
            float w0 = __builtin_amdgcn_exp2f(v0[0] - mm);
            float w1 = __builtin_amdgcn_exp2f(v1[0] - mm);
            float inv = 1.0f / (v0[1] * w0 + v1[1] * w1);
            w0 *= inv; w1 *= inv;
            bf16x8 a  = *(const bf16x8*)&ysrc[row * CI + c8];
            bf16x8 b2 = *(const bf16x8*)&ysrc[H + row * CI + c8];
            bf16x8 ov;
            #pragma unroll
            for (int i = 0; i < 4; ++i) {
                float lo = bf2f(a[2*i]) * w0 + bf2f(b2[2*i]) * w1;
                float hi = bf2f(a[2*i+1]) * w0 + bf2f(b2[2*i+1]) * w1;
                uint32_t pk = cvt_pk_bf16(lo, hi);
                ov[2*i]   = (short)(pk & 0xFFFF);
                ov[2*i+1] = (short)(pk >> 16);
            }
            *(bf16x8*)&Bl[n][c8] = ov;
        }
    }
    __syncthreads();

    f32x4 acc[2][8];
    #pragma unroll
    for (int i = 0; i < 2; ++i)
        #pragma unroll
        for (int j = 0; j < 8; ++j) acc[i][j] = (f32x4){0.f, 0.f, 0.f, 0.f};

    #pragma unroll
    for (int kf = 0; kf < 4; ++kf) {
        bf16x8 a0 = *(const bf16x8*)&A_lds[w * 32 + lr][kf * 32 + lg * 8];
        bf16x8 a1 = *(const bf16x8*)&A_lds[w * 32 + 16 + lr][kf * 32 + lg * 8];
        #pragma unroll
        for (int nt = 0; nt < 8; ++nt) {
            bf16x8 bv = *(const bf16x8*)&Bl[nt * 16 + lr][kf * 32 + lg * 8];
            acc[0][nt] = __builtin_amdgcn_mfma_f32_16x16x32_bf16(a0, bv, acc[0][nt], 0, 0, 0);
            acc[1][nt] = __builtin_amdgcn_mfma_f32_16x16x32_bf16(a1, bv, acc[1][nt], 0, 0, 0);
        }
    }

    #pragma unroll
    for (int wo = 0; wo < 2; ++wo) {
        #pragma unroll
        for (int rr = 0; rr < 4; ++rr) {
            int o = o0 + w * 32 + wo * 16 + lg * 4 + rr;
            float bias = bw[o];
            #pragma unroll
            for (int nt = 0; nt < 8; ++nt) {
                size_t idx = ((size_t)b * CIN + o) * NN + nn + nt * 16 + lr;
                out[idx] = acc[wo][nt][rr] + bias + x[idx];
            }
        }
    }
}

// ---------------------------------------------------------------------------
extern "C" void kernel_launch(void* const* d_in, const int* in_sizes, int n_in,
                              void* d_out, int out_size, void* d_ws, size_t ws_size,
                              hipStream_t stream)
{
    const float* x     = (const float*)d_in[0];
    const float* gamma = (const float*)d_in[1];
    const float* beta  = (const float*)d_in[2];
    const float* mean  = (const float*)d_in[3];
    const float* var   = (const float*)d_in[4];
    const float* wg    = (const float*)d_in[5];
    const float* bg    = (const float*)d_in[6];
    const float* wth   = (const float*)d_in[7];
    const float* bth   = (const float*)d_in[8];
    const float* wph   = (const float*)d_in[9];
    const float* bph   = (const float*)d_in[10];
    const float* ww    = (const float*)d_in[11];
    const float* bw    = (const float*)d_in[12];

    // ws layout: qp 8MB | kp 8MB | vtp 8MB | ml 0.5MB | [yh 16MB if room]
    // Preferred: yh lives in ws -> out_kernel<0> fuses the merge (reads yh
    // while writing d_out). Fallback (small ws): yh in d_out + merge kernel.
    const size_t seg = (size_t)BB * NN * CI;
    short* qp  = (short*)d_ws;
    short* kp  = qp + seg;
    short* vtp = kp + seg;
    float* ml  = (float*)(vtp + seg);
    const size_t yh_off = 25u * 1024 * 1024;
    const bool fused = ws_size >= yh_off + 2 * seg * sizeof(short);
    short* yh = fused ? (short*)((char*)d_ws + yh_off) : (short*)d_out;
    (void)in_sizes; (void)n_in; (void)out_size;

    proj_kernel<<<BB * (NN / 64), 256, 0, stream>>>(
        x, gamma, beta, mean, var, wg, bg, wth, bth, wph, bph, qp, kp, vtp);
    attn_kernel<<<2 * BB * (NN / 128), 256, 0, stream>>>(qp, kp, vtp, yh, ml);
    if (fused) {
        out_kernel<0><<<2 * BB * (NN / 128), 256, 0, stream>>>(
            yh, ml, ww, bw, x, (float*)d_out);
    } else {
        short* yp = qp;   // reuse: q dead after attn
        merge_kernel<<<BB * NN / 8, 256, 0, stream>>>(yh, ml, yp);
        out_kernel<1><<<2 * BB * (NN / 128), 256, 0, stream>>>(
            yp, ml, ww, bw, x, (float*)d_out);
    }
}

// Round 11
// 117.574 us; speedup vs baseline: 3.7857x; 1.0274x over previous
//
#include <hip/hip_runtime.h>
#include <hip/hip_bf16.h>
#include <stdint.h>

#define BB   8
#define CIN  256
#define CI   128
#define NN   4096
#define EPSV 1e-5f
#define LOG2E 1.44269504088896340736f

typedef __attribute__((ext_vector_type(8))) short bf16x8;
typedef __attribute__((ext_vector_type(4))) short bf16x4;
typedef __attribute__((ext_vector_type(4))) float f32x4;
typedef __attribute__((ext_vector_type(2))) float f32x2;
typedef __attribute__((ext_vector_type(2))) unsigned int u32x2;

static __device__ inline short f2bf(float f) {
    uint32_t u = __builtin_bit_cast(uint32_t, f);
    u += 0x7FFFu + ((u >> 16) & 1u);   // round-to-nearest-even
    return (short)(u >> 16);
}

static __device__ inline float bf2f(short s) {
    uint32_t u = ((uint32_t)(uint16_t)s) << 16;
    return __builtin_bit_cast(float, u);
}

static __device__ inline uint32_t cvt_pk_bf16(float lo, float hi) {
    uint32_t r;
    asm("v_cvt_pk_bf16_f32 %0, %1, %2" : "=v"(r) : "v"(lo), "v"(hi));
    return r;
}

// ---------------------------------------------------------------------------
// Kernel 1 (FUSED): BN + all three 1x1 projections in one pass over x.
// ---------------------------------------------------------------------------
__global__ __launch_bounds__(256, 2) void proj_kernel(
    const float* __restrict__ x,
    const float* __restrict__ gamma, const float* __restrict__ beta,
    const float* __restrict__ mean,  const float* __restrict__ var,
    const float* __restrict__ wg,  const float* __restrict__ bg,
    const float* __restrict__ wth, const float* __restrict__ bth,
    const float* __restrict__ wph, const float* __restrict__ bph,
    short* __restrict__ qp, short* __restrict__ kp, short* __restrict__ vtp)
{
    __shared__ float s_scale[CIN];
    __shared__ float s_shift[CIN];
    __shared__ __align__(16) short A_lds[64][264];   // [n][c] full K, pad 264
    __shared__ __align__(16) short B_lds[128][72];   // [o][c-chunk], reused x12

    const int tid = threadIdx.x;
    const int b   = blockIdx.x & 7;           // batch == XCD
    const int n0  = (blockIdx.x >> 3) * 64;
    const int w = tid >> 6, lane = tid & 63, lr = lane & 15, lg = lane >> 4;

    {   // BN scale/shift (256 threads == 256 channels)
        float sc = gamma[tid] * rsqrtf(var[tid] + EPSV);
        s_scale[tid] = sc;
        s_shift[tid] = beta[tid] - mean[tid] * sc;
    }
    __syncthreads();

    // stage BN(x) -> A_lds[n][c] bf16, once (16 passes)
    #pragma unroll
    for (int p = 0; p < 16; ++p) {
        int c  = p * 16 + (tid >> 4);
        int n4 = (tid & 15) * 4;
        f32x4 v = *(const f32x4*)&x[((size_t)b * CIN + c) * NN + n0 + n4];
        float sc = s_scale[c], sh = s_shift[c];
        #pragma unroll
        for (int i = 0; i < 4; ++i)
            A_lds[n4 + i][c] = f2bf(v[i] * sc + sh);
    }
    __syncthreads();

    const float* WS[3] = {wth, wph, wg};
    const float* BS[3] = {bth, bph, bg};

    #pragma unroll
    for (int s = 0; s < 3; ++s) {
        f32x4 acc[8];
        #pragma unroll
        for (int i = 0; i < 8; ++i) acc[i] = (f32x4){0.f, 0.f, 0.f, 0.f};

        for (int c0 = 0; c0 < CIN; c0 += 64) {
            // stage B chunk [o][c0..c0+63]
            #pragma unroll
            for (int p = 0; p < 8; ++p) {
                int o  = p * 16 + (tid >> 4);
                int c4 = (tid & 15) * 4;
                f32x4 v = *(const f32x4*)&WS[s][(size_t)o * CIN + c0 + c4];
                bf16x4 bv;
                #pragma unroll
                for (int i = 0; i < 4; ++i) bv[i] = f2bf(v[i]);
                *(bf16x4*)&B_lds[o][c4] = bv;
            }
            __syncthreads();

            bf16x8 a0 = *(const bf16x8*)&A_lds[w * 16 + lr][c0 + lg * 8];
            bf16x8 a1 = *(const bf16x8*)&A_lds[w * 16 + lr][c0 + 32 + lg * 8];
            #pragma unroll
            for (int ot = 0; ot < 8; ++ot) {
                bf16x8 b0 = *(const bf16x8*)&B_lds[ot * 16 + lr][lg * 8];
                bf16x8 b1 = *(const bf16x8*)&B_lds[ot * 16 + lr][32 + lg * 8];
                acc[ot] = __builtin_amdgcn_mfma_f32_16x16x32_bf16(a0, b0, acc[ot], 0, 0, 0);
                acc[ot] = __builtin_amdgcn_mfma_f32_16x16x32_bf16(a1, b1, acc[ot], 0, 0, 0);
            }
            __syncthreads();
        }

        if (s < 2) {   // Q / K: (b, n, c) row-major; Q scaled by log2e
            short* dst = (s == 0) ? qp : kp;
            const float om = (s == 0) ? LOG2E : 1.0f;
            #pragma unroll
            for (int ot = 0; ot < 8; ++ot) {
                float bias = BS[s][ot * 16 + lr];
                #pragma unroll
                for (int rr = 0; rr < 4; ++rr) {
                    int n = n0 + w * 16 + lg * 4 + rr;
                    dst[((size_t)b * NN + n) * CI + ot * 16 + lr] = f2bf((acc[ot][rr] + bias) * om);
                }
            }
        } else {       // V^T: (b, c, n)
            #pragma unroll
            for (int ot = 0; ot < 8; ++ot) {
                float bias = BS[s][ot * 16 + lr];
                bf16x4 pk;
                #pragma unroll
                for (int rr = 0; rr < 4; ++rr) pk[rr] = f2bf(acc[ot][rr] + bias);
                *(bf16x4*)&vtp[((size_t)b * CI + ot * 16 + lr) * NN + n0 + w * 16 + lg * 4] = pk;
            }
        }
    }
}

// ---------------------------------------------------------------------------
// Kernel 2: flash attention — exact R9 structure (86.5us proven).
// SPLIT-KV x2, grid 512 = 8 batch x 2 half x 32 q-tiles -> 2 blk/CU.
// 4 waves x 2 Q-strips; K/V double-buffered via global_load_lds (pre-swizzled
// source, linear LDS dest); 1 barrier/iter; sm0->sm1 then one PV MFMA cluster.
// 192 regs (128 VGPR + 64 AGPR) = 2 waves/SIMD. Do NOT raise occupancy
// (R6/R7/R8) and do NOT split the PV cluster (R10 regression).
// ---------------------------------------------------------------------------
__global__ __launch_bounds__(256, 2) void attn_kernel(
    const short* __restrict__ qp, const short* __restrict__ kp,
    const short* __restrict__ vtp, short* __restrict__ yh,
    float* __restrict__ ml)
{
    __shared__ __align__(16) char K_sh[2][64 * 256];    // [m][c] swizzled, 16KB x2
    __shared__ __align__(16) char V_sh[2][128 * 128];   // [c][m] swizzled, 16KB x2
    __shared__ __align__(16) char P_sh[4][16 * 128];    // per-wave single P buf

    const int tid  = threadIdx.x;
    const int b    = blockIdx.x & 7;            // batch == XCD (round-robin)
    const int half = (blockIdx.x >> 3) & 1;     // kv half
    const int n0   = (blockIdx.x >> 4) * 128;
    const int w = tid >> 6, lane = tid & 63, lr = lane & 15, lg = lane >> 4;
    const int NT = NN / 128;                    // 32 kv tiles per half
    const int t0 = half * NT;

    // loop-carried per-lane global source pointers (pre-swizzled), LDS dest linear
    const char* kgp[4];
    const char* vgp[4];
    #pragma unroll
    for (int r = 0; r < 4; ++r) {
        int idx = ((r * 4 + w) << 6) + lane;          // 16B-chunk index 0..1023
        int mm  = idx >> 4, cb = (idx & 15) << 4;     // K: row m, dest col-byte
        kgp[r] = (const char*)(kp + (size_t)b * NN * CI + (size_t)t0 * 64 * CI
                               + (size_t)mm * CI) + (cb ^ ((mm & 7) << 4));
        int cc = idx >> 3, cbv = (idx & 7) << 4;      // V: row c, dest col-byte
        vgp[r] = (const char*)(vtp + (size_t)b * CI * NN + (size_t)t0 * 64
                               + (size_t)cc * NN) + (cbv ^ ((cc & 7) << 4));
    }
    auto stage = [&](int bufi) {
        #pragma unroll
        for (int r = 0; r < 4; ++r) {
            __builtin_amdgcn_global_load_lds(
                (const __attribute__((address_space(1))) void*)kgp[r],
                (__attribute__((address_space(3))) void*)&K_sh[bufi][(r * 4 + w) << 10],
                16, 0, 0);
            __builtin_amdgcn_global_load_lds(
                (const __attribute__((address_space(1))) void*)vgp[r],
                (__attribute__((address_space(3))) void*)&V_sh[bufi][(r * 4 + w) << 10],
                16, 0, 0);
            kgp[r] += 64 * CI * 2;    // next K tile: 16 KB
            vgp[r] += 64 * 2;         // next V tile: 128 B
        }
    };

    // Q strips in registers (B-frag for mfma(K,Q): col=q=lr, k contiguous)
    bf16x8 qf[2][4];
    #pragma unroll
    for (int s = 0; s < 2; ++s) {
        const short* qrow = qp + ((size_t)b * NN + n0 + w * 32 + s * 16 + lr) * CI;
        #pragma unroll
        for (int kf = 0; kf < 4; ++kf)
            qf[s][kf] = *(const bf16x8*)&qrow[kf * 32 + lg * 8];
    }

    f32x4 yacc[2][8];
    #pragma unroll
    for (int s = 0; s < 2; ++s)
        #pragma unroll
        for (int i = 0; i < 8; ++i) yacc[s][i] = (f32x4){0.f, 0.f, 0.f, 0.f};
    float m_run[2] = {-__builtin_huge_valf(), -__builtin_huge_valf()};
    float l_run[2] = {0.f, 0.f};   // per-lane partials; reduced after the loop

    stage(0);
    __syncthreads();

    for (int t = 0; t < NT; ++t) {
        const int cur = t & 1;
        if (t + 1 < NT) stage(cur ^ 1);   // issue before compute

        // S^T = K Q : lane (lr,lg) holds S[q=lr][m=mt*16+lg*4+rr] per strip
        const char* Kc = K_sh[cur];
        f32x4 sa[2][4];
        __builtin_amdgcn_s_setprio(1);
        #pragma unroll
        for (int mt = 0; mt < 4; ++mt) {
            const int mrow = mt * 16 + lr;
            const int sw   = (mrow & 7) << 4;
            sa[0][mt] = (f32x4){0.f, 0.f, 0.f, 0.f};
            sa[1][mt] = (f32x4){0.f, 0.f, 0.f, 0.f};
            #pragma unroll
            for (int kf = 0; kf < 4; ++kf) {
                bf16x8 kfrag = *(const bf16x8*)(Kc + (mrow << 8) + ((kf * 64 + lg * 16) ^ sw));
                sa[0][mt] = __builtin_amdgcn_mfma_f32_16x16x32_bf16(kfrag, qf[0][kf], sa[0][mt], 0, 0, 0);
                sa[1][mt] = __builtin_amdgcn_mfma_f32_16x16x32_bf16(kfrag, qf[1][kf], sa[1][mt], 0, 0, 0);
            }
        }
        __builtin_amdgcn_s_setprio(0);

        // lazy online softmax: per-lane partial max only on the common path
        float tml[2];
        #pragma unroll
        for (int s = 0; s < 2; ++s) {
            float tm = fmaxf(fmaxf(fmaxf(sa[s][0][0], sa[s][0][1]), fmaxf(sa[s][0][2], sa[s][0][3])),
                             fmaxf(fmaxf(sa[s][1][0], sa[s][1][1]), fmaxf(sa[s][1][2], sa[s][1][3])));
            tm = fmaxf(tm, fmaxf(fmaxf(fmaxf(sa[s][2][0], sa[s][2][1]), fmaxf(sa[s][2][2], sa[s][2][3])),
                                 fmaxf(fmaxf(sa[s][3][0], sa[s][3][1]), fmaxf(sa[s][3][2], sa[s][3][3]))));
            tml[s] = tm;
        }
        if (__any((tml[0] - m_run[0] > 8.f) || (tml[1] - m_run[1] > 8.f))) {
            #pragma unroll
            for (int s = 0; s < 2; ++s) {
                float tm = tml[s];
                tm = fmaxf(tm, __shfl_xor(tm, 16));
                tm = fmaxf(tm, __shfl_xor(tm, 32));
                float mnew = fmaxf(m_run[s], tm);
                float sc   = __builtin_amdgcn_exp2f(m_run[s] - mnew);
                m_run[s] = mnew;
                l_run[s] *= sc;
                #pragma unroll
                for (int rr = 0; rr < 4; ++rr) {
                    float scb = __shfl(sc, (lane & 48) | (lg * 4 + rr));
                    #pragma unroll
                    for (int ct = 0; ct < 8; ++ct) yacc[s][ct][rr] *= scb;
                }
            }
        }

        // V-frags into regs early (shared by both strips)
        const char* Vc = V_sh[cur];
        bf16x8 vf[2][8];
        #pragma unroll
        for (int kf = 0; kf < 2; ++kf)
            #pragma unroll
            for (int ct = 0; ct < 8; ++ct) {
                const int vr = ct * 16 + lr;
                vf[kf][ct] = *(const bf16x8*)(Vc + (vr << 7) +
                                              ((kf * 64 + lg * 16) ^ ((vr & 7) << 4)));
            }

        // strip 0: exp2 + cvt_pk pack into per-wave P buf, then read pa0
        char* Pb = P_sh[w];
        const int psw = (lr & 7) << 4;
        bf16x8 pa0[2], pa1[2];
        {
            float rs = 0.f;
            #pragma unroll
            for (int mt = 0; mt < 4; ++mt) {
                float e0 = __builtin_amdgcn_exp2f(sa[0][mt][0] - m_run[0]);
                float e1 = __builtin_amdgcn_exp2f(sa[0][mt][1] - m_run[0]);
                float e2 = __builtin_amdgcn_exp2f(sa[0][mt][2] - m_run[0]);
                float e3 = __builtin_amdgcn_exp2f(sa[0][mt][3] - m_run[0]);
                rs += (e0 + e1) + (e2 + e3);
                u32x2 pk = {cvt_pk_bf16(e0, e1), cvt_pk_bf16(e2, e3)};
                *(u32x2*)(Pb + lr * 128 + ((mt * 32 + lg * 8) ^ psw)) = pk;
            }
            l_run[0] += rs;           // per-lane partial; reduced after loop
        }
        asm volatile("" ::: "memory");
        #pragma unroll
        for (int kf = 0; kf < 2; ++kf)
            pa0[kf] = *(const bf16x8*)(Pb + lr * 128 + ((kf * 64 + lg * 16) ^ psw));
        asm volatile("" ::: "memory");

        // strip 1: overwrite same P buf (same-wave DS is in-order; fenced)
        {
            float rs = 0.f;
            #pragma unroll
            for (int mt = 0; mt < 4; ++mt) {
                float e0 = __builtin_amdgcn_exp2f(sa[1][mt][0] - m_run[1]);
                float e1 = __builtin_amdgcn_exp2f(sa[1][mt][1] - m_run[1]);
                float e2 = __builtin_amdgcn_exp2f(sa[1][mt][2] - m_run[1]);
                float e3 = __builtin_amdgcn_exp2f(sa[1][mt][3] - m_run[1]);
                rs += (e0 + e1) + (e2 + e3);
                u32x2 pk = {cvt_pk_bf16(e0, e1), cvt_pk_bf16(e2, e3)};
                *(u32x2*)(Pb + lr * 128 + ((mt * 32 + lg * 8) ^ psw)) = pk;
            }
            l_run[1] += rs;
        }
        asm volatile("" ::: "memory");
        #pragma unroll
        for (int kf = 0; kf < 2; ++kf)
            pa1[kf] = *(const bf16x8*)(Pb + lr * 128 + ((kf * 64 + lg * 16) ^ psw));

        // Y += P V  (single MFMA cluster, both strips interleaved — R9 form)
        __builtin_amdgcn_s_setprio(1);
        #pragma unroll
        for (int kf = 0; kf < 2; ++kf)
            #pragma unroll
            for (int ct = 0; ct < 8; ++ct) {
                yacc[0][ct] = __builtin_amdgcn_mfma_f32_16x16x32_bf16(pa0[kf], vf[kf][ct], yacc[0][ct], 0, 0, 0);
                yacc[1][ct] = __builtin_amdgcn_mfma_f32_16x16x32_bf16(pa1[kf], vf[kf][ct], yacc[1][ct], 0, 0, 0);
            }
        __builtin_amdgcn_s_setprio(0);

        __syncthreads();   // drains vmcnt: next tile staged; buf[cur] reads done
    }

    // reduce l across the 4 lane-groups (deferred from the loop)
    #pragma unroll
    for (int s = 0; s < 2; ++s) {
        float lt = l_run[s];
        lt += __shfl_xor(lt, 16);
        lt += __shfl_xor(lt, 32);
        l_run[s] = lt;
    }

    // store UNNORMALIZED partial Yhat (bf16) + (m,l) per q-row
    short* yb = yh + ((size_t)half * BB + b) * NN * (size_t)CI;
    #pragma unroll
    for (int s = 0; s < 2; ++s) {
        #pragma unroll
        for (int rr = 0; rr < 4; ++rr) {
            int n = n0 + w * 32 + s * 16 + lg * 4 + rr;
            #pragma unroll
            for (int ct = 0; ct < 8; ++ct)
                yb[(size_t)n * CI + ct * 16 + lr] = f2bf(yacc[s][ct][rr]);
        }
    }
    if (lg == 0) {
        #pragma unroll
        for (int s = 0; s < 2; ++s) {
            int n = n0 + w * 32 + s * 16 + lr;
            f32x2 v = {m_run[s], l_run[s]};
            *(f32x2*)&ml[(((size_t)half * BB + b) * NN + n) * 2] = v;
        }
    }
}

// ---------------------------------------------------------------------------
// Kernel 2b (fallback path): merge the two KV-half partials -> Y^T bf16
// ---------------------------------------------------------------------------
__global__ __launch_bounds__(256) void merge_kernel(
    const short* __restrict__ yh, const float* __restrict__ ml,
    short* __restrict__ yp)
{
    const int tid = threadIdx.x;
    const int row = blockIdx.x * 8 + (tid >> 5);    // (b*NN + n) in [0, BB*NN)
    const int c4  = (tid & 31) * 4;
    const size_t H = (size_t)BB * NN * CI;          // half stride in yh
    const size_t R = (size_t)BB * NN * 2;           // half stride in ml

    float m0 = ml[(size_t)row * 2],     l0 = ml[(size_t)row * 2 + 1];
    float m1 = ml[R + (size_t)row * 2], l1 = ml[R + (size_t)row * 2 + 1];
    float mm = fmaxf(m0, m1);
    float w0 = __builtin_amdgcn_exp2f(m0 - mm);
    float w1 = __builtin_amdgcn_exp2f(m1 - mm);
    float inv = 1.0f / (l0 * w0 + l1 * w1);
    w0 *= inv; w1 *= inv;

    bf16x4 a  = *(const bf16x4*)&yh[(size_t)row * CI + c4];
    bf16x4 bb = *(const bf16x4*)&yh[H + (size_t)row * CI + c4];
    bf16x4 o;
    #pragma unroll
    for (int i = 0; i < 4; ++i) o[i] = f2bf(bf2f(a[i]) * w0 + bf2f(bb[i]) * w1);
    *(bf16x4*)&yp[(size_t)row * CI + c4] = o;
}

// ---------------------------------------------------------------------------
// Kernel 3: out = w_w @ Y + b_w + x, 128x128 tiles, XCD-pinned.
// MERGED==0: stage Y by combining the two partials with ml weights (fused,
// no merge kernel; yh must NOT alias d_out). MERGED==1: read pre-merged yp.
// ---------------------------------------------------------------------------
template <int MERGED>
__global__ __launch_bounds__(256) void out_kernel(
    const short* __restrict__ ysrc, const float* __restrict__ ml,
    const float* __restrict__ ww, const float* __restrict__ bw,
    const float* __restrict__ x, float* __restrict__ out)
{
    __shared__ __align__(16) short A_lds[128][136];   // w_w [o][c]
    __shared__ __align__(16) short Bl[128][136];      // Y^T [n][c]

    const int tid  = threadIdx.x;
    const int b    = blockIdx.x & 7;          // batch == XCD
    const int rest = blockIdx.x >> 3;         // 0..63
    const int ob   = rest & 1;
    const int nn   = (rest >> 1) * 128;
    const int o0   = ob * 128;
    const int w = tid >> 6, lane = tid & 63, lr = lane & 15, lg = lane >> 4;

    #pragma unroll
    for (int pass = 0; pass < 8; ++pass) {
        int o  = pass * 16 + (tid >> 4);
        int c8 = (tid & 15) * 8;
        f32x4 v0 = *(const f32x4*)&ww[(size_t)(o0 + o) * CI + c8];
        f32x4 v1 = *(const f32x4*)&ww[(size_t)(o0 + o) * CI + c8 + 4];
        bf16x8 bv;
        #pragma unroll
        for (int i = 0; i < 4; ++i) { bv[i] = f2bf(v0[i]); bv[4 + i] = f2bf(v1[i]); }
        *(bf16x8*)&A_lds[o][c8] = bv;
    }
    #pragma unroll
    for (int pass = 0; pass < 8; ++pass) {
        int n  = pass * 16 + (tid >> 4);
        int c8 = (tid & 15) * 8;
        size_t row = (size_t)b * NN + nn + n;
        if (MERGED) {
            *(bf16x8*)&Bl[n][c8] = *(const bf16x8*)&ysrc[row * CI + c8];
        } else {
            const size_t H = (size_t)BB * NN * CI;
            const size_t R = (size_t)BB * NN * 2;
            f32x2 v0 = *(const f32x2*)&ml[row * 2];
            f32x2 v1 = *(const f32x2*)&ml[R + row * 2];
            float mm = fmaxf(v0[0], v1[0]);
            float w0 = __builtin_amdgcn_exp2f(v0[0] - mm);
            float w1 = __builtin_amdgcn_exp2f(v1[0] - mm);
            float inv = 1.0f / (v0[1] * w0 + v1[1] * w1);
            w0 *= inv; w1 *= inv;
            bf16x8 a  = *(const bf16x8*)&ysrc[row * CI + c8];
            bf16x8 b2 = *(const bf16x8*)&ysrc[H + row * CI + c8];
            bf16x8 ov;
            #pragma unroll
            for (int i = 0; i < 4; ++i) {
                float lo = bf2f(a[2*i]) * w0 + bf2f(b2[2*i]) * w1;
                float hi = bf2f(a[2*i+1]) * w0 + bf2f(b2[2*i+1]) * w1;
                uint32_t pk = cvt_pk_bf16(lo, hi);
                ov[2*i]   = (short)(pk & 0xFFFF);
                ov[2*i+1] = (short)(pk >> 16);
            }
            *(bf16x8*)&Bl[n][c8] = ov;
        }
    }
    __syncthreads();

    f32x4 acc[2][8];
    #pragma unroll
    for (int i = 0; i < 2; ++i)
        #pragma unroll
        for (int j = 0; j < 8; ++j) acc[i][j] = (f32x4){0.f, 0.f, 0.f, 0.f};

    #pragma unroll
    for (int kf = 0; kf < 4; ++kf) {
        bf16x8 a0 = *(const bf16x8*)&A_lds[w * 32 + lr][kf * 32 + lg * 8];
        bf16x8 a1 = *(const bf16x8*)&A_lds[w * 32 + 16 + lr][kf * 32 + lg * 8];
        #pragma unroll
        for (int nt = 0; nt < 8; ++nt) {
            bf16x8 bv = *(const bf16x8*)&Bl[nt * 16 + lr][kf * 32 + lg * 8];
            acc[0][nt] = __builtin_amdgcn_mfma_f32_16x16x32_bf16(a0, bv, acc[0][nt], 0, 0, 0);
            acc[1][nt] = __builtin_amdgcn_mfma_f32_16x16x32_bf16(a1, bv, acc[1][nt], 0, 0, 0);
        }
    }

    #pragma unroll
    for (int wo = 0; wo < 2; ++wo) {
        #pragma unroll
        for (int rr = 0; rr < 4; ++rr) {
            int o = o0 + w * 32 + wo * 16 + lg * 4 + rr;
            float bias = bw[o];
            #pragma unroll
            for (int nt = 0; nt < 8; ++nt) {
                size_t idx = ((size_t)b * CIN + o) * NN + nn + nt * 16 + lr;
                out[idx] = acc[wo][nt][rr] + bias + x[idx];
            }
        }
    }
}

// ---------------------------------------------------------------------------
extern "C" void kernel_launch(void* const* d_in, const int* in_sizes, int n_in,
                              void* d_out, int out_size, void* d_ws, size_t ws_size,
                              hipStream_t stream)
{
    const float* x     = (const float*)d_in[0];
    const float* gamma = (const float*)d_in[1];
    const float* beta  = (const float*)d_in[2];
    const float* mean  = (const float*)d_in[3];
    const float* var   = (const float*)d_in[4];
    const float* wg    = (const float*)d_in[5];
    const float* bg    = (const float*)d_in[6];
    const float* wth   = (const float*)d_in[7];
    const float* bth   = (const float*)d_in[8];
    const float* wph   = (const float*)d_in[9];
    const float* bph   = (const float*)d_in[10];
    const float* ww    = (const float*)d_in[11];
    const float* bw    = (const float*)d_in[12];

    // ws layout: qp 8MB | kp 8MB | vtp 8MB | ml 0.5MB | [yh 16MB if room]
    // Preferred: yh lives in ws -> out_kernel<0> fuses the merge (reads yh
    // while writing d_out). Fallback (small ws): yh in d_out + merge kernel.
    const size_t seg = (size_t)BB * NN * CI;
    short* qp  = (short*)d_ws;
    short* kp  = qp + seg;
    short* vtp = kp + seg;
    float* ml  = (float*)(vtp + seg);
    const size_t yh_off = 25u * 1024 * 1024;
    const bool fused = ws_size >= yh_off + 2 * seg * sizeof(short);
    short* yh = fused ? (short*)((char*)d_ws + yh_off) : (short*)d_out;
    (void)in_sizes; (void)n_in; (void)out_size;

    proj_kernel<<<BB * (NN / 64), 256, 0, stream>>>(
        x, gamma, beta, mean, var, wg, bg, wth, bth, wph, bph, qp, kp, vtp);
    attn_kernel<<<2 * BB * (NN / 128), 256, 0, stream>>>(qp, kp, vtp, yh, ml);
    if (fused) {
        out_kernel<0><<<2 * BB * (NN / 128), 256, 0, stream>>>(
            yh, ml, ww, bw, x, (float*)d_out);
    } else {
        short* yp = qp;   // reuse: q dead after attn
        merge_kernel<<<BB * NN / 8, 256, 0, stream>>>(yh, ml, yp);
        out_kernel<1><<<2 * BB * (NN / 128), 256, 0, stream>>>(
            yp, ml, ww, bw, x, (float*)d_out);
    }
}

// Round 12
// 116.431 us; speedup vs baseline: 3.8229x; 1.0098x over previous
//
#include <hip/hip_runtime.h>
#include <hip/hip_bf16.h>
#include <stdint.h>

#define BB   8
#define CIN  256
#define CI   128
#define NN   4096
#define EPSV 1e-5f
#define LOG2E 1.44269504088896340736f

typedef __attribute__((ext_vector_type(8))) short bf16x8;
typedef __attribute__((ext_vector_type(4))) short bf16x4;
typedef __attribute__((ext_vector_type(4))) float f32x4;
typedef __attribute__((ext_vector_type(2))) float f32x2;
typedef __attribute__((ext_vector_type(2))) unsigned int u32x2;

static __device__ inline short f2bf(float f) {
    uint32_t u = __builtin_bit_cast(uint32_t, f);
    u += 0x7FFFu + ((u >> 16) & 1u);   // round-to-nearest-even
    return (short)(u >> 16);
}

static __device__ inline float bf2f(short s) {
    uint32_t u = ((uint32_t)(uint16_t)s) << 16;
    return __builtin_bit_cast(float, u);
}

static __device__ inline uint32_t cvt_pk_bf16(float lo, float hi) {
    uint32_t r;
    asm("v_cvt_pk_bf16_f32 %0, %1, %2" : "=v"(r) : "v"(lo), "v"(hi));
    return r;
}

// ---------------------------------------------------------------------------
// Kernel 0 (PREP): convert weights to bf16 once.
// wq: 3 matrices x 4 chunks(64c) x 128 o x 8 blocks(16B), block jj stored at
// ((jj ^ (o&7))<<4) within the row -> proj can global_load_lds LINEARLY and
// read with the K-style XOR swizzle. w_theta pre-scaled by log2(e).
// wwb: w_w plain bf16 [256][128] for out_kernel.
// ---------------------------------------------------------------------------
__global__ __launch_bounds__(256) void prep_kernel(
    const float* __restrict__ wth, const float* __restrict__ wph,
    const float* __restrict__ wg,  const float* __restrict__ ww,
    short* __restrict__ wq, short* __restrict__ wwb)
{
    int t = blockIdx.x * 256 + threadIdx.x;
    if (t < 12288) {                       // 3 x 128 x 32 16B-blocks
        int s  = t >> 12;                  // 4096 blocks per matrix
        int r  = t & 4095;
        int o  = r >> 5;                   // 0..127
        int j  = r & 31;                   // 16B block within 256 c
        int k  = j >> 3, jj = j & 7;       // chunk, block-within-chunk
        const float* W = (s == 0) ? wth : (s == 1) ? wph : wg;
        float sc = (s == 0) ? LOG2E : 1.0f;
        const float* src = &W[(size_t)o * CIN + k * 64 + jj * 8];
        bf16x8 d;
        #pragma unroll
        for (int i = 0; i < 8; ++i) d[i] = f2bf(src[i] * sc);
        size_t doff = (size_t)s * 65536 + (size_t)k * 16384
                    + (size_t)o * 128 + (size_t)((jj ^ (o & 7)) << 4);
        *(bf16x8*)((char*)wq + doff) = d;
    } else if (t < 16384) {                // ww: 256 x 16 16B-blocks
        int r = t - 12288;
        int o = r >> 4, j = r & 15;
        const float* src = &ww[(size_t)o * CI + j * 8];
        bf16x8 d;
        #pragma unroll
        for (int i = 0; i < 8; ++i) d[i] = f2bf(src[i]);
        *(bf16x8*)&wwb[(size_t)o * CI + j * 8] = d;
    }
}

// ---------------------------------------------------------------------------
// Kernel 1 (FUSED): BN + all three 1x1 projections in one pass over x.
// Weights staged via global_load_lds from prepped bf16 (pre-swizzled source,
// linear LDS dest), double-buffered: 1 barrier per chunk. BN(x) staged once
// with cvt_pk pair-writes (u32).
// ---------------------------------------------------------------------------
__global__ __launch_bounds__(256, 2) void proj_kernel(
    const float* __restrict__ x,
    const float* __restrict__ gamma, const float* __restrict__ beta,
    const float* __restrict__ mean,  const float* __restrict__ var,
    const short* __restrict__ wq,
    const float* __restrict__ bth, const float* __restrict__ bph,
    const float* __restrict__ bg,
    short* __restrict__ qp, short* __restrict__ kp, short* __restrict__ vtp)
{
    __shared__ float s_scale[CIN];
    __shared__ float s_shift[CIN];
    __shared__ __align__(16) short A_lds[64][264];   // [n][c] full K, pad 264
    __shared__ __align__(16) char  B_sh[2][128 * 128]; // swizzled chunk, 16KB x2

    const int tid = threadIdx.x;
    const int b   = blockIdx.x & 7;           // batch == XCD
    const int n0  = (blockIdx.x >> 3) * 64;
    const int w = tid >> 6, lane = tid & 63, lr = lane & 15, lg = lane >> 4;

    {   // BN scale/shift (256 threads == 256 channels)
        float sc = gamma[tid] * rsqrtf(var[tid] + EPSV);
        s_scale[tid] = sc;
        s_shift[tid] = beta[tid] - mean[tid] * sc;
    }
    __syncthreads();

    // stage BN(x) -> A_lds[n][c] bf16, once; pair-column u32 writes
    #pragma unroll
    for (int p = 0; p < 8; ++p) {
        int c2 = p * 32 + (tid >> 4) * 2;
        int n4 = (tid & 15) * 4;
        f32x4 v0 = *(const f32x4*)&x[((size_t)b * CIN + c2) * NN + n0 + n4];
        f32x4 v1 = *(const f32x4*)&x[((size_t)b * CIN + c2 + 1) * NN + n0 + n4];
        float sc0 = s_scale[c2],     sh0 = s_shift[c2];
        float sc1 = s_scale[c2 + 1], sh1 = s_shift[c2 + 1];
        #pragma unroll
        for (int i = 0; i < 4; ++i) {
            uint32_t pk = cvt_pk_bf16(v0[i] * sc0 + sh0, v1[i] * sc1 + sh1);
            *(uint32_t*)&A_lds[n4 + i][c2] = pk;
        }
    }

    // stage weight chunk idx (= s*4 + k) into B_sh[buf], linear DMA
    auto stageB = [&](int buf, int idx) {
        const char* src = (const char*)wq + (size_t)idx * 16384;
        #pragma unroll
        for (int r = 0; r < 4; ++r) {
            __builtin_amdgcn_global_load_lds(
                (const __attribute__((address_space(1))) void*)
                    (src + ((((r * 4 + w) << 6) + lane) << 4)),
                (__attribute__((address_space(3))) void*)&B_sh[buf][(r * 4 + w) << 10],
                16, 0, 0);
        }
    };
    stageB(0, 0);
    __syncthreads();    // drains A writes + first B chunk

    const float* BS[3] = {bth, bph, bg};
    f32x4 acc[8];

    for (int idx = 0; idx < 12; ++idx) {
        const int s = idx >> 2, k = idx & 3, buf = idx & 1;
        if (idx + 1 < 12) stageB(buf ^ 1, idx + 1);   // drains at loop-end bar

        if (k == 0) {
            #pragma unroll
            for (int i = 0; i < 8; ++i) acc[i] = (f32x4){0.f, 0.f, 0.f, 0.f};
        }
        const int c0 = k * 64;
        bf16x8 a0 = *(const bf16x8*)&A_lds[w * 16 + lr][c0 + lg * 8];
        bf16x8 a1 = *(const bf16x8*)&A_lds[w * 16 + lr][c0 + 32 + lg * 8];
        const char* Bc = B_sh[buf];
        #pragma unroll
        for (int ot = 0; ot < 8; ++ot) {
            const int o  = ot * 16 + lr;
            const int sw = (o & 7) << 4;
            bf16x8 b0 = *(const bf16x8*)(Bc + o * 128 + ((lg << 4) ^ sw));
            bf16x8 b1 = *(const bf16x8*)(Bc + o * 128 + (((4 + lg) << 4) ^ sw));
            acc[ot] = __builtin_amdgcn_mfma_f32_16x16x32_bf16(a0, b0, acc[ot], 0, 0, 0);
            acc[ot] = __builtin_amdgcn_mfma_f32_16x16x32_bf16(a1, b1, acc[ot], 0, 0, 0);
        }

        if (k == 3) {
            if (s < 2) {   // Q / K (b,n,c); wth pre-scaled, bias scaled here
                short* dst = (s == 0) ? qp : kp;
                const float om = (s == 0) ? LOG2E : 1.0f;
                #pragma unroll
                for (int ot = 0; ot < 8; ++ot) {
                    float bias = BS[s][ot * 16 + lr] * om;
                    #pragma unroll
                    for (int rr = 0; rr < 4; ++rr) {
                        int n = n0 + w * 16 + lg * 4 + rr;
                        dst[((size_t)b * NN + n) * CI + ot * 16 + lr] = f2bf(acc[ot][rr] + bias);
                    }
                }
            } else {       // V^T (b,c,n)
                #pragma unroll
                for (int ot = 0; ot < 8; ++ot) {
                    float bias = BS[s][ot * 16 + lr];
                    bf16x4 pk;
                    #pragma unroll
                    for (int rr = 0; rr < 4; ++rr) pk[rr] = f2bf(acc[ot][rr] + bias);
                    *(bf16x4*)&vtp[((size_t)b * CI + ot * 16 + lr) * NN + n0 + w * 16 + lg * 4] = pk;
                }
            }
        }
        __syncthreads();   // B reads done; next chunk's DMA drained
    }
}

// ---------------------------------------------------------------------------
// Kernel 2: flash attention — R9/R11 structure (86.5us proven). Frozen.
// SPLIT-KV x2, 2 blk/CU, 192 regs = 2 waves/SIMD. Do NOT raise occupancy
// (R6/R7/R8) and do NOT split the PV cluster (R10 regression).
// ---------------------------------------------------------------------------
__global__ __launch_bounds__(256, 2) void attn_kernel(
    const short* __restrict__ qp, const short* __restrict__ kp,
    const short* __restrict__ vtp, short* __restrict__ yh,
    float* __restrict__ ml)
{
    __shared__ __align__(16) char K_sh[2][64 * 256];    // [m][c] swizzled, 16KB x2
    __shared__ __align__(16) char V_sh[2][128 * 128];   // [c][m] swizzled, 16KB x2
    __shared__ __align__(16) char P_sh[4][16 * 128];    // per-wave single P buf

    const int tid  = threadIdx.x;
    const int b    = blockIdx.x & 7;            // batch == XCD (round-robin)
    const int half = (blockIdx.x >> 3) & 1;     // kv half
    const int n0   = (blockIdx.x >> 4) * 128;
    const int w = tid >> 6, lane = tid & 63, lr = lane & 15, lg = lane >> 4;
    const int NT = NN / 128;                    // 32 kv tiles per half
    const int t0 = half * NT;

    // loop-carried per-lane global source pointers (pre-swizzled), LDS dest linear
    const char* kgp[4];
    const char* vgp[4];
    #pragma unroll
    for (int r = 0; r < 4; ++r) {
        int idx = ((r * 4 + w) << 6) + lane;          // 16B-chunk index 0..1023
        int mm  = idx >> 4, cb = (idx & 15) << 4;     // K: row m, dest col-byte
        kgp[r] = (const char*)(kp + (size_t)b * NN * CI + (size_t)t0 * 64 * CI
                               + (size_t)mm * CI) + (cb ^ ((mm & 7) << 4));
        int cc = idx >> 3, cbv = (idx & 7) << 4;      // V: row c, dest col-byte
        vgp[r] = (const char*)(vtp + (size_t)b * CI * NN + (size_t)t0 * 64
                               + (size_t)cc * NN) + (cbv ^ ((cc & 7) << 4));
    }
    auto stage = [&](int bufi) {
        #pragma unroll
        for (int r = 0; r < 4; ++r) {
            __builtin_amdgcn_global_load_lds(
                (const __attribute__((address_space(1))) void*)kgp[r],
                (__attribute__((address_space(3))) void*)&K_sh[bufi][(r * 4 + w) << 10],
                16, 0, 0);
            __builtin_amdgcn_global_load_lds(
                (const __attribute__((address_space(1))) void*)vgp[r],
                (__attribute__((address_space(3))) void*)&V_sh[bufi][(r * 4 + w) << 10],
                16, 0, 0);
            kgp[r] += 64 * CI * 2;    // next K tile: 16 KB
            vgp[r] += 64 * 2;         // next V tile: 128 B
        }
    };

    // Q strips in registers (B-frag for mfma(K,Q): col=q=lr, k contiguous)
    bf16x8 qf[2][4];
    #pragma unroll
    for (int s = 0; s < 2; ++s) {
        const short* qrow = qp + ((size_t)b * NN + n0 + w * 32 + s * 16 + lr) * CI;
        #pragma unroll
        for (int kf = 0; kf < 4; ++kf)
            qf[s][kf] = *(const bf16x8*)&qrow[kf * 32 + lg * 8];
    }

    f32x4 yacc[2][8];
    #pragma unroll
    for (int s = 0; s < 2; ++s)
        #pragma unroll
        for (int i = 0; i < 8; ++i) yacc[s][i] = (f32x4){0.f, 0.f, 0.f, 0.f};
    float m_run[2] = {-__builtin_huge_valf(), -__builtin_huge_valf()};
    float l_run[2] = {0.f, 0.f};   // per-lane partials; reduced after the loop

    stage(0);
    __syncthreads();

    for (int t = 0; t < NT; ++t) {
        const int cur = t & 1;
        if (t + 1 < NT) stage(cur ^ 1);   // issue before compute

        // S^T = K Q : lane (lr,lg) holds S[q=lr][m=mt*16+lg*4+rr] per strip
        const char* Kc = K_sh[cur];
        f32x4 sa[2][4];
        __builtin_amdgcn_s_setprio(1);
        #pragma unroll
        for (int mt = 0; mt < 4; ++mt) {
            const int mrow = mt * 16 + lr;
            const int sw   = (mrow & 7) << 4;
            sa[0][mt] = (f32x4){0.f, 0.f, 0.f, 0.f};
            sa[1][mt] = (f32x4){0.f, 0.f, 0.f, 0.f};
            #pragma unroll
            for (int kf = 0; kf < 4; ++kf) {
                bf16x8 kfrag = *(const bf16x8*)(Kc + (mrow << 8) + ((kf * 64 + lg * 16) ^ sw));
                sa[0][mt] = __builtin_amdgcn_mfma_f32_16x16x32_bf16(kfrag, qf[0][kf], sa[0][mt], 0, 0, 0);
                sa[1][mt] = __builtin_amdgcn_mfma_f32_16x16x32_bf16(kfrag, qf[1][kf], sa[1][mt], 0, 0, 0);
            }
        }
        __builtin_amdgcn_s_setprio(0);

        // lazy online softmax: per-lane partial max only on the common path
        float tml[2];
        #pragma unroll
        for (int s = 0; s < 2; ++s) {
            float tm = fmaxf(fmaxf(fmaxf(sa[s][0][0], sa[s][0][1]), fmaxf(sa[s][0][2], sa[s][0][3])),
                             fmaxf(fmaxf(sa[s][1][0], sa[s][1][1]), fmaxf(sa[s][1][2], sa[s][1][3])));
            tm = fmaxf(tm, fmaxf(fmaxf(fmaxf(sa[s][2][0], sa[s][2][1]), fmaxf(sa[s][2][2], sa[s][2][3])),
                                 fmaxf(fmaxf(sa[s][3][0], sa[s][3][1]), fmaxf(sa[s][3][2], sa[s][3][3]))));
            tml[s] = tm;
        }
        if (__any((tml[0] - m_run[0] > 8.f) || (tml[1] - m_run[1] > 8.f))) {
            #pragma unroll
            for (int s = 0; s < 2; ++s) {
                float tm = tml[s];
                tm = fmaxf(tm, __shfl_xor(tm, 16));
                tm = fmaxf(tm, __shfl_xor(tm, 32));
                float mnew = fmaxf(m_run[s], tm);
                float sc   = __builtin_amdgcn_exp2f(m_run[s] - mnew);
                m_run[s] = mnew;
                l_run[s] *= sc;
                #pragma unroll
                for (int rr = 0; rr < 4; ++rr) {
                    float scb = __shfl(sc, (lane & 48) | (lg * 4 + rr));
                    #pragma unroll
                    for (int ct = 0; ct < 8; ++ct) yacc[s][ct][rr] *= scb;
                }
            }
        }

        // V-frags into regs early (shared by both strips)
        const char* Vc = V_sh[cur];
        bf16x8 vf[2][8];
        #pragma unroll
        for (int kf = 0; kf < 2; ++kf)
            #pragma unroll
            for (int ct = 0; ct < 8; ++ct) {
                const int vr = ct * 16 + lr;
                vf[kf][ct] = *(const bf16x8*)(Vc + (vr << 7) +
                                              ((kf * 64 + lg * 16) ^ ((vr & 7) << 4)));
            }

        // strip 0: exp2 + cvt_pk pack into per-wave P buf, then read pa0
        char* Pb = P_sh[w];
        const int psw = (lr & 7) << 4;
        bf16x8 pa0[2], pa1[2];
        {
            float rs = 0.f;
            #pragma unroll
            for (int mt = 0; mt < 4; ++mt) {
                float e0 = __builtin_amdgcn_exp2f(sa[0][mt][0] - m_run[0]);
                float e1 = __builtin_amdgcn_exp2f(sa[0][mt][1] - m_run[0]);
                float e2 = __builtin_amdgcn_exp2f(sa[0][mt][2] - m_run[0]);
                float e3 = __builtin_amdgcn_exp2f(sa[0][mt][3] - m_run[0]);
                rs += (e0 + e1) + (e2 + e3);
                u32x2 pk = {cvt_pk_bf16(e0, e1), cvt_pk_bf16(e2, e3)};
                *(u32x2*)(Pb + lr * 128 + ((mt * 32 + lg * 8) ^ psw)) = pk;
            }
            l_run[0] += rs;           // per-lane partial; reduced after loop
        }
        asm volatile("" ::: "memory");
        #pragma unroll
        for (int kf = 0; kf < 2; ++kf)
            pa0[kf] = *(const bf16x8*)(Pb + lr * 128 + ((kf * 64 + lg * 16) ^ psw));
        asm volatile("" ::: "memory");

        // strip 1: overwrite same P buf (same-wave DS is in-order; fenced)
        {
            float rs = 0.f;
            #pragma unroll
            for (int mt = 0; mt < 4; ++mt) {
                float e0 = __builtin_amdgcn_exp2f(sa[1][mt][0] - m_run[1]);
                float e1 = __builtin_amdgcn_exp2f(sa[1][mt][1] - m_run[1]);
                float e2 = __builtin_amdgcn_exp2f(sa[1][mt][2] - m_run[1]);
                float e3 = __builtin_amdgcn_exp2f(sa[1][mt][3] - m_run[1]);
                rs += (e0 + e1) + (e2 + e3);
                u32x2 pk = {cvt_pk_bf16(e0, e1), cvt_pk_bf16(e2, e3)};
                *(u32x2*)(Pb + lr * 128 + ((mt * 32 + lg * 8) ^ psw)) = pk;
            }
            l_run[1] += rs;
        }
        asm volatile("" ::: "memory");
        #pragma unroll
        for (int kf = 0; kf < 2; ++kf)
            pa1[kf] = *(const bf16x8*)(Pb + lr * 128 + ((kf * 64 + lg * 16) ^ psw));

        // Y += P V  (single MFMA cluster, both strips interleaved — R9 form)
        __builtin_amdgcn_s_setprio(1);
        #pragma unroll
        for (int kf = 0; kf < 2; ++kf)
            #pragma unroll
            for (int ct = 0; ct < 8; ++ct) {
                yacc[0][ct] = __builtin_amdgcn_mfma_f32_16x16x32_bf16(pa0[kf], vf[kf][ct], yacc[0][ct], 0, 0, 0);
                yacc[1][ct] = __builtin_amdgcn_mfma_f32_16x16x32_bf16(pa1[kf], vf[kf][ct], yacc[1][ct], 0, 0, 0);
            }
        __builtin_amdgcn_s_setprio(0);

        __syncthreads();   // drains vmcnt: next tile staged; buf[cur] reads done
    }

    // reduce l across the 4 lane-groups (deferred from the loop)
    #pragma unroll
    for (int s = 0; s < 2; ++s) {
        float lt = l_run[s];
        lt += __shfl_xor(lt, 16);
        lt += __shfl_xor(lt, 32);
        l_run[s] = lt;
    }

    // store UNNORMALIZED partial Yhat (bf16) + (m,l) per q-row
    short* yb = yh + ((size_t)half * BB + b) * NN * (size_t)CI;
    #pragma unroll
    for (int s = 0; s < 2; ++s) {
        #pragma unroll
        for (int rr = 0; rr < 4; ++rr) {
            int n = n0 + w * 32 + s * 16 + lg * 4 + rr;
            #pragma unroll
            for (int ct = 0; ct < 8; ++ct)
                yb[(size_t)n * CI + ct * 16 + lr] = f2bf(yacc[s][ct][rr]);
        }
    }
    if (lg == 0) {
        #pragma unroll
        for (int s = 0; s < 2; ++s) {
            int n = n0 + w * 32 + s * 16 + lr;
            f32x2 v = {m_run[s], l_run[s]};
            *(f32x2*)&ml[(((size_t)half * BB + b) * NN + n) * 2] = v;
        }
    }
}

// ---------------------------------------------------------------------------
// Kernel 2b (fallback path): merge the two KV-half partials -> Y^T bf16
// ---------------------------------------------------------------------------
__global__ __launch_bounds__(256) void merge_kernel(
    const short* __restrict__ yh, const float* __restrict__ ml,
    short* __restrict__ yp)
{
    const int tid = threadIdx.x;
    const int row = blockIdx.x * 8 + (tid >> 5);    // (b*NN + n) in [0, BB*NN)
    const int c4  = (tid & 31) * 4;
    const size_t H = (size_t)BB * NN * CI;          // half stride in yh
    const size_t R = (size_t)BB * NN * 2;           // half stride in ml

    float m0 = ml[(size_t)row * 2],     l0 = ml[(size_t)row * 2 + 1];
    float m1 = ml[R + (size_t)row * 2], l1 = ml[R + (size_t)row * 2 + 1];
    float mm = fmaxf(m0, m1);
    float w0 = __builtin_amdgcn_exp2f(m0 - mm);
    float w1 = __builtin_amdgcn_exp2f(m1 - mm);
    float inv = 1.0f / (l0 * w0 + l1 * w1);
    w0 *= inv; w1 *= inv;

    bf16x4 a  = *(const bf16x4*)&yh[(size_t)row * CI + c4];
    bf16x4 bb = *(const bf16x4*)&yh[H + (size_t)row * CI + c4];
    bf16x4 o;
    #pragma unroll
    for (int i = 0; i < 4; ++i) o[i] = f2bf(bf2f(a[i]) * w0 + bf2f(bb[i]) * w1);
    *(bf16x4*)&yp[(size_t)row * CI + c4] = o;
}

// ---------------------------------------------------------------------------
// Kernel 3: out = w_w @ Y + b_w + x, 128x128 tiles, XCD-pinned. w_w from
// prepped bf16 (no f32 load / cvt). MERGED==0: fuse the partial merge into
// Y staging (yh must NOT alias d_out). MERGED==1: read pre-merged yp.
// ---------------------------------------------------------------------------
template <int MERGED>
__global__ __launch_bounds__(256) void out_kernel(
    const short* __restrict__ ysrc, const float* __restrict__ ml,
    const short* __restrict__ wwb, const float* __restrict__ bw,
    const float* __restrict__ x, float* __restrict__ out)
{
    __shared__ __align__(16) short A_lds[128][136];   // w_w [o][c]
    __shared__ __align__(16) short Bl[128][136];      // Y^T [n][c]

    const int tid  = threadIdx.x;
    const int b    = blockIdx.x & 7;          // batch == XCD
    const int rest = blockIdx.x >> 3;         // 0..63
    const int ob   = rest & 1;
    const int nn   = (rest >> 1) * 128;
    const int o0   = ob * 128;
    const int w = tid >> 6, lane = tid & 63, lr = lane & 15, lg = lane >> 4;

    #pragma unroll
    for (int pass = 0; pass < 8; ++pass) {
        int o  = pass * 16 + (tid >> 4);
        int c8 = (tid & 15) * 8;
        *(bf16x8*)&A_lds[o][c8] = *(const bf16x8*)&wwb[(size_t)(o0 + o) * CI + c8];
    }
    #pragma unroll
    for (int pass = 0; pass < 8; ++pass) {
        int n  = pass * 16 + (tid >> 4);
        int c8 = (tid & 15) * 8;
        size_t row = (size_t)b * NN + nn + n;
        if (MERGED) {
            *(bf16x8*)&Bl[n][c8] = *(const bf16x8*)&ysrc[row * CI + c8];
        } else {
            const size_t H = (size_t)BB * NN * CI;
            const size_t R = (size_t)BB * NN * 2;
            f32x2 v0 = *(const f32x2*)&ml[row * 2];
            f32x2 v1 = *(const f32x2*)&ml[R + row * 2];
            float mm = fmaxf(v0[0], v1[0]);
            float w0 = __builtin_amdgcn_exp2f(v0[0] - mm);
            float w1 = __builtin_amdgcn_exp2f(v1[0] - mm);
            float inv = 1.0f / (v0[1] * w0 + v1[1] * w1);
            w0 *= inv; w1 *= inv;
            bf16x8 a  = *(const bf16x8*)&ysrc[row * CI + c8];
            bf16x8 b2 = *(const bf16x8*)&ysrc[H + row * CI + c8];
            bf16x8 ov;
            #pragma unroll
            for (int i = 0; i < 4; ++i) {
                float lo = bf2f(a[2*i]) * w0 + bf2f(b2[2*i]) * w1;
                float hi = bf2f(a[2*i+1]) * w0 + bf2f(b2[2*i+1]) * w1;
                uint32_t pk = cvt_pk_bf16(lo, hi);
                ov[2*i]   = (short)(pk & 0xFFFF);
                ov[2*i+1] = (short)(pk >> 16);
            }
            *(bf16x8*)&Bl[n][c8] = ov;
        }
    }
    __syncthreads();

    f32x4 acc[2][8];
    #pragma unroll
    for (int i = 0; i < 2; ++i)
        #pragma unroll
        for (int j = 0; j < 8; ++j) acc[i][j] = (f32x4){0.f, 0.f, 0.f, 0.f};

    #pragma unroll
    for (int kf = 0; kf < 4; ++kf) {
        bf16x8 a0 = *(const bf16x8*)&A_lds[w * 32 + lr][kf * 32 + lg * 8];
        bf16x8 a1 = *(const bf16x8*)&A_lds[w * 32 + 16 + lr][kf * 32 + lg * 8];
        #pragma unroll
        for (int nt = 0; nt < 8; ++nt) {
            bf16x8 bv = *(const bf16x8*)&Bl[nt * 16 + lr][kf * 32 + lg * 8];
            acc[0][nt] = __builtin_amdgcn_mfma_f32_16x16x32_bf16(a0, bv, acc[0][nt], 0, 0, 0);
            acc[1][nt] = __builtin_amdgcn_mfma_f32_16x16x32_bf16(a1, bv, acc[1][nt], 0, 0, 0);
        }
    }

    #pragma unroll
    for (int wo = 0; wo < 2; ++wo) {
        #pragma unroll
        for (int rr = 0; rr < 4; ++rr) {
            int o = o0 + w * 32 + wo * 16 + lg * 4 + rr;
            float bias = bw[o];
            #pragma unroll
            for (int nt = 0; nt < 8; ++nt) {
                size_t idx = ((size_t)b * CIN + o) * NN + nn + nt * 16 + lr;
                out[idx] = acc[wo][nt][rr] + bias + x[idx];
            }
        }
    }
}

// ---------------------------------------------------------------------------
extern "C" void kernel_launch(void* const* d_in, const int* in_sizes, int n_in,
                              void* d_out, int out_size, void* d_ws, size_t ws_size,
                              hipStream_t stream)
{
    const float* x     = (const float*)d_in[0];
    const float* gamma = (const float*)d_in[1];
    const float* beta  = (const float*)d_in[2];
    const float* mean  = (const float*)d_in[3];
    const float* var   = (const float*)d_in[4];
    const float* wg    = (const float*)d_in[5];
    const float* bg    = (const float*)d_in[6];
    const float* wth   = (const float*)d_in[7];
    const float* bth   = (const float*)d_in[8];
    const float* wph   = (const float*)d_in[9];
    const float* bph   = (const float*)d_in[10];
    const float* ww    = (const float*)d_in[11];
    const float* bw    = (const float*)d_in[12];

    // ws layout: qp 8MB | kp 8MB | vtp 8MB | ml 0.5MB | wq 192KB | wwb 64KB |
    //            (pad) | yh 16MB @25MiB.  d_out never aliases scratch in the
    //            fused path; fallback uses yh in d_out + merge kernel.
    const size_t seg = (size_t)BB * NN * CI;
    short* qp  = (short*)d_ws;
    short* kp  = qp + seg;
    short* vtp = kp + seg;
    float* ml  = (float*)(vtp + seg);                       // ends at 24.5 MiB
    short* wq  = (short*)((char*)d_ws + 25690112);          // 24.5 MiB
    short* wwb = (short*)((char*)d_ws + 25690112 + 196608); // +192 KiB
    const size_t yh_off = 25u * 1024 * 1024;
    const bool fused = ws_size >= yh_off + 2 * seg * sizeof(short);
    short* yh = fused ? (short*)((char*)d_ws + yh_off) : (short*)d_out;
    (void)in_sizes; (void)n_in; (void)out_size;

    prep_kernel<<<64, 256, 0, stream>>>(wth, wph, wg, ww, wq, wwb);
    proj_kernel<<<BB * (NN / 64), 256, 0, stream>>>(
        x, gamma, beta, mean, var, wq, bth, bph, bg, qp, kp, vtp);
    attn_kernel<<<2 * BB * (NN / 128), 256, 0, stream>>>(qp, kp, vtp, yh, ml);
    if (fused) {
        out_kernel<0><<<2 * BB * (NN / 128), 256, 0, stream>>>(
            yh, ml, wwb, bw, x, (float*)d_out);
    } else {
        short* yp = qp;   // reuse: q dead after attn
        merge_kernel<<<BB * NN / 8, 256, 0, stream>>>(yh, ml, yp);
        out_kernel<1><<<2 * BB * (NN / 128), 256, 0, stream>>>(
            yp, ml, wwb, bw, x, (float*)d_out);
    }
}

// Round 13
// 103.454 us; speedup vs baseline: 4.3024x; 1.1254x over previous
//
#include <hip/hip_runtime.h>
#include <hip/hip_bf16.h>
#include <stdint.h>

#define BB   8
#define CIN  256
#define CI   128
#define NN   4096
#define EPSV 1e-5f
#define LOG2E 1.44269504088896340736f

typedef __attribute__((ext_vector_type(8))) short bf16x8;
typedef __attribute__((ext_vector_type(4))) short bf16x4;
typedef __attribute__((ext_vector_type(4))) float f32x4;
typedef __attribute__((ext_vector_type(2))) float f32x2;
typedef __attribute__((ext_vector_type(2))) unsigned int u32x2;
typedef __attribute__((ext_vector_type(4))) int i32x4;
typedef __attribute__((ext_vector_type(8))) int i32x8;

static __device__ inline short f2bf(float f) {
    uint32_t u = __builtin_bit_cast(uint32_t, f);
    u += 0x7FFFu + ((u >> 16) & 1u);   // round-to-nearest-even
    return (short)(u >> 16);
}

static __device__ inline float bf2f(short s) {
    uint32_t u = ((uint32_t)(uint16_t)s) << 16;
    return __builtin_bit_cast(float, u);
}

static __device__ inline uint32_t cvt_pk_bf16(float lo, float hi) {
    uint32_t r;
    asm("v_cvt_pk_bf16_f32 %0, %1, %2" : "=v"(r) : "v"(lo), "v"(hi));
    return r;
}

// ---------------------------------------------------------------------------
// Kernel 0 (PREP): convert weights to bf16 once (wq pre-swizzled for proj's
// global_load_lds; w_theta pre-scaled by log2e; wwb plain bf16 for out).
// ---------------------------------------------------------------------------
__global__ __launch_bounds__(256) void prep_kernel(
    const float* __restrict__ wth, const float* __restrict__ wph,
    const float* __restrict__ wg,  const float* __restrict__ ww,
    short* __restrict__ wq, short* __restrict__ wwb)
{
    int t = blockIdx.x * 256 + threadIdx.x;
    if (t < 12288) {                       // 3 x 128 x 32 16B-blocks
        int s  = t >> 12;
        int r  = t & 4095;
        int o  = r >> 5;
        int j  = r & 31;
        int k  = j >> 3, jj = j & 7;
        const float* W = (s == 0) ? wth : (s == 1) ? wph : wg;
        float sc = (s == 0) ? LOG2E : 1.0f;
        const float* src = &W[(size_t)o * CIN + k * 64 + jj * 8];
        bf16x8 d;
        #pragma unroll
        for (int i = 0; i < 8; ++i) d[i] = f2bf(src[i] * sc);
        size_t doff = (size_t)s * 65536 + (size_t)k * 16384
                    + (size_t)o * 128 + (size_t)((jj ^ (o & 7)) << 4);
        *(bf16x8*)((char*)wq + doff) = d;
    } else if (t < 16384) {                // ww: 256 x 16 16B-blocks
        int r = t - 12288;
        int o = r >> 4, j = r & 15;
        const float* src = &ww[(size_t)o * CI + j * 8];
        bf16x8 d;
        #pragma unroll
        for (int i = 0; i < 8; ++i) d[i] = f2bf(src[i]);
        *(bf16x8*)&wwb[(size_t)o * CI + j * 8] = d;
    }
}

// ---------------------------------------------------------------------------
// Kernel 1 (FUSED): BN + three 1x1 projections. Q,K stored as FP8 e4m3
// (rows of 128 B) for the MX QK^T; V^T stored bf16 (b,c,n).
// ---------------------------------------------------------------------------
__global__ __launch_bounds__(256, 2) void proj_kernel(
    const float* __restrict__ x,
    const float* __restrict__ gamma, const float* __restrict__ beta,
    const float* __restrict__ mean,  const float* __restrict__ var,
    const short* __restrict__ wq,
    const float* __restrict__ bth, const float* __restrict__ bph,
    const float* __restrict__ bg,
    unsigned char* __restrict__ qp, unsigned char* __restrict__ kp,
    short* __restrict__ vtp)
{
    __shared__ float s_scale[CIN];
    __shared__ float s_shift[CIN];
    __shared__ __align__(16) short A_lds[64][264];     // [n][c] full K, pad 264
    __shared__ __align__(16) char  B_sh[2][128 * 128]; // swizzled chunk, 16KB x2

    const int tid = threadIdx.x;
    const int b   = blockIdx.x & 7;           // batch == XCD
    const int n0  = (blockIdx.x >> 3) * 64;
    const int w = tid >> 6, lane = tid & 63, lr = lane & 15, lg = lane >> 4;

    {   // BN scale/shift (256 threads == 256 channels)
        float sc = gamma[tid] * rsqrtf(var[tid] + EPSV);
        s_scale[tid] = sc;
        s_shift[tid] = beta[tid] - mean[tid] * sc;
    }
    __syncthreads();

    // stage BN(x) -> A_lds[n][c] bf16, once; pair-column u32 writes
    #pragma unroll
    for (int p = 0; p < 8; ++p) {
        int c2 = p * 32 + (tid >> 4) * 2;
        int n4 = (tid & 15) * 4;
        f32x4 v0 = *(const f32x4*)&x[((size_t)b * CIN + c2) * NN + n0 + n4];
        f32x4 v1 = *(const f32x4*)&x[((size_t)b * CIN + c2 + 1) * NN + n0 + n4];
        float sc0 = s_scale[c2],     sh0 = s_shift[c2];
        float sc1 = s_scale[c2 + 1], sh1 = s_shift[c2 + 1];
        #pragma unroll
        for (int i = 0; i < 4; ++i) {
            uint32_t pk = cvt_pk_bf16(v0[i] * sc0 + sh0, v1[i] * sc1 + sh1);
            *(uint32_t*)&A_lds[n4 + i][c2] = pk;
        }
    }

    auto stageB = [&](int buf, int idx) {
        const char* src = (const char*)wq + (size_t)idx * 16384;
        #pragma unroll
        for (int r = 0; r < 4; ++r) {
            __builtin_amdgcn_global_load_lds(
                (const __attribute__((address_space(1))) void*)
                    (src + ((((r * 4 + w) << 6) + lane) << 4)),
                (__attribute__((address_space(3))) void*)&B_sh[buf][(r * 4 + w) << 10],
                16, 0, 0);
        }
    };
    stageB(0, 0);
    __syncthreads();

    const float* BS[3] = {bth, bph, bg};
    f32x4 acc[8];

    for (int idx = 0; idx < 12; ++idx) {
        const int s = idx >> 2, k = idx & 3, buf = idx & 1;
        if (idx + 1 < 12) stageB(buf ^ 1, idx + 1);

        if (k == 0) {
            #pragma unroll
            for (int i = 0; i < 8; ++i) acc[i] = (f32x4){0.f, 0.f, 0.f, 0.f};
        }
        const int c0 = k * 64;
        bf16x8 a0 = *(const bf16x8*)&A_lds[w * 16 + lr][c0 + lg * 8];
        bf16x8 a1 = *(const bf16x8*)&A_lds[w * 16 + lr][c0 + 32 + lg * 8];
        const char* Bc = B_sh[buf];
        #pragma unroll
        for (int ot = 0; ot < 8; ++ot) {
            const int o  = ot * 16 + lr;
            const int sw = (o & 7) << 4;
            bf16x8 b0 = *(const bf16x8*)(Bc + o * 128 + ((lg << 4) ^ sw));
            bf16x8 b1 = *(const bf16x8*)(Bc + o * 128 + (((4 + lg) << 4) ^ sw));
            acc[ot] = __builtin_amdgcn_mfma_f32_16x16x32_bf16(a0, b0, acc[ot], 0, 0, 0);
            acc[ot] = __builtin_amdgcn_mfma_f32_16x16x32_bf16(a1, b1, acc[ot], 0, 0, 0);
        }

        if (k == 3) {
            if (s < 2) {   // Q / K: fp8 e4m3 bytes, rows of 128 B
                unsigned char* dst = (s == 0) ? qp : kp;
                const float om = (s == 0) ? LOG2E : 1.0f;
                #pragma unroll
                for (int ot = 0; ot < 8; ++ot) {
                    float bias = BS[s][ot * 16 + lr] * om;
                    #pragma unroll
                    for (int rr = 0; rr < 4; ++rr) {
                        int n = n0 + w * 16 + lg * 4 + rr;
                        uint32_t pk = __builtin_amdgcn_cvt_pk_fp8_f32(
                            acc[ot][rr] + bias, 0.f, 0, false);
                        dst[((size_t)b * NN + n) * 128 + ot * 16 + lr] =
                            (unsigned char)(pk & 0xFF);
                    }
                }
            } else {       // V^T (b,c,n) bf16
                #pragma unroll
                for (int ot = 0; ot < 8; ++ot) {
                    float bias = BS[s][ot * 16 + lr];
                    bf16x4 pk;
                    #pragma unroll
                    for (int rr = 0; rr < 4; ++rr) pk[rr] = f2bf(acc[ot][rr] + bias);
                    *(bf16x4*)&vtp[((size_t)b * CI + ot * 16 + lr) * NN + n0 + w * 16 + lg * 4] = pk;
                }
            }
        }
        __syncthreads();
    }
}

// ---------------------------------------------------------------------------
// Kernel 2: flash attention — R9/R11 body, QK^T via MX-fp8 K=128 (one
// mfma_scale per S-tile, scale=1.0). Layout-agnostic: K-frag and Q-frag use
// the identical (lane,elem)->c convention, so the dot product pairs c with c
// regardless of HW k-ordering. PV stays bf16. SPLIT-KV x2, 2 blk/CU,
// 2 waves/SIMD. Do NOT raise occupancy (R6/7/8); do NOT split PV (R10).
// ---------------------------------------------------------------------------
__global__ __launch_bounds__(256, 2) void attn_kernel(
    const unsigned char* __restrict__ qp, const unsigned char* __restrict__ kp,
    const short* __restrict__ vtp, short* __restrict__ yh,
    float* __restrict__ ml)
{
    __shared__ __align__(16) char K_sh[2][64 * 128];    // fp8 [m][c] swizzled, 8KB x2
    __shared__ __align__(16) char V_sh[2][128 * 128];   // bf16 [c][m] swizzled, 16KB x2
    __shared__ __align__(16) char P_sh[4][16 * 128];    // per-wave single P buf

    const int tid  = threadIdx.x;
    const int b    = blockIdx.x & 7;            // batch == XCD (round-robin)
    const int half = (blockIdx.x >> 3) & 1;     // kv half
    const int n0   = (blockIdx.x >> 4) * 128;
    const int w = tid >> 6, lane = tid & 63, lr = lane & 15, lg = lane >> 4;
    const int NT = NN / 128;                    // 32 kv tiles per half
    const int t0 = half * NT;

    // loop-carried per-lane global source pointers (pre-swizzled), LDS dest linear
    const unsigned char* kgp[2];
    const char* vgp[4];
    #pragma unroll
    for (int r = 0; r < 2; ++r) {               // K fp8: 512 16B-chunks/tile
        int idx = ((r * 4 + w) << 6) + lane;    // 0..511
        int mm  = idx >> 3, cb = (idx & 7) << 4;
        kgp[r] = kp + (size_t)b * NN * 128 + (size_t)(t0 * 64 + mm) * 128
               + (cb ^ ((mm & 7) << 4));
    }
    #pragma unroll
    for (int r = 0; r < 4; ++r) {               // V bf16: 1024 chunks/tile
        int idx = ((r * 4 + w) << 6) + lane;
        int cc = idx >> 3, cbv = (idx & 7) << 4;
        vgp[r] = (const char*)(vtp + (size_t)b * CI * NN + (size_t)t0 * 64
                               + (size_t)cc * NN) + (cbv ^ ((cc & 7) << 4));
    }
    auto stage = [&](int bufi) {
        #pragma unroll
        for (int r = 0; r < 2; ++r) {
            __builtin_amdgcn_global_load_lds(
                (const __attribute__((address_space(1))) void*)kgp[r],
                (__attribute__((address_space(3))) void*)&K_sh[bufi][(r * 4 + w) << 10],
                16, 0, 0);
            kgp[r] += 64 * 128;       // next K tile: 8 KB
        }
        #pragma unroll
        for (int r = 0; r < 4; ++r) {
            __builtin_amdgcn_global_load_lds(
                (const __attribute__((address_space(1))) void*)vgp[r],
                (__attribute__((address_space(3))) void*)&V_sh[bufi][(r * 4 + w) << 10],
                16, 0, 0);
            vgp[r] += 64 * 2;         // next V tile: 128 B
        }
    };

    // Q strips in registers: fp8 B-frag, 32 B/lane = 8 dwords per strip
    i32x8 qf8[2];
    #pragma unroll
    for (int s = 0; s < 2; ++s) {
        const unsigned char* qrow = qp + ((size_t)b * NN + n0 + w * 32 + s * 16 + lr) * 128;
        i32x4 lo = *(const i32x4*)(qrow + lg * 32);
        i32x4 hi = *(const i32x4*)(qrow + lg * 32 + 16);
        qf8[s] = (i32x8){lo[0], lo[1], lo[2], lo[3], hi[0], hi[1], hi[2], hi[3]};
    }

    f32x4 yacc[2][8];
    #pragma unroll
    for (int s = 0; s < 2; ++s)
        #pragma unroll
        for (int i = 0; i < 8; ++i) yacc[s][i] = (f32x4){0.f, 0.f, 0.f, 0.f};
    float m_run[2] = {-__builtin_huge_valf(), -__builtin_huge_valf()};
    float l_run[2] = {0.f, 0.f};   // per-lane partials; reduced after the loop

    stage(0);
    __syncthreads();

    for (int t = 0; t < NT; ++t) {
        const int cur = t & 1;
        if (t + 1 < NT) stage(cur ^ 1);   // issue before compute

        // S^T = K Q : one mfma_scale (K=128=D) per (mt, strip); scale = 1.0
        const char* Kc = K_sh[cur];
        f32x4 sa[2][4];
        __builtin_amdgcn_s_setprio(1);
        #pragma unroll
        for (int mt = 0; mt < 4; ++mt) {
            const int mrow = mt * 16 + lr;
            const int sw   = (mrow & 7) << 4;
            const char* kr = Kc + mrow * 128;
            i32x4 k0 = *(const i32x4*)(kr + ((lg * 32) ^ sw));
            i32x4 k1 = *(const i32x4*)(kr + ((lg * 32 + 16) ^ sw));
            i32x8 kf8 = (i32x8){k0[0], k0[1], k0[2], k0[3], k1[0], k1[1], k1[2], k1[3]};
            sa[0][mt] = __builtin_amdgcn_mfma_scale_f32_16x16x128_f8f6f4(
                kf8, qf8[0], (f32x4){0.f, 0.f, 0.f, 0.f},
                0, 0, 0, 0x7F7F7F7F, 0, 0x7F7F7F7F);
            sa[1][mt] = __builtin_amdgcn_mfma_scale_f32_16x16x128_f8f6f4(
                kf8, qf8[1], (f32x4){0.f, 0.f, 0.f, 0.f},
                0, 0, 0, 0x7F7F7F7F, 0, 0x7F7F7F7F);
        }
        __builtin_amdgcn_s_setprio(0);

        // lazy online softmax: per-lane partial max only on the common path
        float tml[2];
        #pragma unroll
        for (int s = 0; s < 2; ++s) {
            float tm = fmaxf(fmaxf(fmaxf(sa[s][0][0], sa[s][0][1]), fmaxf(sa[s][0][2], sa[s][0][3])),
                             fmaxf(fmaxf(sa[s][1][0], sa[s][1][1]), fmaxf(sa[s][1][2], sa[s][1][3])));
            tm = fmaxf(tm, fmaxf(fmaxf(fmaxf(sa[s][2][0], sa[s][2][1]), fmaxf(sa[s][2][2], sa[s][2][3])),
                                 fmaxf(fmaxf(sa[s][3][0], sa[s][3][1]), fmaxf(sa[s][3][2], sa[s][3][3]))));
            tml[s] = tm;
        }
        if (__any((tml[0] - m_run[0] > 8.f) || (tml[1] - m_run[1] > 8.f))) {
            #pragma unroll
            for (int s = 0; s < 2; ++s) {
                float tm = tml[s];
                tm = fmaxf(tm, __shfl_xor(tm, 16));
                tm = fmaxf(tm, __shfl_xor(tm, 32));
                float mnew = fmaxf(m_run[s], tm);
                float sc   = __builtin_amdgcn_exp2f(m_run[s] - mnew);
                m_run[s] = mnew;
                l_run[s] *= sc;
                #pragma unroll
                for (int rr = 0; rr < 4; ++rr) {
                    float scb = __shfl(sc, (lane & 48) | (lg * 4 + rr));
                    #pragma unroll
                    for (int ct = 0; ct < 8; ++ct) yacc[s][ct][rr] *= scb;
                }
            }
        }

        // V-frags into regs early (shared by both strips)
        const char* Vc = V_sh[cur];
        bf16x8 vf[2][8];
        #pragma unroll
        for (int kf = 0; kf < 2; ++kf)
            #pragma unroll
            for (int ct = 0; ct < 8; ++ct) {
                const int vr = ct * 16 + lr;
                vf[kf][ct] = *(const bf16x8*)(Vc + (vr << 7) +
                                              ((kf * 64 + lg * 16) ^ ((vr & 7) << 4)));
            }

        // strip 0: exp2 + cvt_pk pack into per-wave P buf, then read pa0
        char* Pb = P_sh[w];
        const int psw = (lr & 7) << 4;
        bf16x8 pa0[2], pa1[2];
        {
            float rs = 0.f;
            #pragma unroll
            for (int mt = 0; mt < 4; ++mt) {
                float e0 = __builtin_amdgcn_exp2f(sa[0][mt][0] - m_run[0]);
                float e1 = __builtin_amdgcn_exp2f(sa[0][mt][1] - m_run[0]);
                float e2 = __builtin_amdgcn_exp2f(sa[0][mt][2] - m_run[0]);
                float e3 = __builtin_amdgcn_exp2f(sa[0][mt][3] - m_run[0]);
                rs += (e0 + e1) + (e2 + e3);
                u32x2 pk = {cvt_pk_bf16(e0, e1), cvt_pk_bf16(e2, e3)};
                *(u32x2*)(Pb + lr * 128 + ((mt * 32 + lg * 8) ^ psw)) = pk;
            }
            l_run[0] += rs;
        }
        asm volatile("" ::: "memory");
        #pragma unroll
        for (int kf = 0; kf < 2; ++kf)
            pa0[kf] = *(const bf16x8*)(Pb + lr * 128 + ((kf * 64 + lg * 16) ^ psw));
        asm volatile("" ::: "memory");

        // strip 1: overwrite same P buf (same-wave DS is in-order; fenced)
        {
            float rs = 0.f;
            #pragma unroll
            for (int mt = 0; mt < 4; ++mt) {
                float e0 = __builtin_amdgcn_exp2f(sa[1][mt][0] - m_run[1]);
                float e1 = __builtin_amdgcn_exp2f(sa[1][mt][1] - m_run[1]);
                float e2 = __builtin_amdgcn_exp2f(sa[1][mt][2] - m_run[1]);
                float e3 = __builtin_amdgcn_exp2f(sa[1][mt][3] - m_run[1]);
                rs += (e0 + e1) + (e2 + e3);
                u32x2 pk = {cvt_pk_bf16(e0, e1), cvt_pk_bf16(e2, e3)};
                *(u32x2*)(Pb + lr * 128 + ((mt * 32 + lg * 8) ^ psw)) = pk;
            }
            l_run[1] += rs;
        }
        asm volatile("" ::: "memory");
        #pragma unroll
        for (int kf = 0; kf < 2; ++kf)
            pa1[kf] = *(const bf16x8*)(Pb + lr * 128 + ((kf * 64 + lg * 16) ^ psw));

        // Y += P V  (single MFMA cluster, both strips interleaved — R9 form)
        __builtin_amdgcn_s_setprio(1);
        #pragma unroll
        for (int kf = 0; kf < 2; ++kf)
            #pragma unroll
            for (int ct = 0; ct < 8; ++ct) {
                yacc[0][ct] = __builtin_amdgcn_mfma_f32_16x16x32_bf16(pa0[kf], vf[kf][ct], yacc[0][ct], 0, 0, 0);
                yacc[1][ct] = __builtin_amdgcn_mfma_f32_16x16x32_bf16(pa1[kf], vf[kf][ct], yacc[1][ct], 0, 0, 0);
            }
        __builtin_amdgcn_s_setprio(0);

        __syncthreads();   // drains vmcnt: next tile staged; buf[cur] reads done
    }

    // reduce l across the 4 lane-groups (deferred from the loop)
    #pragma unroll
    for (int s = 0; s < 2; ++s) {
        float lt = l_run[s];
        lt += __shfl_xor(lt, 16);
        lt += __shfl_xor(lt, 32);
        l_run[s] = lt;
    }

    // store UNNORMALIZED partial Yhat (bf16) + (m,l) per q-row
    short* yb = yh + ((size_t)half * BB + b) * NN * (size_t)CI;
    #pragma unroll
    for (int s = 0; s < 2; ++s) {
        #pragma unroll
        for (int rr = 0; rr < 4; ++rr) {
            int n = n0 + w * 32 + s * 16 + lg * 4 + rr;
            #pragma unroll
            for (int ct = 0; ct < 8; ++ct)
                yb[(size_t)n * CI + ct * 16 + lr] = f2bf(yacc[s][ct][rr]);
        }
    }
    if (lg == 0) {
        #pragma unroll
        for (int s = 0; s < 2; ++s) {
            int n = n0 + w * 32 + s * 16 + lr;
            f32x2 v = {m_run[s], l_run[s]};
            *(f32x2*)&ml[(((size_t)half * BB + b) * NN + n) * 2] = v;
        }
    }
}

// ---------------------------------------------------------------------------
// Kernel 2b (fallback path): merge the two KV-half partials -> Y^T bf16
// ---------------------------------------------------------------------------
__global__ __launch_bounds__(256) void merge_kernel(
    const short* __restrict__ yh, const float* __restrict__ ml,
    short* __restrict__ yp)
{
    const int tid = threadIdx.x;
    const int row = blockIdx.x * 8 + (tid >> 5);
    const int c4  = (tid & 31) * 4;
    const size_t H = (size_t)BB * NN * CI;
    const size_t R = (size_t)BB * NN * 2;

    float m0 = ml[(size_t)row * 2],     l0 = ml[(size_t)row * 2 + 1];
    float m1 = ml[R + (size_t)row * 2], l1 = ml[R + (size_t)row * 2 + 1];
    float mm = fmaxf(m0, m1);
    float w0 = __builtin_amdgcn_exp2f(m0 - mm);
    float w1 = __builtin_amdgcn_exp2f(m1 - mm);
    float inv = 1.0f / (l0 * w0 + l1 * w1);
    w0 *= inv; w1 *= inv;

    bf16x4 a  = *(const bf16x4*)&yh[(size_t)row * CI + c4];
    bf16x4 bb = *(const bf16x4*)&yh[H + (size_t)row * CI + c4];
    bf16x4 o;
    #pragma unroll
    for (int i = 0; i < 4; ++i) o[i] = f2bf(bf2f(a[i]) * w0 + bf2f(bb[i]) * w1);
    *(bf16x4*)&yp[(size_t)row * CI + c4] = o;
}

// ---------------------------------------------------------------------------
// Kernel 3: out = w_w @ Y + b_w + x, 128x128 tiles, XCD-pinned. w_w from
// prepped bf16. MERGED==0: fuse the partial merge into Y staging.
// ---------------------------------------------------------------------------
template <int MERGED>
__global__ __launch_bounds__(256) void out_kernel(
    const short* __restrict__ ysrc, const float* __restrict__ ml,
    const short* __restrict__ wwb, const float* __restrict__ bw,
    const float* __restrict__ x, float* __restrict__ out)
{
    __shared__ __align__(16) short A_lds[128][136];   // w_w [o][c]
    __shared__ __align__(16) short Bl[128][136];      // Y^T [n][c]

    const int tid  = threadIdx.x;
    const int b    = blockIdx.x & 7;
    const int rest = blockIdx.x >> 3;
    const int ob   = rest & 1;
    const int nn   = (rest >> 1) * 128;
    const int o0   = ob * 128;
    const int w = tid >> 6, lane = tid & 63, lr = lane & 15, lg = lane >> 4;

    #pragma unroll
    for (int pass = 0; pass < 8; ++pass) {
        int o  = pass * 16 + (tid >> 4);
        int c8 = (tid & 15) * 8;
        *(bf16x8*)&A_lds[o][c8] = *(const bf16x8*)&wwb[(size_t)(o0 + o) * CI + c8];
    }
    #pragma unroll
    for (int pass = 0; pass < 8; ++pass) {
        int n  = pass * 16 + (tid >> 4);
        int c8 = (tid & 15) * 8;
        size_t row = (size_t)b * NN + nn + n;
        if (MERGED) {
            *(bf16x8*)&Bl[n][c8] = *(const bf16x8*)&ysrc[row * CI + c8];
        } else {
            const size_t H = (size_t)BB * NN * CI;
            const size_t R = (size_t)BB * NN * 2;
            f32x2 v0 = *(const f32x2*)&ml[row * 2];
            f32x2 v1 = *(const f32x2*)&ml[R + row * 2];
            float mm = fmaxf(v0[0], v1[0]);
            float w0 = __builtin_amdgcn_exp2f(v0[0] - mm);
            float w1 = __builtin_amdgcn_exp2f(v1[0] - mm);
            float inv = 1.0f / (v0[1] * w0 + v1[1] * w1);
            w0 *= inv; w1 *= inv;
            bf16x8 a  = *(const bf16x8*)&ysrc[row * CI + c8];
            bf16x8 b2 = *(const bf16x8*)&ysrc[H + row * CI + c8];
            bf16x8 ov;
            #pragma unroll
            for (int i = 0; i < 4; ++i) {
                float lo = bf2f(a[2*i]) * w0 + bf2f(b2[2*i]) * w1;
                float hi = bf2f(a[2*i+1]) * w0 + bf2f(b2[2*i+1]) * w1;
                uint32_t pk = cvt_pk_bf16(lo, hi);
                ov[2*i]   = (short)(pk & 0xFFFF);
                ov[2*i+1] = (short)(pk >> 16);
            }
            *(bf16x8*)&Bl[n][c8] = ov;
        }
    }
    __syncthreads();

    f32x4 acc[2][8];
    #pragma unroll
    for (int i = 0; i < 2; ++i)
        #pragma unroll
        for (int j = 0; j < 8; ++j) acc[i][j] = (f32x4){0.f, 0.f, 0.f, 0.f};

    #pragma unroll
    for (int kf = 0; kf < 4; ++kf) {
        bf16x8 a0 = *(const bf16x8*)&A_lds[w * 32 + lr][kf * 32 + lg * 8];
        bf16x8 a1 = *(const bf16x8*)&A_lds[w * 32 + 16 + lr][kf * 32 + lg * 8];
        #pragma unroll
        for (int nt = 0; nt < 8; ++nt) {
            bf16x8 bv = *(const bf16x8*)&Bl[nt * 16 + lr][kf * 32 + lg * 8];
            acc[0][nt] = __builtin_amdgcn_mfma_f32_16x16x32_bf16(a0, bv, acc[0][nt], 0, 0, 0);
            acc[1][nt] = __builtin_amdgcn_mfma_f32_16x16x32_bf16(a1, bv, acc[1][nt], 0, 0, 0);
        }
    }

    #pragma unroll
    for (int wo = 0; wo < 2; ++wo) {
        #pragma unroll
        for (int rr = 0; rr < 4; ++rr) {
            int o = o0 + w * 32 + wo * 16 + lg * 4 + rr;
            float bias = bw[o];
            #pragma unroll
            for (int nt = 0; nt < 8; ++nt) {
                size_t idx = ((size_t)b * CIN + o) * NN + nn + nt * 16 + lr;
                out[idx] = acc[wo][nt][rr] + bias + x[idx];
            }
        }
    }
}

// ---------------------------------------------------------------------------
extern "C" void kernel_launch(void* const* d_in, const int* in_sizes, int n_in,
                              void* d_out, int out_size, void* d_ws, size_t ws_size,
                              hipStream_t stream)
{
    const float* x     = (const float*)d_in[0];
    const float* gamma = (const float*)d_in[1];
    const float* beta  = (const float*)d_in[2];
    const float* mean  = (const float*)d_in[3];
    const float* var   = (const float*)d_in[4];
    const float* wg    = (const float*)d_in[5];
    const float* bg    = (const float*)d_in[6];
    const float* wth   = (const float*)d_in[7];
    const float* bth   = (const float*)d_in[8];
    const float* wph   = (const float*)d_in[9];
    const float* bph   = (const float*)d_in[10];
    const float* ww    = (const float*)d_in[11];
    const float* bw    = (const float*)d_in[12];

    // ws layout (offsets unchanged vs R12; qp/kp slots now half-used fp8):
    // qp fp8 4MB @0 | kp fp8 4MB @8MB | vtp 8MB @16MB | ml 0.5MB @24MB |
    // wq @24.5MiB | wwb | yh 16MB @25MiB.
    const size_t seg = (size_t)BB * NN * CI;
    unsigned char* qp = (unsigned char*)d_ws;
    unsigned char* kp = (unsigned char*)d_ws + seg * sizeof(short);
    short* vtp = (short*)((char*)d_ws + 2 * seg * sizeof(short));
    float* ml  = (float*)((char*)d_ws + 3 * seg * sizeof(short));
    short* wq  = (short*)((char*)d_ws + 25690112);
    short* wwb = (short*)((char*)d_ws + 25690112 + 196608);
    const size_t yh_off = 25u * 1024 * 1024;
    const bool fused = ws_size >= yh_off + 2 * seg * sizeof(short);
    short* yh = fused ? (short*)((char*)d_ws + yh_off) : (short*)d_out;
    (void)in_sizes; (void)n_in; (void)out_size;

    prep_kernel<<<64, 256, 0, stream>>>(wth, wph, wg, ww, wq, wwb);
    proj_kernel<<<BB * (NN / 64), 256, 0, stream>>>(
        x, gamma, beta, mean, var, wq, bth, bph, bg, qp, kp, vtp);
    attn_kernel<<<2 * BB * (NN / 128), 256, 0, stream>>>(qp, kp, vtp, yh, ml);
    if (fused) {
        out_kernel<0><<<2 * BB * (NN / 128), 256, 0, stream>>>(
            yh, ml, wwb, bw, x, (float*)d_out);
    } else {
        short* yp = (short*)d_ws;   // reuse: q dead after attn
        merge_kernel<<<BB * NN / 8, 256, 0, stream>>>(yh, ml, yp);
        out_kernel<1><<<2 * BB * (NN / 128), 256, 0, stream>>>(
            yp, ml, wwb, bw, x, (float*)d_out);
    }
}

// Round 14
// 100.814 us; speedup vs baseline: 4.4151x; 1.0262x over previous
//
#include <hip/hip_runtime.h>
#include <hip/hip_bf16.h>
#include <stdint.h>

#define BB   8
#define CIN  256
#define CI   128
#define NN   4096
#define EPSV 1e-5f
#define LOG2E 1.44269504088896340736f

typedef __attribute__((ext_vector_type(8))) short bf16x8;
typedef __attribute__((ext_vector_type(4))) short bf16x4;
typedef __attribute__((ext_vector_type(4))) float f32x4;
typedef __attribute__((ext_vector_type(2))) float f32x2;
typedef __attribute__((ext_vector_type(2))) unsigned int u32x2;
typedef __attribute__((ext_vector_type(4))) int i32x4;
typedef __attribute__((ext_vector_type(8))) int i32x8;

static __device__ inline short f2bf(float f) {
    uint32_t u = __builtin_bit_cast(uint32_t, f);
    u += 0x7FFFu + ((u >> 16) & 1u);   // round-to-nearest-even
    return (short)(u >> 16);
}

static __device__ inline float bf2f(short s) {
    uint32_t u = ((uint32_t)(uint16_t)s) << 16;
    return __builtin_bit_cast(float, u);
}

static __device__ inline uint32_t cvt_pk_bf16(float lo, float hi) {
    uint32_t r;
    asm("v_cvt_pk_bf16_f32 %0, %1, %2" : "=v"(r) : "v"(lo), "v"(hi));
    return r;
}

// ---------------------------------------------------------------------------
// Kernel 0 (PREP): weights -> bf16 once (wq pre-swizzled; wth pre-scaled by
// log2e; wwb plain bf16 for out).
// ---------------------------------------------------------------------------
__global__ __launch_bounds__(256) void prep_kernel(
    const float* __restrict__ wth, const float* __restrict__ wph,
    const float* __restrict__ wg,  const float* __restrict__ ww,
    short* __restrict__ wq, short* __restrict__ wwb)
{
    int t = blockIdx.x * 256 + threadIdx.x;
    if (t < 12288) {                       // 3 x 128 x 32 16B-blocks
        int s  = t >> 12;
        int r  = t & 4095;
        int o  = r >> 5;
        int j  = r & 31;
        int k  = j >> 3, jj = j & 7;
        const float* W = (s == 0) ? wth : (s == 1) ? wph : wg;
        float sc = (s == 0) ? LOG2E : 1.0f;
        const float* src = &W[(size_t)o * CIN + k * 64 + jj * 8];
        bf16x8 d;
        #pragma unroll
        for (int i = 0; i < 8; ++i) d[i] = f2bf(src[i] * sc);
        size_t doff = (size_t)s * 65536 + (size_t)k * 16384
                    + (size_t)o * 128 + (size_t)((jj ^ (o & 7)) << 4);
        *(bf16x8*)((char*)wq + doff) = d;
    } else if (t < 16384) {                // ww: 256 x 16 16B-blocks
        int r = t - 12288;
        int o = r >> 4, j = r & 15;
        const float* src = &ww[(size_t)o * CI + j * 8];
        bf16x8 d;
        #pragma unroll
        for (int i = 0; i < 8; ++i) d[i] = f2bf(src[i]);
        *(bf16x8*)&wwb[(size_t)o * CI + j * 8] = d;
    }
}

// ---------------------------------------------------------------------------
// Kernel 1 (FUSED): BN + three 1x1 projections. Q,K AND V^T stored as FP8
// e4m3 (Q/K rows of 128 B; V^T (b,c,n) 1 B/elem).
// ---------------------------------------------------------------------------
__global__ __launch_bounds__(256, 2) void proj_kernel(
    const float* __restrict__ x,
    const float* __restrict__ gamma, const float* __restrict__ beta,
    const float* __restrict__ mean,  const float* __restrict__ var,
    const short* __restrict__ wq,
    const float* __restrict__ bth, const float* __restrict__ bph,
    const float* __restrict__ bg,
    unsigned char* __restrict__ qp, unsigned char* __restrict__ kp,
    unsigned char* __restrict__ vt8)
{
    __shared__ float s_scale[CIN];
    __shared__ float s_shift[CIN];
    __shared__ __align__(16) short A_lds[64][264];     // [n][c] full K, pad 264
    __shared__ __align__(16) char  B_sh[2][128 * 128]; // swizzled chunk, 16KB x2

    const int tid = threadIdx.x;
    const int b   = blockIdx.x & 7;           // batch == XCD
    const int n0  = (blockIdx.x >> 3) * 64;
    const int w = tid >> 6, lane = tid & 63, lr = lane & 15, lg = lane >> 4;

    {   // BN scale/shift (256 threads == 256 channels)
        float sc = gamma[tid] * rsqrtf(var[tid] + EPSV);
        s_scale[tid] = sc;
        s_shift[tid] = beta[tid] - mean[tid] * sc;
    }
    __syncthreads();

    // stage BN(x) -> A_lds[n][c] bf16, once; pair-column u32 writes
    #pragma unroll
    for (int p = 0; p < 8; ++p) {
        int c2 = p * 32 + (tid >> 4) * 2;
        int n4 = (tid & 15) * 4;
        f32x4 v0 = *(const f32x4*)&x[((size_t)b * CIN + c2) * NN + n0 + n4];
        f32x4 v1 = *(const f32x4*)&x[((size_t)b * CIN + c2 + 1) * NN + n0 + n4];
        float sc0 = s_scale[c2],     sh0 = s_shift[c2];
        float sc1 = s_scale[c2 + 1], sh1 = s_shift[c2 + 1];
        #pragma unroll
        for (int i = 0; i < 4; ++i) {
            uint32_t pk = cvt_pk_bf16(v0[i] * sc0 + sh0, v1[i] * sc1 + sh1);
            *(uint32_t*)&A_lds[n4 + i][c2] = pk;
        }
    }

    auto stageB = [&](int buf, int idx) {
        const char* src = (const char*)wq + (size_t)idx * 16384;
        #pragma unroll
        for (int r = 0; r < 4; ++r) {
            __builtin_amdgcn_global_load_lds(
                (const __attribute__((address_space(1))) void*)
                    (src + ((((r * 4 + w) << 6) + lane) << 4)),
                (__attribute__((address_space(3))) void*)&B_sh[buf][(r * 4 + w) << 10],
                16, 0, 0);
        }
    };
    stageB(0, 0);
    __syncthreads();

    const float* BS[3] = {bth, bph, bg};
    f32x4 acc[8];

    for (int idx = 0; idx < 12; ++idx) {
        const int s = idx >> 2, k = idx & 3, buf = idx & 1;
        if (idx + 1 < 12) stageB(buf ^ 1, idx + 1);

        if (k == 0) {
            #pragma unroll
            for (int i = 0; i < 8; ++i) acc[i] = (f32x4){0.f, 0.f, 0.f, 0.f};
        }
        const int c0 = k * 64;
        bf16x8 a0 = *(const bf16x8*)&A_lds[w * 16 + lr][c0 + lg * 8];
        bf16x8 a1 = *(const bf16x8*)&A_lds[w * 16 + lr][c0 + 32 + lg * 8];
        const char* Bc = B_sh[buf];
        #pragma unroll
        for (int ot = 0; ot < 8; ++ot) {
            const int o  = ot * 16 + lr;
            const int sw = (o & 7) << 4;
            bf16x8 b0 = *(const bf16x8*)(Bc + o * 128 + ((lg << 4) ^ sw));
            bf16x8 b1 = *(const bf16x8*)(Bc + o * 128 + (((4 + lg) << 4) ^ sw));
            acc[ot] = __builtin_amdgcn_mfma_f32_16x16x32_bf16(a0, b0, acc[ot], 0, 0, 0);
            acc[ot] = __builtin_amdgcn_mfma_f32_16x16x32_bf16(a1, b1, acc[ot], 0, 0, 0);
        }

        if (k == 3) {
            if (s < 2) {   // Q / K: fp8 e4m3 bytes, rows of 128 B
                unsigned char* dst = (s == 0) ? qp : kp;
                const float om = (s == 0) ? LOG2E : 1.0f;
                #pragma unroll
                for (int ot = 0; ot < 8; ++ot) {
                    float bias = BS[s][ot * 16 + lr] * om;
                    #pragma unroll
                    for (int rr = 0; rr < 4; ++rr) {
                        int n = n0 + w * 16 + lg * 4 + rr;
                        uint32_t pk = __builtin_amdgcn_cvt_pk_fp8_f32(
                            acc[ot][rr] + bias, 0.f, 0, false);
                        dst[((size_t)b * NN + n) * 128 + ot * 16 + lr] =
                            (unsigned char)(pk & 0xFF);
                    }
                }
            } else {       // V^T (b,c,n) fp8: 4 consecutive n -> 1 dword
                #pragma unroll
                for (int ot = 0; ot < 8; ++ot) {
                    float bias = BS[s][ot * 16 + lr];
                    uint32_t d = __builtin_amdgcn_cvt_pk_fp8_f32(
                        acc[ot][0] + bias, acc[ot][1] + bias, 0, false);
                    d = __builtin_amdgcn_cvt_pk_fp8_f32(
                        acc[ot][2] + bias, acc[ot][3] + bias, d, true);
                    *(uint32_t*)&vt8[((size_t)b * CI + ot * 16 + lr) * NN
                                     + n0 + w * 16 + lg * 4] = d;
                }
            }
        }
        __syncthreads();
    }
}

// ---------------------------------------------------------------------------
// Kernel 2: flash attention — all-fp8 MFMA. QK^T: MX-fp8 K=128 per tile
// (R13, proven). PV: pair-wise — P packed fp8 per strip into a 128-B row
// (half per tile); at odd t one mfma_scale 16x16x128 per (ct,strip), K=128
// = 2 tiles of m. V fp8 staged per pair (16KB dbuf). Rescale checks at even
// t only, THR=4 (fp8 P <= ~2^6 << 448). SPLIT-KV x2, 2 blk/CU, 2 waves/SIMD.
// Do NOT raise occupancy (R6/7/8); do NOT split MFMA clusters (R10).
// ---------------------------------------------------------------------------
__global__ __launch_bounds__(256, 2) void attn_kernel(
    const unsigned char* __restrict__ qp, const unsigned char* __restrict__ kp,
    const unsigned char* __restrict__ vt8, short* __restrict__ yh,
    float* __restrict__ ml)
{
    __shared__ __align__(16) char K_sh[2][64 * 128];     // fp8 [m][c] swz, 8KB x2
    __shared__ __align__(16) char V_sh[2][128 * 128];    // fp8 [c][m-pair] swz, 16KB x2
    __shared__ __align__(16) char P_sh[4][2][16 * 128];  // fp8 [wave][strip][q][m-pair]

    const int tid  = threadIdx.x;
    const int b    = blockIdx.x & 7;            // batch == XCD (round-robin)
    const int half = (blockIdx.x >> 3) & 1;     // kv half
    const int n0   = (blockIdx.x >> 4) * 128;
    const int w = tid >> 6, lane = tid & 63, lr = lane & 15, lg = lane >> 4;
    const int NT = NN / 128;                    // 32 kv tiles per half
    const int t0 = half * NT;

    // loop-carried per-lane global source pointers (pre-swizzled), LDS dest linear
    const unsigned char* kgp[2];
    const unsigned char* vgp[4];
    #pragma unroll
    for (int r = 0; r < 2; ++r) {               // K fp8: 512 16B-chunks/tile
        int idx = ((r * 4 + w) << 6) + lane;
        int mm  = idx >> 3, cb = (idx & 7) << 4;
        kgp[r] = kp + (size_t)b * NN * 128 + (size_t)(t0 * 64 + mm) * 128
               + (cb ^ ((mm & 7) << 4));
    }
    #pragma unroll
    for (int r = 0; r < 4; ++r) {               // V fp8: 1024 chunks per PAIR
        int idx = ((r * 4 + w) << 6) + lane;
        int cc = idx >> 3, cbv = (idx & 7) << 4;
        vgp[r] = vt8 + (size_t)b * CI * NN + (size_t)cc * NN + t0 * 64
               + (cbv ^ ((cc & 7) << 4));
    }
    auto stageK = [&](int bufi) {
        #pragma unroll
        for (int r = 0; r < 2; ++r) {
            __builtin_amdgcn_global_load_lds(
                (const __attribute__((address_space(1))) void*)kgp[r],
                (__attribute__((address_space(3))) void*)&K_sh[bufi][(r * 4 + w) << 10],
                16, 0, 0);
            kgp[r] += 64 * 128;       // next K tile: 8 KB
        }
    };
    auto stageV = [&](int bufi) {
        #pragma unroll
        for (int r = 0; r < 4; ++r) {
            __builtin_amdgcn_global_load_lds(
                (const __attribute__((address_space(1))) void*)vgp[r],
                (__attribute__((address_space(3))) void*)&V_sh[bufi][(r * 4 + w) << 10],
                16, 0, 0);
            vgp[r] += 128;            // next pair: 128 m-bytes
        }
    };

    // Q strips in registers: fp8 B-frag, 32 B/lane = 8 dwords per strip
    i32x8 qf8[2];
    #pragma unroll
    for (int s = 0; s < 2; ++s) {
        const unsigned char* qrow = qp + ((size_t)b * NN + n0 + w * 32 + s * 16 + lr) * 128;
        i32x4 lo = *(const i32x4*)(qrow + lg * 32);
        i32x4 hi = *(const i32x4*)(qrow + lg * 32 + 16);
        qf8[s] = (i32x8){lo[0], lo[1], lo[2], lo[3], hi[0], hi[1], hi[2], hi[3]};
    }

    f32x4 yacc[2][8];
    #pragma unroll
    for (int s = 0; s < 2; ++s)
        #pragma unroll
        for (int i = 0; i < 8; ++i) yacc[s][i] = (f32x4){0.f, 0.f, 0.f, 0.f};
    float m_run[2] = {-__builtin_huge_valf(), -__builtin_huge_valf()};
    float l_run[2] = {0.f, 0.f};   // per-lane partials; reduced after the loop

    stageK(0);
    stageV(0);
    __syncthreads();

    const int psw = (lr & 7) << 4;

    for (int t = 0; t < NT; ++t) {
        const int kcur = t & 1;
        if (t + 1 < NT) stageK(kcur ^ 1);
        const int p = t >> 1;
        if ((t & 1) == 0 && p + 1 < NT / 2) stageV((p & 1) ^ 1);

        // S^T = K Q : one mfma_scale (K=128=D) per (mt, strip); scale = 1.0
        const char* Kc = K_sh[kcur];
        f32x4 sa[2][4];
        __builtin_amdgcn_s_setprio(1);
        #pragma unroll
        for (int mt = 0; mt < 4; ++mt) {
            const int mrow = mt * 16 + lr;
            const int sw   = (mrow & 7) << 4;
            const char* kr = Kc + mrow * 128;
            i32x4 k0 = *(const i32x4*)(kr + ((lg * 32) ^ sw));
            i32x4 k1 = *(const i32x4*)(kr + ((lg * 32 + 16) ^ sw));
            i32x8 kf8 = (i32x8){k0[0], k0[1], k0[2], k0[3], k1[0], k1[1], k1[2], k1[3]};
            sa[0][mt] = __builtin_amdgcn_mfma_scale_f32_16x16x128_f8f6f4(
                kf8, qf8[0], (f32x4){0.f, 0.f, 0.f, 0.f},
                0, 0, 0, 0x7F7F7F7F, 0, 0x7F7F7F7F);
            sa[1][mt] = __builtin_amdgcn_mfma_scale_f32_16x16x128_f8f6f4(
                kf8, qf8[1], (f32x4){0.f, 0.f, 0.f, 0.f},
                0, 0, 0, 0x7F7F7F7F, 0, 0x7F7F7F7F);
        }
        __builtin_amdgcn_s_setprio(0);

        // lazy online softmax; rescale only at EVEN t (before the pair's P),
        // THR=4 keeps fp8 P well under e4m3 max (448).
        if ((t & 1) == 0) {
            float tml[2];
            #pragma unroll
            for (int s = 0; s < 2; ++s) {
                float tm = fmaxf(fmaxf(fmaxf(sa[s][0][0], sa[s][0][1]), fmaxf(sa[s][0][2], sa[s][0][3])),
                                 fmaxf(fmaxf(sa[s][1][0], sa[s][1][1]), fmaxf(sa[s][1][2], sa[s][1][3])));
                tm = fmaxf(tm, fmaxf(fmaxf(fmaxf(sa[s][2][0], sa[s][2][1]), fmaxf(sa[s][2][2], sa[s][2][3])),
                                     fmaxf(fmaxf(sa[s][3][0], sa[s][3][1]), fmaxf(sa[s][3][2], sa[s][3][3]))));
                tml[s] = tm;
            }
            if (__any((tml[0] - m_run[0] > 4.f) || (tml[1] - m_run[1] > 4.f))) {
                #pragma unroll
                for (int s = 0; s < 2; ++s) {
                    float tm = tml[s];
                    tm = fmaxf(tm, __shfl_xor(tm, 16));
                    tm = fmaxf(tm, __shfl_xor(tm, 32));
                    float mnew = fmaxf(m_run[s], tm);
                    float sc   = __builtin_amdgcn_exp2f(m_run[s] - mnew);
                    m_run[s] = mnew;
                    l_run[s] *= sc;
                    #pragma unroll
                    for (int rr = 0; rr < 4; ++rr) {
                        float scb = __shfl(sc, (lane & 48) | (lg * 4 + rr));
                        #pragma unroll
                        for (int ct = 0; ct < 8; ++ct) yacc[s][ct][rr] *= scb;
                    }
                }
            }
        }

        // P = exp2(S - m) packed fp8 into half (t&1) of the pair row
        const int h64 = (t & 1) << 6;
        #pragma unroll
        for (int s = 0; s < 2; ++s) {
            char* Pb = &P_sh[w][s][0] + lr * 128;
            float rs = 0.f;
            #pragma unroll
            for (int mt = 0; mt < 4; ++mt) {
                float e0 = __builtin_amdgcn_exp2f(sa[s][mt][0] - m_run[s]);
                float e1 = __builtin_amdgcn_exp2f(sa[s][mt][1] - m_run[s]);
                float e2 = __builtin_amdgcn_exp2f(sa[s][mt][2] - m_run[s]);
                float e3 = __builtin_amdgcn_exp2f(sa[s][mt][3] - m_run[s]);
                rs += (e0 + e1) + (e2 + e3);
                uint32_t d = __builtin_amdgcn_cvt_pk_fp8_f32(e0, e1, 0, false);
                d = __builtin_amdgcn_cvt_pk_fp8_f32(e2, e3, d, true);
                *(uint32_t*)(Pb + ((h64 + mt * 16 + lg * 4) ^ psw)) = d;
            }
            l_run[s] += rs;
        }

        if (t & 1) {
            // PV over the pair: K=128 = 2 tiles of m, fp8 P x fp8 V
            asm volatile("" ::: "memory");   // order P writes -> reads (same wave)
            i32x8 pa8[2];
            #pragma unroll
            for (int s = 0; s < 2; ++s) {
                const char* Pb = &P_sh[w][s][0] + lr * 128;
                i32x4 p0 = *(const i32x4*)(Pb + ((lg * 32) ^ psw));
                i32x4 p1 = *(const i32x4*)(Pb + ((lg * 32 + 16) ^ psw));
                pa8[s] = (i32x8){p0[0], p0[1], p0[2], p0[3], p1[0], p1[1], p1[2], p1[3]};
            }
            const char* Vc = V_sh[p & 1];
            __builtin_amdgcn_s_setprio(1);
            #pragma unroll
            for (int ct = 0; ct < 8; ++ct) {
                const char* vrow = Vc + (ct * 16 + lr) * 128;
                i32x4 v0 = *(const i32x4*)(vrow + ((lg * 32) ^ psw));
                i32x4 v1 = *(const i32x4*)(vrow + ((lg * 32 + 16) ^ psw));
                i32x8 vf8 = (i32x8){v0[0], v0[1], v0[2], v0[3], v1[0], v1[1], v1[2], v1[3]};
                yacc[0][ct] = __builtin_amdgcn_mfma_scale_f32_16x16x128_f8f6f4(
                    pa8[0], vf8, yacc[0][ct], 0, 0, 0, 0x7F7F7F7F, 0, 0x7F7F7F7F);
                yacc[1][ct] = __builtin_amdgcn_mfma_scale_f32_16x16x128_f8f6f4(
                    pa8[1], vf8, yacc[1][ct], 0, 0, 0, 0x7F7F7F7F, 0, 0x7F7F7F7F);
            }
            __builtin_amdgcn_s_setprio(0);
        }

        __syncthreads();   // drains vmcnt: staged tiles ready; LDS reads done
    }

    // reduce l across the 4 lane-groups (deferred from the loop)
    #pragma unroll
    for (int s = 0; s < 2; ++s) {
        float lt = l_run[s];
        lt += __shfl_xor(lt, 16);
        lt += __shfl_xor(lt, 32);
        l_run[s] = lt;
    }

    // store UNNORMALIZED partial Yhat (bf16) + (m,l) per q-row
    short* yb = yh + ((size_t)half * BB + b) * NN * (size_t)CI;
    #pragma unroll
    for (int s = 0; s < 2; ++s) {
        #pragma unroll
        for (int rr = 0; rr < 4; ++rr) {
            int n = n0 + w * 32 + s * 16 + lg * 4 + rr;
            #pragma unroll
            for (int ct = 0; ct < 8; ++ct)
                yb[(size_t)n * CI + ct * 16 + lr] = f2bf(yacc[s][ct][rr]);
        }
    }
    if (lg == 0) {
        #pragma unroll
        for (int s = 0; s < 2; ++s) {
            int n = n0 + w * 32 + s * 16 + lr;
            f32x2 v = {m_run[s], l_run[s]};
            *(f32x2*)&ml[(((size_t)half * BB + b) * NN + n) * 2] = v;
        }
    }
}

// ---------------------------------------------------------------------------
// Kernel 2b (fallback path): merge the two KV-half partials -> Y^T bf16
// ---------------------------------------------------------------------------
__global__ __launch_bounds__(256) void merge_kernel(
    const short* __restrict__ yh, const float* __restrict__ ml,
    short* __restrict__ yp)
{
    const int tid = threadIdx.x;
    const int row = blockIdx.x * 8 + (tid >> 5);
    const int c4  = (tid & 31) * 4;
    const size_t H = (size_t)BB * NN * CI;
    const size_t R = (size_t)BB * NN * 2;

    float m0 = ml[(size_t)row * 2],     l0 = ml[(size_t)row * 2 + 1];
    float m1 = ml[R + (size_t)row * 2], l1 = ml[R + (size_t)row * 2 + 1];
    float mm = fmaxf(m0, m1);
    float w0 = __builtin_amdgcn_exp2f(m0 - mm);
    float w1 = __builtin_amdgcn_exp2f(m1 - mm);
    float inv = 1.0f / (l0 * w0 + l1 * w1);
    w0 *= inv; w1 *= inv;

    bf16x4 a  = *(const bf16x4*)&yh[(size_t)row * CI + c4];
    bf16x4 bb = *(const bf16x4*)&yh[H + (size_t)row * CI + c4];
    bf16x4 o;
    #pragma unroll
    for (int i = 0; i < 4; ++i) o[i] = f2bf(bf2f(a[i]) * w0 + bf2f(bb[i]) * w1);
    *(bf16x4*)&yp[(size_t)row * CI + c4] = o;
}

// ---------------------------------------------------------------------------
// Kernel 3: out = w_w @ Y + b_w + x, 128x128 tiles, XCD-pinned. w_w from
// prepped bf16. MERGED==0: fuse the partial merge into Y staging.
// ---------------------------------------------------------------------------
template <int MERGED>
__global__ __launch_bounds__(256) void out_kernel(
    const short* __restrict__ ysrc, const float* __restrict__ ml,
    const short* __restrict__ wwb, const float* __restrict__ bw,
    const float* __restrict__ x, float* __restrict__ out)
{
    __shared__ __align__(16) short A_lds[128][136];   // w_w [o][c]
    __shared__ __align__(16) short Bl[128][136];      // Y^T [n][c]

    const int tid  = threadIdx.x;
    const int b    = blockIdx.x & 7;
    const int rest = blockIdx.x >> 3;
    const int ob   = rest & 1;
    const int nn   = (rest >> 1) * 128;
    const int o0   = ob * 128;
    const int w = tid >> 6, lane = tid & 63, lr = lane & 15, lg = lane >> 4;

    #pragma unroll
    for (int pass = 0; pass < 8; ++pass) {
        int o  = pass * 16 + (tid >> 4);
        int c8 = (tid & 15) * 8;
        *(bf16x8*)&A_lds[o][c8] = *(const bf16x8*)&wwb[(size_t)(o0 + o) * CI + c8];
    }
    #pragma unroll
    for (int pass = 0; pass < 8; ++pass) {
        int n  = pass * 16 + (tid >> 4);
        int c8 = (tid & 15) * 8;
        size_t row = (size_t)b * NN + nn + n;
        if (MERGED) {
            *(bf16x8*)&Bl[n][c8] = *(const bf16x8*)&ysrc[row * CI + c8];
        } else {
            const size_t H = (size_t)BB * NN * CI;
            const size_t R = (size_t)BB * NN * 2;
            f32x2 v0 = *(const f32x2*)&ml[row * 2];
            f32x2 v1 = *(const f32x2*)&ml[R + row * 2];
            float mm = fmaxf(v0[0], v1[0]);
            float w0 = __builtin_amdgcn_exp2f(v0[0] - mm);
            float w1 = __builtin_amdgcn_exp2f(v1[0] - mm);
            float inv = 1.0f / (v0[1] * w0 + v1[1] * w1);
            w0 *= inv; w1 *= inv;
            bf16x8 a  = *(const bf16x8*)&ysrc[row * CI + c8];
            bf16x8 b2 = *(const bf16x8*)&ysrc[H + row * CI + c8];
            bf16x8 ov;
            #pragma unroll
            for (int i = 0; i < 4; ++i) {
                float lo = bf2f(a[2*i]) * w0 + bf2f(b2[2*i]) * w1;
                float hi = bf2f(a[2*i+1]) * w0 + bf2f(b2[2*i+1]) * w1;
                uint32_t pk = cvt_pk_bf16(lo, hi);
                ov[2*i]   = (short)(pk & 0xFFFF);
                ov[2*i+1] = (short)(pk >> 16);
            }
            *(bf16x8*)&Bl[n][c8] = ov;
        }
    }
    __syncthreads();

    f32x4 acc[2][8];
    #pragma unroll
    for (int i = 0; i < 2; ++i)
        #pragma unroll
        for (int j = 0; j < 8; ++j) acc[i][j] = (f32x4){0.f, 0.f, 0.f, 0.f};

    #pragma unroll
    for (int kf = 0; kf < 4; ++kf) {
        bf16x8 a0 = *(const bf16x8*)&A_lds[w * 32 + lr][kf * 32 + lg * 8];
        bf16x8 a1 = *(const bf16x8*)&A_lds[w * 32 + 16 + lr][kf * 32 + lg * 8];
        #pragma unroll
        for (int nt = 0; nt < 8; ++nt) {
            bf16x8 bv = *(const bf16x8*)&Bl[nt * 16 + lr][kf * 32 + lg * 8];
            acc[0][nt] = __builtin_amdgcn_mfma_f32_16x16x32_bf16(a0, bv, acc[0][nt], 0, 0, 0);
            acc[1][nt] = __builtin_amdgcn_mfma_f32_16x16x32_bf16(a1, bv, acc[1][nt], 0, 0, 0);
        }
    }

    #pragma unroll
    for (int wo = 0; wo < 2; ++wo) {
        #pragma unroll
        for (int rr = 0; rr < 4; ++rr) {
            int o = o0 + w * 32 + wo * 16 + lg * 4 + rr;
            float bias = bw[o];
            #pragma unroll
            for (int nt = 0; nt < 8; ++nt) {
                size_t idx = ((size_t)b * CIN + o) * NN + nn + nt * 16 + lr;
                out[idx] = acc[wo][nt][rr] + bias + x[idx];
            }
        }
    }
}

// ---------------------------------------------------------------------------
extern "C" void kernel_launch(void* const* d_in, const int* in_sizes, int n_in,
                              void* d_out, int out_size, void* d_ws, size_t ws_size,
                              hipStream_t stream)
{
    const float* x     = (const float*)d_in[0];
    const float* gamma = (const float*)d_in[1];
    const float* beta  = (const float*)d_in[2];
    const float* mean  = (const float*)d_in[3];
    const float* var   = (const float*)d_in[4];
    const float* wg    = (const float*)d_in[5];
    const float* bg    = (const float*)d_in[6];
    const float* wth   = (const float*)d_in[7];
    const float* bth   = (const float*)d_in[8];
    const float* wph   = (const float*)d_in[9];
    const float* bph   = (const float*)d_in[10];
    const float* ww    = (const float*)d_in[11];
    const float* bw    = (const float*)d_in[12];

    // ws layout (slot offsets unchanged; fp8 buffers half-use their slots):
    // qp fp8 4MB @0 | kp fp8 4MB @8MB | vt8 fp8 4MB @16MB | ml @24MB |
    // wq @24.5MiB | wwb | yh 16MB @25MiB.
    const size_t seg = (size_t)BB * NN * CI;
    unsigned char* qp  = (unsigned char*)d_ws;
    unsigned char* kp  = (unsigned char*)d_ws + seg * sizeof(short);
    unsigned char* vt8 = (unsigned char*)d_ws + 2 * seg * sizeof(short);
    float* ml  = (float*)((char*)d_ws + 3 * seg * sizeof(short));
    short* wq  = (short*)((char*)d_ws + 25690112);
    short* wwb = (short*)((char*)d_ws + 25690112 + 196608);
    const size_t yh_off = 25u * 1024 * 1024;
    const bool fused = ws_size >= yh_off + 2 * seg * sizeof(short);
    short* yh = fused ? (short*)((char*)d_ws + yh_off) : (short*)d_out;
    (void)in_sizes; (void)n_in; (void)out_size;

    prep_kernel<<<64, 256, 0, stream>>>(wth, wph, wg, ww, wq, wwb);
    proj_kernel<<<BB * (NN / 64), 256, 0, stream>>>(
        x, gamma, beta, mean, var, wq, bth, bph, bg, qp, kp, vt8);
    attn_kernel<<<2 * BB * (NN / 128), 256, 0, stream>>>(qp, kp, vt8, yh, ml);
    if (fused) {
        out_kernel<0><<<2 * BB * (NN / 128), 256, 0, stream>>>(
            yh, ml, wwb, bw, x, (float*)d_out);
    } else {
        short* yp = (short*)d_ws;   // reuse: q dead after attn
        merge_kernel<<<BB * NN / 8, 256, 0, stream>>>(yh, ml, yp);
        out_kernel<1><<<2 * BB * (NN / 128), 256, 0, stream>>>(
            yp, ml, wwb, bw, x, (float*)d_out);
    }
}

// Round 15
// 93.168 us; speedup vs baseline: 4.7774x; 1.0821x over previous
//
#include <hip/hip_runtime.h>
#include <hip/hip_bf16.h>
#include <stdint.h>

#define BB   8
#define CIN  256
#define CI   128
#define NN   4096
#define EPSV 1e-5f
#define LOG2E 1.44269504088896340736f

typedef __attribute__((ext_vector_type(8))) short bf16x8;
typedef __attribute__((ext_vector_type(4))) short bf16x4;
typedef __attribute__((ext_vector_type(4))) float f32x4;
typedef __attribute__((ext_vector_type(2))) float f32x2;
typedef __attribute__((ext_vector_type(2))) unsigned int u32x2;
typedef __attribute__((ext_vector_type(4))) int i32x4;
typedef __attribute__((ext_vector_type(8))) int i32x8;

static __device__ inline short f2bf(float f) {
    uint32_t u = __builtin_bit_cast(uint32_t, f);
    u += 0x7FFFu + ((u >> 16) & 1u);   // round-to-nearest-even
    return (short)(u >> 16);
}

static __device__ inline float bf2f(short s) {
    uint32_t u = ((uint32_t)(uint16_t)s) << 16;
    return __builtin_bit_cast(float, u);
}

static __device__ inline uint32_t cvt_pk_bf16(float lo, float hi) {
    uint32_t r;
    asm("v_cvt_pk_bf16_f32 %0, %1, %2" : "=v"(r) : "v"(lo), "v"(hi));
    return r;
}

// ---------------------------------------------------------------------------
// Kernel 0 (PREP): weights -> bf16 once (wq pre-swizzled; wth pre-scaled by
// log2e; wwb plain bf16 for out).
// ---------------------------------------------------------------------------
__global__ __launch_bounds__(256) void prep_kernel(
    const float* __restrict__ wth, const float* __restrict__ wph,
    const float* __restrict__ wg,  const float* __restrict__ ww,
    short* __restrict__ wq, short* __restrict__ wwb)
{
    int t = blockIdx.x * 256 + threadIdx.x;
    if (t < 12288) {                       // 3 x 128 x 32 16B-blocks
        int s  = t >> 12;
        int r  = t & 4095;
        int o  = r >> 5;
        int j  = r & 31;
        int k  = j >> 3, jj = j & 7;
        const float* W = (s == 0) ? wth : (s == 1) ? wph : wg;
        float sc = (s == 0) ? LOG2E : 1.0f;
        const float* src = &W[(size_t)o * CIN + k * 64 + jj * 8];
        bf16x8 d;
        #pragma unroll
        for (int i = 0; i < 8; ++i) d[i] = f2bf(src[i] * sc);
        size_t doff = (size_t)s * 65536 + (size_t)k * 16384
                    + (size_t)o * 128 + (size_t)((jj ^ (o & 7)) << 4);
        *(bf16x8*)((char*)wq + doff) = d;
    } else if (t < 16384) {                // ww: 256 x 16 16B-blocks
        int r = t - 12288;
        int o = r >> 4, j = r & 15;
        const float* src = &ww[(size_t)o * CI + j * 8];
        bf16x8 d;
        #pragma unroll
        for (int i = 0; i < 8; ++i) d[i] = f2bf(src[i]);
        *(bf16x8*)&wwb[(size_t)o * CI + j * 8] = d;
    }
}

// ---------------------------------------------------------------------------
// Kernel 1 (FUSED): BN + three 1x1 projections. Q,K AND V^T stored as FP8
// e4m3 (Q/K rows of 128 B; V^T (b,c,n) 1 B/elem).
// ---------------------------------------------------------------------------
__global__ __launch_bounds__(256, 2) void proj_kernel(
    const float* __restrict__ x,
    const float* __restrict__ gamma, const float* __restrict__ beta,
    const float* __restrict__ mean,  const float* __restrict__ var,
    const short* __restrict__ wq,
    const float* __restrict__ bth, const float* __restrict__ bph,
    const float* __restrict__ bg,
    unsigned char* __restrict__ qp, unsigned char* __restrict__ kp,
    unsigned char* __restrict__ vt8)
{
    __shared__ float s_scale[CIN];
    __shared__ float s_shift[CIN];
    __shared__ __align__(16) short A_lds[64][264];     // [n][c] full K, pad 264
    __shared__ __align__(16) char  B_sh[2][128 * 128]; // swizzled chunk, 16KB x2

    const int tid = threadIdx.x;
    const int b   = blockIdx.x & 7;           // batch == XCD
    const int n0  = (blockIdx.x >> 3) * 64;
    const int w = tid >> 6, lane = tid & 63, lr = lane & 15, lg = lane >> 4;

    {   // BN scale/shift (256 threads == 256 channels)
        float sc = gamma[tid] * rsqrtf(var[tid] + EPSV);
        s_scale[tid] = sc;
        s_shift[tid] = beta[tid] - mean[tid] * sc;
    }
    __syncthreads();

    // stage BN(x) -> A_lds[n][c] bf16, once; pair-column u32 writes
    #pragma unroll
    for (int p = 0; p < 8; ++p) {
        int c2 = p * 32 + (tid >> 4) * 2;
        int n4 = (tid & 15) * 4;
        f32x4 v0 = *(const f32x4*)&x[((size_t)b * CIN + c2) * NN + n0 + n4];
        f32x4 v1 = *(const f32x4*)&x[((size_t)b * CIN + c2 + 1) * NN + n0 + n4];
        float sc0 = s_scale[c2],     sh0 = s_shift[c2];
        float sc1 = s_scale[c2 + 1], sh1 = s_shift[c2 + 1];
        #pragma unroll
        for (int i = 0; i < 4; ++i) {
            uint32_t pk = cvt_pk_bf16(v0[i] * sc0 + sh0, v1[i] * sc1 + sh1);
            *(uint32_t*)&A_lds[n4 + i][c2] = pk;
        }
    }

    auto stageB = [&](int buf, int idx) {
        const char* src = (const char*)wq + (size_t)idx * 16384;
        #pragma unroll
        for (int r = 0; r < 4; ++r) {
            __builtin_amdgcn_global_load_lds(
                (const __attribute__((address_space(1))) void*)
                    (src + ((((r * 4 + w) << 6) + lane) << 4)),
                (__attribute__((address_space(3))) void*)&B_sh[buf][(r * 4 + w) << 10],
                16, 0, 0);
        }
    };
    stageB(0, 0);
    __syncthreads();

    const float* BS[3] = {bth, bph, bg};
    f32x4 acc[8];

    for (int idx = 0; idx < 12; ++idx) {
        const int s = idx >> 2, k = idx & 3, buf = idx & 1;
        if (idx + 1 < 12) stageB(buf ^ 1, idx + 1);

        if (k == 0) {
            #pragma unroll
            for (int i = 0; i < 8; ++i) acc[i] = (f32x4){0.f, 0.f, 0.f, 0.f};
        }
        const int c0 = k * 64;
        bf16x8 a0 = *(const bf16x8*)&A_lds[w * 16 + lr][c0 + lg * 8];
        bf16x8 a1 = *(const bf16x8*)&A_lds[w * 16 + lr][c0 + 32 + lg * 8];
        const char* Bc = B_sh[buf];
        #pragma unroll
        for (int ot = 0; ot < 8; ++ot) {
            const int o  = ot * 16 + lr;
            const int sw = (o & 7) << 4;
            bf16x8 b0 = *(const bf16x8*)(Bc + o * 128 + ((lg << 4) ^ sw));
            bf16x8 b1 = *(const bf16x8*)(Bc + o * 128 + (((4 + lg) << 4) ^ sw));
            acc[ot] = __builtin_amdgcn_mfma_f32_16x16x32_bf16(a0, b0, acc[ot], 0, 0, 0);
            acc[ot] = __builtin_amdgcn_mfma_f32_16x16x32_bf16(a1, b1, acc[ot], 0, 0, 0);
        }

        if (k == 3) {
            if (s < 2) {   // Q / K: fp8 e4m3 bytes, rows of 128 B
                unsigned char* dst = (s == 0) ? qp : kp;
                const float om = (s == 0) ? LOG2E : 1.0f;
                #pragma unroll
                for (int ot = 0; ot < 8; ++ot) {
                    float bias = BS[s][ot * 16 + lr] * om;
                    #pragma unroll
                    for (int rr = 0; rr < 4; ++rr) {
                        int n = n0 + w * 16 + lg * 4 + rr;
                        uint32_t pk = __builtin_amdgcn_cvt_pk_fp8_f32(
                            acc[ot][rr] + bias, 0.f, 0, false);
                        dst[((size_t)b * NN + n) * 128 + ot * 16 + lr] =
                            (unsigned char)(pk & 0xFF);
                    }
                }
            } else {       // V^T (b,c,n) fp8: 4 consecutive n -> 1 dword
                #pragma unroll
                for (int ot = 0; ot < 8; ++ot) {
                    float bias = BS[s][ot * 16 + lr];
                    uint32_t d = __builtin_amdgcn_cvt_pk_fp8_f32(
                        acc[ot][0] + bias, acc[ot][1] + bias, 0, false);
                    d = __builtin_amdgcn_cvt_pk_fp8_f32(
                        acc[ot][2] + bias, acc[ot][3] + bias, d, true);
                    *(uint32_t*)&vt8[((size_t)b * CI + ot * 16 + lr) * NN
                                     + n0 + w * 16 + lg * 4] = d;
                }
            }
        }
        __syncthreads();
    }
}

// ---------------------------------------------------------------------------
// Kernel 2: flash attention — all-fp8 MFMA, KVBLK=128/iter (16 iters, 16
// barriers: half of R14's stall events). QK^T: 8 mt x 2 strips mfma_scale
// K=128. PV: 8 ct x 2 strips mfma_scale K=128 (m=0..127 in one instr).
// LDS 72KB = K 2x16 + V 2x16 + P 4x2KB -> 2 blk/CU, 2 waves/SIMD.
// Do NOT raise occupancy (R6/7/8); do NOT split MFMA clusters (R10).
// ---------------------------------------------------------------------------
__global__ __launch_bounds__(256, 2) void attn_kernel(
    const unsigned char* __restrict__ qp, const unsigned char* __restrict__ kp,
    const unsigned char* __restrict__ vt8, short* __restrict__ yh,
    float* __restrict__ ml)
{
    __shared__ __align__(16) char K_sh[2][128 * 128];   // fp8 [m][c] swz, 16KB x2
    __shared__ __align__(16) char V_sh[2][128 * 128];   // fp8 [c][m] swz, 16KB x2
    __shared__ __align__(16) char P_sh[4][16 * 128];    // fp8 per-wave P buf, 2KB

    const int tid  = threadIdx.x;
    const int b    = blockIdx.x & 7;            // batch == XCD (round-robin)
    const int half = (blockIdx.x >> 3) & 1;     // kv half
    const int n0   = (blockIdx.x >> 4) * 128;
    const int w = tid >> 6, lane = tid & 63, lr = lane & 15, lg = lane >> 4;
    const int NT = NN / 256;                    // 16 kv iters (128 m each) per half
    const int t0 = half * NT;

    // loop-carried per-lane global source pointers (pre-swizzled), LDS dest linear
    const unsigned char* kgp[4];
    const unsigned char* vgp[4];
    #pragma unroll
    for (int r = 0; r < 4; ++r) {               // K fp8: 1024 16B-chunks/iter
        int idx = ((r * 4 + w) << 6) + lane;
        int mm  = idx >> 3, cb = (idx & 7) << 4;
        kgp[r] = kp + (size_t)b * NN * 128 + (size_t)(t0 * 128 + mm) * 128
               + (cb ^ ((mm & 7) << 4));
        int cc = idx >> 3, cbv = (idx & 7) << 4;
        vgp[r] = vt8 + (size_t)b * CI * NN + (size_t)cc * NN + t0 * 128
               + (cbv ^ ((cc & 7) << 4));
    }
    auto stage = [&](int bufi) {
        #pragma unroll
        for (int r = 0; r < 4; ++r) {
            __builtin_amdgcn_global_load_lds(
                (const __attribute__((address_space(1))) void*)kgp[r],
                (__attribute__((address_space(3))) void*)&K_sh[bufi][(r * 4 + w) << 10],
                16, 0, 0);
            kgp[r] += 128 * 128;      // next K iter: 16 KB
            __builtin_amdgcn_global_load_lds(
                (const __attribute__((address_space(1))) void*)vgp[r],
                (__attribute__((address_space(3))) void*)&V_sh[bufi][(r * 4 + w) << 10],
                16, 0, 0);
            vgp[r] += 128;            // next V iter: 128 m-bytes
        }
    };

    // Q strips in registers: fp8 B-frag, 32 B/lane = 8 dwords per strip
    i32x8 qf8[2];
    #pragma unroll
    for (int s = 0; s < 2; ++s) {
        const unsigned char* qrow = qp + ((size_t)b * NN + n0 + w * 32 + s * 16 + lr) * 128;
        i32x4 lo = *(const i32x4*)(qrow + lg * 32);
        i32x4 hi = *(const i32x4*)(qrow + lg * 32 + 16);
        qf8[s] = (i32x8){lo[0], lo[1], lo[2], lo[3], hi[0], hi[1], hi[2], hi[3]};
    }

    f32x4 yacc[2][8];
    #pragma unroll
    for (int s = 0; s < 2; ++s)
        #pragma unroll
        for (int i = 0; i < 8; ++i) yacc[s][i] = (f32x4){0.f, 0.f, 0.f, 0.f};
    float m_run[2] = {-__builtin_huge_valf(), -__builtin_huge_valf()};
    float l_run[2] = {0.f, 0.f};   // per-lane partials; reduced after the loop

    stage(0);
    __syncthreads();

    const int psw = (lr & 7) << 4;

    for (int t = 0; t < NT; ++t) {
        const int cur = t & 1;
        if (t + 1 < NT) stage(cur ^ 1);   // issue before compute

        // S^T = K Q : 8 mt x 2 strips, one mfma_scale (K=128=D) each
        const char* Kc = K_sh[cur];
        f32x4 sa[2][8];
        __builtin_amdgcn_s_setprio(1);
        #pragma unroll
        for (int mt = 0; mt < 8; ++mt) {
            const int mrow = mt * 16 + lr;
            const int sw   = (mrow & 7) << 4;
            const char* kr = Kc + mrow * 128;
            i32x4 k0 = *(const i32x4*)(kr + ((lg * 32) ^ sw));
            i32x4 k1 = *(const i32x4*)(kr + ((lg * 32 + 16) ^ sw));
            i32x8 kf8 = (i32x8){k0[0], k0[1], k0[2], k0[3], k1[0], k1[1], k1[2], k1[3]};
            sa[0][mt] = __builtin_amdgcn_mfma_scale_f32_16x16x128_f8f6f4(
                kf8, qf8[0], (f32x4){0.f, 0.f, 0.f, 0.f},
                0, 0, 0, 0x7F7F7F7F, 0, 0x7F7F7F7F);
            sa[1][mt] = __builtin_amdgcn_mfma_scale_f32_16x16x128_f8f6f4(
                kf8, qf8[1], (f32x4){0.f, 0.f, 0.f, 0.f},
                0, 0, 0, 0x7F7F7F7F, 0, 0x7F7F7F7F);
        }
        __builtin_amdgcn_s_setprio(0);

        // lazy online softmax: per-lane partial max; THR=4 keeps fp8 P
        // well under e4m3 max (448).
        float tml[2];
        #pragma unroll
        for (int s = 0; s < 2; ++s) {
            float tm = -__builtin_huge_valf();
            #pragma unroll
            for (int mt = 0; mt < 8; ++mt)
                tm = fmaxf(tm, fmaxf(fmaxf(sa[s][mt][0], sa[s][mt][1]),
                                     fmaxf(sa[s][mt][2], sa[s][mt][3])));
            tml[s] = tm;
        }
        if (__any((tml[0] - m_run[0] > 4.f) || (tml[1] - m_run[1] > 4.f))) {
            #pragma unroll
            for (int s = 0; s < 2; ++s) {
                float tm = tml[s];
                tm = fmaxf(tm, __shfl_xor(tm, 16));
                tm = fmaxf(tm, __shfl_xor(tm, 32));
                float mnew = fmaxf(m_run[s], tm);
                float sc   = __builtin_amdgcn_exp2f(m_run[s] - mnew);
                m_run[s] = mnew;
                l_run[s] *= sc;
                #pragma unroll
                for (int rr = 0; rr < 4; ++rr) {
                    float scb = __shfl(sc, (lane & 48) | (lg * 4 + rr));
                    #pragma unroll
                    for (int ct = 0; ct < 8; ++ct) yacc[s][ct][rr] *= scb;
                }
            }
        }

        // strips: exp2 + fp8 pack into per-wave P buf, read pa8, PV per strip
        i32x8 pa8[2];
        #pragma unroll
        for (int s = 0; s < 2; ++s) {
            char* Pb = P_sh[w] + lr * 128;
            float rs = 0.f;
            #pragma unroll
            for (int mt = 0; mt < 8; ++mt) {
                float e0 = __builtin_amdgcn_exp2f(sa[s][mt][0] - m_run[s]);
                float e1 = __builtin_amdgcn_exp2f(sa[s][mt][1] - m_run[s]);
                float e2 = __builtin_amdgcn_exp2f(sa[s][mt][2] - m_run[s]);
                float e3 = __builtin_amdgcn_exp2f(sa[s][mt][3] - m_run[s]);
                rs += (e0 + e1) + (e2 + e3);
                uint32_t d = __builtin_amdgcn_cvt_pk_fp8_f32(e0, e1, 0, false);
                d = __builtin_amdgcn_cvt_pk_fp8_f32(e2, e3, d, true);
                *(uint32_t*)(Pb + ((mt * 16 + lg * 4) ^ psw)) = d;
            }
            l_run[s] += rs;
            asm volatile("" ::: "memory");   // order P writes -> reads (same wave)
            i32x4 p0 = *(const i32x4*)(Pb + ((lg * 32) ^ psw));
            i32x4 p1 = *(const i32x4*)(Pb + ((lg * 32 + 16) ^ psw));
            pa8[s] = (i32x8){p0[0], p0[1], p0[2], p0[3], p1[0], p1[1], p1[2], p1[3]};
            asm volatile("" ::: "memory");   // pa read before next strip's writes
        }

        // Y += P V : 8 ct x 2 strips, one mfma_scale (K=128 m) each
        const char* Vc = V_sh[cur];
        __builtin_amdgcn_s_setprio(1);
        #pragma unroll
        for (int ct = 0; ct < 8; ++ct) {
            const char* vrow = Vc + (ct * 16 + lr) * 128;
            i32x4 v0 = *(const i32x4*)(vrow + ((lg * 32) ^ psw));
            i32x4 v1 = *(const i32x4*)(vrow + ((lg * 32 + 16) ^ psw));
            i32x8 vf8 = (i32x8){v0[0], v0[1], v0[2], v0[3], v1[0], v1[1], v1[2], v1[3]};
            yacc[0][ct] = __builtin_amdgcn_mfma_scale_f32_16x16x128_f8f6f4(
                pa8[0], vf8, yacc[0][ct], 0, 0, 0, 0x7F7F7F7F, 0, 0x7F7F7F7F);
            yacc[1][ct] = __builtin_amdgcn_mfma_scale_f32_16x16x128_f8f6f4(
                pa8[1], vf8, yacc[1][ct], 0, 0, 0, 0x7F7F7F7F, 0, 0x7F7F7F7F);
        }
        __builtin_amdgcn_s_setprio(0);

        __syncthreads();   // drains vmcnt: next tiles staged; buf[cur] reads done
    }

    // reduce l across the 4 lane-groups (deferred from the loop)
    #pragma unroll
    for (int s = 0; s < 2; ++s) {
        float lt = l_run[s];
        lt += __shfl_xor(lt, 16);
        lt += __shfl_xor(lt, 32);
        l_run[s] = lt;
    }

    // store UNNORMALIZED partial Yhat (bf16) + (m,l) per q-row
    short* yb = yh + ((size_t)half * BB + b) * NN * (size_t)CI;
    #pragma unroll
    for (int s = 0; s < 2; ++s) {
        #pragma unroll
        for (int rr = 0; rr < 4; ++rr) {
            int n = n0 + w * 32 + s * 16 + lg * 4 + rr;
            #pragma unroll
            for (int ct = 0; ct < 8; ++ct)
                yb[(size_t)n * CI + ct * 16 + lr] = f2bf(yacc[s][ct][rr]);
        }
    }
    if (lg == 0) {
        #pragma unroll
        for (int s = 0; s < 2; ++s) {
            int n = n0 + w * 32 + s * 16 + lr;
            f32x2 v = {m_run[s], l_run[s]};
            *(f32x2*)&ml[(((size_t)half * BB + b) * NN + n) * 2] = v;
        }
    }
}

// ---------------------------------------------------------------------------
// Kernel 2b (fallback path): merge the two KV-half partials -> Y^T bf16
// ---------------------------------------------------------------------------
__global__ __launch_bounds__(256) void merge_kernel(
    const short* __restrict__ yh, const float* __restrict__ ml,
    short* __restrict__ yp)
{
    const int tid = threadIdx.x;
    const int row = blockIdx.x * 8 + (tid >> 5);
    const int c4  = (tid & 31) * 4;
    const size_t H = (size_t)BB * NN * CI;
    const size_t R = (size_t)BB * NN * 2;

    float m0 = ml[(size_t)row * 2],     l0 = ml[(size_t)row * 2 + 1];
    float m1 = ml[R + (size_t)row * 2], l1 = ml[R + (size_t)row * 2 + 1];
    float mm = fmaxf(m0, m1);
    float w0 = __builtin_amdgcn_exp2f(m0 - mm);
    float w1 = __builtin_amdgcn_exp2f(m1 - mm);
    float inv = 1.0f / (l0 * w0 + l1 * w1);
    w0 *= inv; w1 *= inv;

    bf16x4 a  = *(const bf16x4*)&yh[(size_t)row * CI + c4];
    bf16x4 bb = *(const bf16x4*)&yh[H + (size_t)row * CI + c4];
    bf16x4 o;
    #pragma unroll
    for (int i = 0; i < 4; ++i) o[i] = f2bf(bf2f(a[i]) * w0 + bf2f(bb[i]) * w1);
    *(bf16x4*)&yp[(size_t)row * CI + c4] = o;
}

// ---------------------------------------------------------------------------
// Kernel 3: out = w_w @ Y + b_w + x, 128x128 tiles, XCD-pinned. w_w from
// prepped bf16. MERGED==0: fuse the partial merge into Y staging.
// ---------------------------------------------------------------------------
template <int MERGED>
__global__ __launch_bounds__(256) void out_kernel(
    const short* __restrict__ ysrc, const float* __restrict__ ml,
    const short* __restrict__ wwb, const float* __restrict__ bw,
    const float* __restrict__ x, float* __restrict__ out)
{
    __shared__ __align__(16) short A_lds[128][136];   // w_w [o][c]
    __shared__ __align__(16) short Bl[128][136];      // Y^T [n][c]

    const int tid  = threadIdx.x;
    const int b    = blockIdx.x & 7;
    const int rest = blockIdx.x >> 3;
    const int ob   = rest & 1;
    const int nn   = (rest >> 1) * 128;
    const int o0   = ob * 128;
    const int w = tid >> 6, lane = tid & 63, lr = lane & 15, lg = lane >> 4;

    #pragma unroll
    for (int pass = 0; pass < 8; ++pass) {
        int o  = pass * 16 + (tid >> 4);
        int c8 = (tid & 15) * 8;
        *(bf16x8*)&A_lds[o][c8] = *(const bf16x8*)&wwb[(size_t)(o0 + o) * CI + c8];
    }
    #pragma unroll
    for (int pass = 0; pass < 8; ++pass) {
        int n  = pass * 16 + (tid >> 4);
        int c8 = (tid & 15) * 8;
        size_t row = (size_t)b * NN + nn + n;
        if (MERGED) {
            *(bf16x8*)&Bl[n][c8] = *(const bf16x8*)&ysrc[row * CI + c8];
        } else {
            const size_t H = (size_t)BB * NN * CI;
            const size_t R = (size_t)BB * NN * 2;
            f32x2 v0 = *(const f32x2*)&ml[row * 2];
            f32x2 v1 = *(const f32x2*)&ml[R + row * 2];
            float mm = fmaxf(v0[0], v1[0]);
            float w0 = __builtin_amdgcn_exp2f(v0[0] - mm);
            float w1 = __builtin_amdgcn_exp2f(v1[0] - mm);
            float inv = 1.0f / (v0[1] * w0 + v1[1] * w1);
            w0 *= inv; w1 *= inv;
            bf16x8 a  = *(const bf16x8*)&ysrc[row * CI + c8];
            bf16x8 b2 = *(const bf16x8*)&ysrc[H + row * CI + c8];
            bf16x8 ov;
            #pragma unroll
            for (int i = 0; i < 4; ++i) {
                float lo = bf2f(a[2*i]) * w0 + bf2f(b2[2*i]) * w1;
                float hi = bf2f(a[2*i+1]) * w0 + bf2f(b2[2*i+1]) * w1;
                uint32_t pk = cvt_pk_bf16(lo, hi);
                ov[2*i]   = (short)(pk & 0xFFFF);
                ov[2*i+1] = (short)(pk >> 16);
            }
            *(bf16x8*)&Bl[n][c8] = ov;
        }
    }
    __syncthreads();

    f32x4 acc[2][8];
    #pragma unroll
    for (int i = 0; i < 2; ++i)
        #pragma unroll
        for (int j = 0; j < 8; ++j) acc[i][j] = (f32x4){0.f, 0.f, 0.f, 0.f};

    #pragma unroll
    for (int kf = 0; kf < 4; ++kf) {
        bf16x8 a0 = *(const bf16x8*)&A_lds[w * 32 + lr][kf * 32 + lg * 8];
        bf16x8 a1 = *(const bf16x8*)&A_lds[w * 32 + 16 + lr][kf * 32 + lg * 8];
        #pragma unroll
        for (int nt = 0; nt < 8; ++nt) {
            bf16x8 bv = *(const bf16x8*)&Bl[nt * 16 + lr][kf * 32 + lg * 8];
            acc[0][nt] = __builtin_amdgcn_mfma_f32_16x16x32_bf16(a0, bv, acc[0][nt], 0, 0, 0);
            acc[1][nt] = __builtin_amdgcn_mfma_f32_16x16x32_bf16(a1, bv, acc[1][nt], 0, 0, 0);
        }
    }

    #pragma unroll
    for (int wo = 0; wo < 2; ++wo) {
        #pragma unroll
        for (int rr = 0; rr < 4; ++rr) {
            int o = o0 + w * 32 + wo * 16 + lg * 4 + rr;
            float bias = bw[o];
            #pragma unroll
            for (int nt = 0; nt < 8; ++nt) {
                size_t idx = ((size_t)b * CIN + o) * NN + nn + nt * 16 + lr;
                out[idx] = acc[wo][nt][rr] + bias + x[idx];
            }
        }
    }
}

// ---------------------------------------------------------------------------
extern "C" void kernel_launch(void* const* d_in, const int* in_sizes, int n_in,
                              void* d_out, int out_size, void* d_ws, size_t ws_size,
                              hipStream_t stream)
{
    const float* x     = (const float*)d_in[0];
    const float* gamma = (const float*)d_in[1];
    const float* beta  = (const float*)d_in[2];
    const float* mean  = (const float*)d_in[3];
    const float* var   = (const float*)d_in[4];
    const float* wg    = (const float*)d_in[5];
    const float* bg    = (const float*)d_in[6];
    const float* wth   = (const float*)d_in[7];
    const float* bth   = (const float*)d_in[8];
    const float* wph   = (const float*)d_in[9];
    const float* bph   = (const float*)d_in[10];
    const float* ww    = (const float*)d_in[11];
    const float* bw    = (const float*)d_in[12];

    // ws layout (slot offsets unchanged; fp8 buffers half-use their slots):
    // qp fp8 4MB @0 | kp fp8 4MB @8MB | vt8 fp8 4MB @16MB | ml @24MB |
    // wq @24.5MiB | wwb | yh 16MB @25MiB.
    const size_t seg = (size_t)BB * NN * CI;
    unsigned char* qp  = (unsigned char*)d_ws;
    unsigned char* kp  = (unsigned char*)d_ws + seg * sizeof(short);
    unsigned char* vt8 = (unsigned char*)d_ws + 2 * seg * sizeof(short);
    float* ml  = (float*)((char*)d_ws + 3 * seg * sizeof(short));
    short* wq  = (short*)((char*)d_ws + 25690112);
    short* wwb = (short*)((char*)d_ws + 25690112 + 196608);
    const size_t yh_off = 25u * 1024 * 1024;
    const bool fused = ws_size >= yh_off + 2 * seg * sizeof(short);
    short* yh = fused ? (short*)((char*)d_ws + yh_off) : (short*)d_out;
    (void)in_sizes; (void)n_in; (void)out_size;

    prep_kernel<<<64, 256, 0, stream>>>(wth, wph, wg, ww, wq, wwb);
    proj_kernel<<<BB * (NN / 64), 256, 0, stream>>>(
        x, gamma, beta, mean, var, wq, bth, bph, bg, qp, kp, vt8);
    attn_kernel<<<2 * BB * (NN / 128), 256, 0, stream>>>(qp, kp, vt8, yh, ml);
    if (fused) {
        out_kernel<0><<<2 * BB * (NN / 128), 256, 0, stream>>>(
            yh, ml, wwb, bw, x, (float*)d_out);
    } else {
        short* yp = (short*)d_ws;   // reuse: q dead after attn
        merge_kernel<<<BB * NN / 8, 256, 0, stream>>>(yh, ml, yp);
        out_kernel<1><<<2 * BB * (NN / 128), 256, 0, stream>>>(
            yp, ml, wwb, bw, x, (float*)d_out);
    }
}